// Round 16
// baseline (1002.999 us; speedup 1.0000x reference)
//
#include <hip/hip_runtime.h>
#include <hip/hip_bf16.h>

// ---------------------------------------------------------------------------
// Transformer decoder, fp32 I/O. GEMMs: pure bf16 1-product, BK=64 2-phase
// (in-layer) / 128x256 tile (vocab, single dispatch). Attention: QK 3-product
// hi/lo (prob fidelity), PV 1-product. Cross QKV merged via A-select.
// B=2, ST=SS=1024, D=512, H=8, DK=64, L=4, DFF=2048, V=32000.
// ---------------------------------------------------------------------------

#define D_MODEL 512
#define NHEAD   8
#define DKH     64
#define SEQ     1024
#define NLAYER  4
#define DFF_    2048
#define VOCAB   32000
#define BATCH   2
#define MROWS   (BATCH*SEQ)   // 2048
#define PSLAB   1048576L

typedef short bf16x8 __attribute__((ext_vector_type(8)));
typedef short short4v __attribute__((ext_vector_type(4)));
typedef float f32x4  __attribute__((ext_vector_type(4)));

static __device__ __forceinline__ short f2bf(float f) {
    __hip_bfloat16 h = __float2bfloat16(f);
    return *reinterpret_cast<short*>(&h);
}
static __device__ __forceinline__ float bf2f(short s) {
    __hip_bfloat16 h = *reinterpret_cast<__hip_bfloat16*>(&s);
    return __bfloat162float(h);
}
static __device__ __forceinline__ void gld16(const void* g, void* l) {
    __builtin_amdgcn_global_load_lds(
        (__attribute__((address_space(1))) void*)(void*)g,
        (__attribute__((address_space(3))) void*)l, 16, 0, 0);
}

// ---------------- embedding + positional encoding + hi ----------------------
__global__ __launch_bounds__(256) void embed_pe_kernel(
    const int* __restrict__ tokens, const float* __restrict__ emb,
    float* __restrict__ x, short* __restrict__ xh)
{
    long idx = (long)blockIdx.x * 256 + threadIdx.x;   // over 1,048,576
    int  d   = (int)(idx & (D_MODEL - 1));
    long row = idx >> 9;
    int  s   = (int)(row & (SEQ - 1));
    int  tok = tokens[row];
    float twoi = (float)((d >> 1) << 1);
    float div  = expf(twoi * (-9.210340371976184f / 512.0f));
    float arg  = (float)s * div;
    float pe   = (d & 1) ? cosf(arg) : sinf(arg);
    float v = emb[(long)tok * D_MODEL + d] * 22.62741699796952f + pe; // sqrt(512)
    x[idx] = v;
    xh[idx] = f2bf(v);
}

// ---------------- fp32 -> bf16 hi -------------------------------------------
__global__ __launch_bounds__(256) void cvt_kernel(
    const float* __restrict__ in, short* __restrict__ h)
{
    long e = ((long)blockIdx.x * 256 + threadIdx.x) * 4;
    float4 v = *(const float4*)&in[e];
    short4v hv;
    hv[0] = f2bf(v.x); hv[1] = f2bf(v.y); hv[2] = f2bf(v.z); hv[3] = f2bf(v.w);
    *(short4v*)&h[e] = hv;
}

// ---------------- weight transpose-convert: W[K,N] -> WT[N,K] hi ------------
__global__ __launch_bounds__(256) void wtrans_kernel(
    const float* __restrict__ W, short* __restrict__ Th,
    int K, int ldW)
{
    const int n0 = blockIdx.x * 64, k0 = blockIdx.y * 64;
    __shared__ float tile[64][65];
    const int t = threadIdx.x;
#pragma unroll
    for (int i = 0; i < 4; ++i) {
        int e = t + i * 256; int kk = e >> 4; int nn = (e & 15) * 4;
        float4 v = *(const float4*)&W[(long)(k0 + kk) * ldW + n0 + nn];
        tile[kk][nn] = v.x; tile[kk][nn + 1] = v.y;
        tile[kk][nn + 2] = v.z; tile[kk][nn + 3] = v.w;
    }
    __syncthreads();
    const int n = t >> 2, ks = (t & 3) * 16;
    short h8[16];
#pragma unroll
    for (int j = 0; j < 16; ++j) h8[j] = f2bf(tile[ks + j][n]);
    long base = (long)(n0 + n) * K + k0 + ks;
    *(bf16x8*)&Th[base]     = *(bf16x8*)&h8[0];
    *(bf16x8*)&Th[base + 8] = *(bf16x8*)&h8[8];
}

// ---------------- merged per-layer weight transpose (10 matrices, hi only) --
__global__ __launch_bounds__(256) void wtrans_layer_kernel(
    const float* __restrict__ Wqkvo, const float* __restrict__ W1,
    const float* __restrict__ W2, int l,
    short* __restrict__ Th)
{
    const int j = blockIdx.x;
    const float* W; int ldW, K; long dstOff; int n0, k0;
    if (j < 512) {
        int mat = j >> 6, tile_ = j & 63;
        W = Wqkvo + (long)l * 2097152L + (long)mat * 262144L;
        ldW = 512; K = 512; dstOff = (long)mat * 262144L;
        n0 = (tile_ & 7) * 64; k0 = (tile_ >> 3) * 64;
    } else if (j < 768) {
        int t2 = j - 512;
        W = W1 + (long)l * 1048576L; ldW = 2048; K = 512; dstOff = 2097152L;
        n0 = (t2 & 31) * 64; k0 = (t2 >> 5) * 64;
    } else {
        int t3 = j - 768;
        W = W2 + (long)l * 1048576L; ldW = 512; K = 2048; dstOff = 3145728L;
        n0 = (t3 & 7) * 64; k0 = (t3 >> 3) * 64;
    }
    __shared__ float tile[64][65];
    const int t = threadIdx.x;
#pragma unroll
    for (int i = 0; i < 4; ++i) {
        int e = t + i * 256; int kk = e >> 4; int nn = (e & 15) * 4;
        float4 v = *(const float4*)&W[(long)(k0 + kk) * ldW + n0 + nn];
        tile[kk][nn] = v.x; tile[kk][nn + 1] = v.y;
        tile[kk][nn + 2] = v.z; tile[kk][nn + 3] = v.w;
    }
    __syncthreads();
    const int n = t >> 2, ks = (t & 3) * 16;
    short h8[16];
#pragma unroll
    for (int j2 = 0; j2 < 16; ++j2) h8[j2] = f2bf(tile[ks + j2][n]);
    long base = dstOff + (long)(n0 + n) * K + k0 + ks;
    *(bf16x8*)&Th[base]     = *(bf16x8*)&h8[0];
    *(bf16x8*)&Th[base + 8] = *(bf16x8*)&h8[8];
}

// ---------------- 1-product MFMA GEMM, BK-step 2-phase dbuf -----------------
// A = (MODE==3 && z>=aSwitchZ) ? A2h : Ah.  K-window at z*kOff.
// MODE 0: fp32+bias. MODE 2: bf16 hi+bias(+relu). MODE 3: head-major attn
// operand w/ dk swizzle; z!=vtZ -> Q/K hi/lo (z==scaledZ -> *0.125);
// z==vtZ -> transposed V hi. MODE 5: fp32 partial, no bias.
// K-step = BK (32 or 64); BK=64 stages two linear 32-halves per step.
template<int BM, int BN, int BK, int ACT, int MODE>
__global__ __launch_bounds__(256) void gemm_mfma_kernel(
    const short* __restrict__ Ah, const short* __restrict__ A2h,
    const short* __restrict__ Bh,
    const float* __restrict__ bias, float* __restrict__ C,
    short* __restrict__ Ch, short* __restrict__ Cl,
    short* __restrict__ VTh,
    int Keff, int ldA, int ldB, int ldc,
    long zB, long zBias, long zC, int kOff, int scaledZ, int vtZ, int aSwitchZ)
{
    constexpr int KH   = BK / 32;
    constexpr int MT_M = BM / 32;
    constexpr int MT_N = BN / 32;
    const long z = blockIdx.z;
    Bh += z * zB;
    if (MODE != 5) bias += z * zBias;

    const short* Au = (MODE == 3 && (int)z >= aSwitchZ) ? A2h : Ah;

    const int n0 = blockIdx.x * BN, m0 = blockIdx.y * BM;
    const int t = threadIdx.x;
    const int w = t >> 6, lane = t & 63;
    const int wm = w >> 1, wn = w & 1;
    const int lr = lane & 15, ks = lane >> 4;

    __shared__ short sAh[2][KH][BM * 32];
    __shared__ short sBh[2][KH][BN * 32];

    f32x4 acc[MT_M][MT_N];
#pragma unroll
    for (int i = 0; i < MT_M; ++i)
#pragma unroll
        for (int j = 0; j < MT_N; ++j) acc[i][j] = (f32x4){0.f, 0.f, 0.f, 0.f};

    const long rowA = ((long)m0 * ldA + (long)z * kOff) * 2;   // bytes
    const long rowB = ((long)n0 * ldB + (long)z * kOff) * 2;

    auto STAGE = [&](int buf, int kbase) {
#pragma unroll
        for (int h = 0; h < KH; ++h) {
            const int k0 = kbase + h * 32;
#pragma unroll
            for (int i = 0; i < BM / 64; ++i) {
                const int  L = i * 4096 + t * 16;
                const int  r = L >> 6, s = L & 63;
                const long gb = ((long)r * ldA + k0) * 2 + s;
                gld16((const char*)Au + rowA + gb, (char*)&sAh[buf][h][0] + L);
            }
#pragma unroll
            for (int i = 0; i < BN / 64; ++i) {
                const int  L = i * 4096 + t * 16;
                const int  r = L >> 6, s = L & 63;
                const long gb = ((long)r * ldB + k0) * 2 + s;
                gld16((const char*)Bh + rowB + gb, (char*)&sBh[buf][h][0] + L);
            }
        }
    };
    auto COMPUTE = [&](int buf) {
#pragma unroll
        for (int h = 0; h < KH; ++h) {
            bf16x8 ah[MT_M], bh[MT_N];
#pragma unroll
            for (int mt = 0; mt < MT_M; ++mt) {
                int row = wm * (BM / 2) + mt * 16 + lr;
                ah[mt] = *(const bf16x8*)&sAh[buf][h][row * 32 + ks * 8];
            }
#pragma unroll
            for (int nt = 0; nt < MT_N; ++nt) {
                int col = wn * (BN / 2) + nt * 16 + lr;
                bh[nt] = *(const bf16x8*)&sBh[buf][h][col * 32 + ks * 8];
            }
#pragma unroll
            for (int mt = 0; mt < MT_M; ++mt)
#pragma unroll
                for (int nt = 0; nt < MT_N; ++nt)
                    acc[mt][nt] = __builtin_amdgcn_mfma_f32_16x16x32_bf16(
                        ah[mt], bh[nt], acc[mt][nt], 0, 0, 0);
        }
    };

    STAGE(0, 0);
    __syncthreads();
    int cur = 0;
    for (int k0 = 0; k0 < Keff; k0 += BK) {
        if (k0 + BK < Keff) STAGE(cur ^ 1, k0 + BK);
        COMPUTE(cur);
        __syncthreads();
        cur ^= 1;
    }

    const int rq = lane >> 4, cq = lane & 15;
#pragma unroll
    for (int mt = 0; mt < MT_M; ++mt)
#pragma unroll
        for (int nt = 0; nt < MT_N; ++nt) {
            int gr0 = m0 + wm * (BM / 2) + mt * 16 + rq * 4;
            int gc  = n0 + wn * (BN / 2) + nt * 16 + cq;
            float vv[4];
            float bv = (MODE == 5) ? 0.f : bias[gc];
#pragma unroll
            for (int i = 0; i < 4; ++i) {
                float v = acc[mt][nt][i] + bv;
                if (ACT == 1) v = fmaxf(v, 0.f);
                vv[i] = v;
            }
            if (MODE == 0 || MODE == 5) {
#pragma unroll
                for (int i = 0; i < 4; ++i)
                    C[(long)(gr0 + i) * ldc + gc + z * zC] = vv[i];
            } else if (MODE == 2) {
#pragma unroll
                for (int i = 0; i < 4; ++i)
                    Ch[(long)(gr0 + i) * ldc + gc] = f2bf(vv[i]);
            } else {               // MODE 3
                if ((int)z == vtZ) {
                    int b = gr0 >> 10, s0 = gr0 & (SEQ - 1);
                    int hh2 = gc >> 6, dk = gc & 63;
                    int swz = (((dk >> 1) & 3) << 3) | (((dk >> 3) & 1) << 5);
                    long base = (((long)(b * NHEAD + hh2)) * 64 + dk) * 1024
                              + (long)(((s0 & ~7) ^ swz) | (s0 & 7));
                    short4v hv;
#pragma unroll
                    for (int i = 0; i < 4; ++i) hv[i] = f2bf(vv[i]);
                    *(short4v*)&VTh[base] = hv;
                } else {
                    float sc = ((int)z == scaledZ) ? 0.125f : 1.f;
#pragma unroll
                    for (int i = 0; i < 4; ++i) {
                        float v2 = vv[i] * sc;
                        int gr = gr0 + i;
                        int b = gr >> 10, s = gr & (SEQ - 1);
                        int hh2 = gc >> 6, dk = gc & 63;
                        int dks = dk ^ (((s >> 1) & 7) << 3);
                        long oidx = z * zC +
                            (((long)(b * NHEAD + hh2)) * SEQ + s) * 64 + dks;
                        short h = f2bf(v2);
                        Ch[oidx] = h;
                        Cl[oidx] = f2bf(v2 - bf2f(h));
                    }
                }
            }
        }
}

// ---------------- fused attention: 32 q-rows, 2 waves ------------------------
// QK: 3-product hi/lo (probs fidelity). PV: 1-product (P_hi * V_hi).
template<bool CAUSAL>
__global__ __launch_bounds__(128) void attn_fused_kernel(
    const short* __restrict__ Qh, const short* __restrict__ Ql,
    const short* __restrict__ Kh, const short* __restrict__ Kl,
    const short* __restrict__ VTh,
    float* __restrict__ attn, short* __restrict__ Oh)
{
    const int strip = blockIdx.x, bh = blockIdx.y;
    const int q0 = strip * 32;
    const int t = threadIdx.x, w = t >> 6, lane = t & 63;
    const int lr = lane & 15, ks = lane >> 4;
    const int rq = lane >> 4, cq = lane & 15;
    const int sxq = (lr >> 1) & 7;

    __shared__ short sKh[2][64*64], sKl[2][64*64];   // 32 KB
    __shared__ short sVh[2][64*64];                  // 16 KB
    __shared__ short sPh[2][16*80];                  //  5 KB

    const int diag  = strip >> 1;
    const int ktmax = CAUSAL ? diag + 1 : 16;

    {
        const long qb = ((long)bh * SEQ + q0) * 128;
#pragma unroll
        for (int i2 = 0; i2 < 2; ++i2) {
            int L = i2 * 2048 + t * 16; int r = L >> 7, off = L & 127;
            gld16((const char*)Qh + qb + (long)r*128 + off, (char*)&sKh[0][0] + L);
            gld16((const char*)Ql + qb + (long)r*128 + off, (char*)&sKl[0][0] + L);
        }
    }
    __syncthreads();
    bf16x8 qa[2][2];
#pragma unroll
    for (int k0 = 0; k0 < 2; ++k0) {
        int o = (w*16 + lr) * 64 + ((k0*32 + ks*8) ^ (sxq << 3));
        qa[k0][0] = *(const bf16x8*)&sKh[0][o];
        qa[k0][1] = *(const bf16x8*)&sKl[0][o];
    }
    __syncthreads();

    auto stageK = [&](int buf, int kt) {
        const long kb = ((long)bh * SEQ + kt*64) * 128;
#pragma unroll
        for (int i2 = 0; i2 < 4; ++i2) {
            int L = i2*2048 + t*16; int r = L >> 7, off = L & 127;
            gld16((const char*)Kh + kb + (long)r*128 + off, (char*)&sKh[buf][0] + L);
            gld16((const char*)Kl + kb + (long)r*128 + off, (char*)&sKl[buf][0] + L);
        }
    };
    auto stageV = [&](int buf, int kt) {
        const long vb = ((long)bh * 64) * 2048 + (long)kt * 128;
#pragma unroll
        for (int i2 = 0; i2 < 4; ++i2) {
            int L = i2*2048 + t*16; int r = L >> 7, off = L & 127;
            gld16((const char*)VTh + vb + (long)r*2048 + off, (char*)&sVh[buf][0] + L);
        }
    };
    auto scoresOf = [&](int buf, int kt, f32x4* sc) {
#pragma unroll
        for (int nt = 0; nt < 4; ++nt) sc[nt] = (f32x4){0.f, 0.f, 0.f, 0.f};
#pragma unroll
        for (int k0 = 0; k0 < 2; ++k0) {
            bf16x8 kh[4], kl[4];
#pragma unroll
            for (int nt = 0; nt < 4; ++nt) {
                int o = (nt*16 + lr) * 64 + ((k0*32 + ks*8) ^ (sxq << 3));
                kh[nt] = *(const bf16x8*)&sKh[buf][o];
                kl[nt] = *(const bf16x8*)&sKl[buf][o];
            }
#pragma unroll
            for (int nt = 0; nt < 4; ++nt) {
                sc[nt] = __builtin_amdgcn_mfma_f32_16x16x32_bf16(
                    qa[k0][0], kh[nt], sc[nt], 0, 0, 0);
                sc[nt] = __builtin_amdgcn_mfma_f32_16x16x32_bf16(
                    qa[k0][0], kl[nt], sc[nt], 0, 0, 0);
                sc[nt] = __builtin_amdgcn_mfma_f32_16x16x32_bf16(
                    qa[k0][1], kh[nt], sc[nt], 0, 0, 0);
            }
        }
        if (CAUSAL && kt == diag) {
            int row = q0 + w*16 + rq*4;
#pragma unroll
            for (int nt = 0; nt < 4; ++nt) {
                int col = kt*64 + nt*16 + cq;
#pragma unroll
                for (int i = 0; i < 4; ++i)
                    if (col > row + i) sc[nt][i] = -1e9f;
            }
        }
    };

    // ---- pass 1: online max + sum ----
    float m[4]   = {-3e38f, -3e38f, -3e38f, -3e38f};
    float sum[4] = {0.f, 0.f, 0.f, 0.f};
    int cur = 0;
    stageK(0, 0);
    __syncthreads();
    for (int kt = 0; kt < ktmax; ++kt) {
        if (kt + 1 < ktmax) stageK(cur ^ 1, kt + 1);
        f32x4 sc[4];
        scoresOf(cur, kt, sc);
#pragma unroll
        for (int i = 0; i < 4; ++i) {
            float tm = fmaxf(fmaxf(sc[0][i], sc[1][i]), fmaxf(sc[2][i], sc[3][i]));
#pragma unroll
            for (int d2 = 1; d2 <= 8; d2 <<= 1) tm = fmaxf(tm, __shfl_xor(tm, d2, 64));
            float mn = fmaxf(m[i], tm);
            float ps = __expf(sc[0][i] - mn) + __expf(sc[1][i] - mn)
                     + __expf(sc[2][i] - mn) + __expf(sc[3][i] - mn);
#pragma unroll
            for (int d2 = 1; d2 <= 8; d2 <<= 1) ps += __shfl_xor(ps, d2, 64);
            sum[i] = sum[i] * __expf(m[i] - mn) + ps;
            m[i] = mn;
        }
        __syncthreads();
        cur ^= 1;
    }
    float inv[4];
#pragma unroll
    for (int i = 0; i < 4; ++i) inv[i] = 1.f / sum[i];

    // ---- pass 2: recompute, probs out, PV (1-product) ----
    f32x4 acco[4];
#pragma unroll
    for (int nt = 0; nt < 4; ++nt) acco[nt] = (f32x4){0.f, 0.f, 0.f, 0.f};

    cur = 0;
    stageK(0, 0); stageV(0, 0);
    __syncthreads();
    for (int kt = 0; kt < 16; ++kt) {
        if (kt >= ktmax) {
#pragma unroll
            for (int nt = 0; nt < 4; ++nt)
#pragma unroll
                for (int i = 0; i < 4; ++i)
                    attn[((long)bh << 20) + ((long)(q0 + w*16 + rq*4 + i) << 10)
                         + kt*64 + nt*16 + cq] = 0.f;
            continue;
        }
        if (kt + 1 < ktmax) { stageK(cur ^ 1, kt + 1); stageV(cur ^ 1, kt + 1); }
        f32x4 sc[4];
        scoresOf(cur, kt, sc);
#pragma unroll
        for (int nt = 0; nt < 4; ++nt)
#pragma unroll
            for (int i = 0; i < 4; ++i) {
                float p = __expf(sc[nt][i] - m[i]) * inv[i];
                attn[((long)bh << 20) + ((long)(q0 + w*16 + rq*4 + i) << 10)
                     + kt*64 + nt*16 + cq] = p;
                sPh[w][(rq*4 + i)*80 + nt*16 + cq] = f2bf(p);
            }
#pragma unroll
        for (int k0 = 0; k0 < 2; ++k0) {
            bf16x8 pah = *(const bf16x8*)&sPh[w][lr*80 + k0*32 + ks*8];
#pragma unroll
            for (int nt = 0; nt < 4; ++nt) {
                int dk = nt*16 + lr;
                int swz = (((dk >> 1) & 3) << 3) | (((dk >> 3) & 1) << 5);
                int koff = (k0*32 + ks*8) ^ swz;
                bf16x8 vh8 = *(const bf16x8*)&sVh[cur][dk*64 + koff];
                acco[nt] = __builtin_amdgcn_mfma_f32_16x16x32_bf16(
                    pah, vh8, acco[nt], 0, 0, 0);
            }
        }
        __syncthreads();
        cur ^= 1;
    }

    const int b = bh >> 3, hh_ = bh & 7;
#pragma unroll
    for (int nt = 0; nt < 4; ++nt)
#pragma unroll
        for (int i = 0; i < 4; ++i) {
            long oidx = ((long)(b * SEQ + q0 + w*16 + rq*4 + i)) * D_MODEL
                      + hh_*64 + nt*16 + cq;
            Oh[oidx] = f2bf(acco[nt][i]);
        }
}

// ---------------- residual + NS partial slabs + bias + LayerNorm + hi -------
template<int NS>
__global__ __launch_bounds__(256) void add_ln_kernel(
    const float* __restrict__ xin, const float* __restrict__ part, long PS,
    const float* __restrict__ bias,
    const float* __restrict__ g, const float* __restrict__ bb,
    float* __restrict__ xout, short* __restrict__ xh)
{
    long row = blockIdx.x;
    const float* xr = xin + row * D_MODEL;
    float*       xo = xout+ row * D_MODEL;
    short*       hh = xh  + row * D_MODEL;
    int t = threadIdx.x;

    float a0 = xr[t]       + bias[t];
    float a1 = xr[t + 256] + bias[t + 256];
#pragma unroll
    for (int s2 = 0; s2 < NS; ++s2) {
        a0 += part[s2 * PS + row * D_MODEL + t];
        a1 += part[s2 * PS + row * D_MODEL + t + 256];
    }

    float s = a0 + a1;
#pragma unroll
    for (int m = 32; m; m >>= 1) s += __shfl_xor(s, m, 64);
    __shared__ float red1[4];
    __shared__ float red2[4];
    int w = t >> 6, lane = t & 63;
    if (lane == 0) red1[w] = s;
    __syncthreads();
    float mean = (red1[0] + red1[1] + red1[2] + red1[3]) * (1.f / 512.f);

    float d0 = a0 - mean, d1 = a1 - mean;
    float q = d0 * d0 + d1 * d1;
#pragma unroll
    for (int m = 32; m; m >>= 1) q += __shfl_xor(q, m, 64);
    if (lane == 0) red2[w] = q;
    __syncthreads();
    float var  = (red2[0] + red2[1] + red2[2] + red2[3]) * (1.f / 512.f);
    float rstd = rsqrtf(var + 1e-5f);

    float r0 = d0 * rstd * g[t]       + bb[t];
    float r1 = d1 * rstd * g[t + 256] + bb[t + 256];
    xo[t] = r0; xo[t + 256] = r1;
    hh[t] = f2bf(r0);
    hh[t + 256] = f2bf(r1);
}

// ---------------------------------------------------------------------------
extern "C" void kernel_launch(void* const* d_in, const int* in_sizes, int n_in,
                              void* d_out, int out_size, void* d_ws, size_t ws_size,
                              hipStream_t stream)
{
    const int*   tokens = (const int*)  d_in[0];
    const float* enc    = (const float*)d_in[1];
    const float* emb    = (const float*)d_in[3];
    const float* Wqkvo  = (const float*)d_in[4];   // [L,2,4,D,D]
    const float* bqkvo  = (const float*)d_in[5];   // [L,2,4,D]
    const float* W1     = (const float*)d_in[6];   // [L,D,DFF]
    const float* b1     = (const float*)d_in[7];
    const float* W2     = (const float*)d_in[8];   // [L,DFF,D]
    const float* b2     = (const float*)d_in[9];
    const float* lng    = (const float*)d_in[10];  // [L,3,D]
    const float* lnb    = (const float*)d_in[11];
    const float* Wout   = (const float*)d_in[12];  // [D,V]
    const float* bout   = (const float*)d_in[13];

    float* out    = (float*)d_out;
    float* selfA  = out + 65536000L;
    float* crossA = selfA + 67108864L;

    // workspace carve (~93 MB)
    char* p = (char*)d_ws;
    auto carve = [&](size_t bytes) { char* r = p; p += (bytes + 255) & ~255UL; return r; };
    float* x      = (float*)carve(1048576L * 4);
    short* xh     = (short*)carve(1048576L * 2);
    short* ench   = (short*)carve(1048576L * 2);
    short* qh     = (short*)carve(2097152L * 2);   // head-major Q|K hi
    short* ql     = (short*)carve(2097152L * 2);   // head-major Q|K lo
    short* vth    = (short*)carve(1048576L * 2);   // transposed V hi
    short* oh     = (short*)carve(1048576L * 2);
    short* t1h    = (short*)carve(4194304L * 2);   // FFN1 out hi
    float* part   = (float*)carve(4L * PSLAB * 4); // 4 K-split slabs
    short* WTLh   = (short*)carve(4194304L * 2);   // per-layer weights T hi
    short* WTh    = (short*)carve(16384000L * 2);  // full vocab WT hi (32.8 MB)

    const long PW = 262144L;    // 512*512
    const long HS = 1048576L;   // per attention operand slab

    embed_pe_kernel<<<4096, 256, 0, stream>>>(tokens, emb, x, xh);
    cvt_kernel<<<1024, 256, 0, stream>>>(enc, ench);

    for (int l = 0; l < NLAYER; ++l) {
        const float* bl = bqkvo + (long)l * 4096L;
        const float* bc = bl + 2048;
        const float* g  = lng + (long)l * 3 * 512;
        const float* bb = lnb + (long)l * 3 * 512;

        wtrans_layer_kernel<<<1024, 256, 0, stream>>>(Wqkvo, W1, W2, l, WTLh);

        // ---- self-attention (QKV one dispatch, A always xh) ----
        gemm_mfma_kernel<64,64,64,0,3><<<dim3(8, 32, 3), 256, 0, stream>>>(
            xh, xh, WTLh, bl, nullptr, qh, ql, vth,
            512, 512, 512, 0, PW, 512, HS, 0, /*scaledZ=*/0, /*vtZ=*/2,
            /*aSwitchZ=*/3);
        attn_fused_kernel<true><<<dim3(32, 16), 128, 0, stream>>>(
            qh, ql, qh + HS, ql + HS, vth,
            selfA + (long)l * 16777216L, oh);
        gemm_mfma_kernel<64,64,64,0,5><<<dim3(8, 32, 2), 256, 0, stream>>>(
            oh, nullptr, WTLh + 3*PW, nullptr, part, nullptr, nullptr, nullptr,
            256, 512, 512, 512, 0, 0, PSLAB, 256, -1, -1, 99);
        add_ln_kernel<2><<<MROWS, 256, 0, stream>>>(
            x, part, PSLAB, bl + 3*512, g, bb, x, xh);

        // ---- cross-attention (QKV merged: z0 Q from xh, z1 K / z2 V from enc)
        gemm_mfma_kernel<64,64,64,0,3><<<dim3(8, 32, 3), 256, 0, stream>>>(
            xh, ench, WTLh + 4*PW, bc, nullptr, qh, ql, vth,
            512, 512, 512, 0, PW, 512, HS, 0, /*scaledZ=*/0, /*vtZ=*/2,
            /*aSwitchZ=*/1);
        attn_fused_kernel<false><<<dim3(32, 16), 128, 0, stream>>>(
            qh, ql, qh + HS, ql + HS, vth,
            crossA + (long)l * 16777216L, oh);
        gemm_mfma_kernel<64,64,64,0,5><<<dim3(8, 32, 2), 256, 0, stream>>>(
            oh, nullptr, WTLh + 7*PW, nullptr, part, nullptr, nullptr, nullptr,
            256, 512, 512, 512, 0, 0, PSLAB, 256, -1, -1, 99);
        add_ln_kernel<2><<<MROWS, 256, 0, stream>>>(
            x, part, PSLAB, bc + 3*512, g + 512, bb + 512, x, xh);

        // ---- FFN ----
        gemm_mfma_kernel<64,64,64,1,2><<<dim3(32, 32, 1), 256, 0, stream>>>(
            xh, nullptr, WTLh + 2097152L, b1 + (long)l * 2048,
            nullptr, t1h, nullptr, nullptr,
            512, 512, 512, 2048, 0, 0, 0, 0, -1, -1, 99);
        gemm_mfma_kernel<64,64,64,0,5><<<dim3(8, 32, 4), 256, 0, stream>>>(
            t1h, nullptr, WTLh + 3145728L, nullptr, part,
            nullptr, nullptr, nullptr,
            512, 2048, 2048, 512, 0, 0, PSLAB, 512, -1, -1, 99);
        add_ln_kernel<4><<<MROWS, 256, 0, stream>>>(
            x, part, PSLAB, b2 + (long)l * 512, g + 1024, bb + 1024, x, xh);
    }

    // ---- final vocab projection: full width, one wtrans + one GEMM ----
    wtrans_kernel<<<dim3(500, 8, 1), 256, 0, stream>>>(Wout, WTh, 512, VOCAB);
    gemm_mfma_kernel<128,256,32,0,0><<<dim3(125, 16, 1), 256, 0, stream>>>(
        xh, nullptr, WTh, bout, out,
        nullptr, nullptr, nullptr,
        512, 512, 512, VOCAB, 0, 0, 0, 0, -1, -1, 99);
}

// Round 17
// 992.412 us; speedup vs baseline: 1.0107x; 1.0107x over previous
//
#include <hip/hip_runtime.h>
#include <hip/hip_bf16.h>

// ---------------------------------------------------------------------------
// Transformer decoder, fp32 I/O. GEMMs: pure bf16 1-product, BK=32 2-phase
// dbuf (R15 config). Attention: QK 3-product hi/lo (prob fidelity), PV
// 1-product; vectorized causal zero-fill. Cross QKV merged via A-select.
// B=2, ST=SS=1024, D=512, H=8, DK=64, L=4, DFF=2048, V=32000.
// ---------------------------------------------------------------------------

#define D_MODEL 512
#define NHEAD   8
#define DKH     64
#define SEQ     1024
#define NLAYER  4
#define DFF_    2048
#define VOCAB   32000
#define BATCH   2
#define MROWS   (BATCH*SEQ)   // 2048
#define PSLAB   1048576L

typedef short bf16x8 __attribute__((ext_vector_type(8)));
typedef short short4v __attribute__((ext_vector_type(4)));
typedef float f32x4  __attribute__((ext_vector_type(4)));

static __device__ __forceinline__ short f2bf(float f) {
    __hip_bfloat16 h = __float2bfloat16(f);
    return *reinterpret_cast<short*>(&h);
}
static __device__ __forceinline__ float bf2f(short s) {
    __hip_bfloat16 h = *reinterpret_cast<__hip_bfloat16*>(&s);
    return __bfloat162float(h);
}
static __device__ __forceinline__ void gld16(const void* g, void* l) {
    __builtin_amdgcn_global_load_lds(
        (__attribute__((address_space(1))) void*)(void*)g,
        (__attribute__((address_space(3))) void*)l, 16, 0, 0);
}

// ---------------- embedding + positional encoding + hi ----------------------
__global__ __launch_bounds__(256) void embed_pe_kernel(
    const int* __restrict__ tokens, const float* __restrict__ emb,
    float* __restrict__ x, short* __restrict__ xh)
{
    long idx = (long)blockIdx.x * 256 + threadIdx.x;   // over 1,048,576
    int  d   = (int)(idx & (D_MODEL - 1));
    long row = idx >> 9;
    int  s   = (int)(row & (SEQ - 1));
    int  tok = tokens[row];
    float twoi = (float)((d >> 1) << 1);
    float div  = expf(twoi * (-9.210340371976184f / 512.0f));
    float arg  = (float)s * div;
    float pe   = (d & 1) ? cosf(arg) : sinf(arg);
    float v = emb[(long)tok * D_MODEL + d] * 22.62741699796952f + pe; // sqrt(512)
    x[idx] = v;
    xh[idx] = f2bf(v);
}

// ---------------- fp32 -> bf16 hi -------------------------------------------
__global__ __launch_bounds__(256) void cvt_kernel(
    const float* __restrict__ in, short* __restrict__ h)
{
    long e = ((long)blockIdx.x * 256 + threadIdx.x) * 4;
    float4 v = *(const float4*)&in[e];
    short4v hv;
    hv[0] = f2bf(v.x); hv[1] = f2bf(v.y); hv[2] = f2bf(v.z); hv[3] = f2bf(v.w);
    *(short4v*)&h[e] = hv;
}

// ---------------- weight transpose-convert: W[K,N] -> WT[N,K] hi ------------
__global__ __launch_bounds__(256) void wtrans_kernel(
    const float* __restrict__ W, short* __restrict__ Th,
    int K, int ldW)
{
    const int n0 = blockIdx.x * 64, k0 = blockIdx.y * 64;
    __shared__ float tile[64][65];
    const int t = threadIdx.x;
#pragma unroll
    for (int i = 0; i < 4; ++i) {
        int e = t + i * 256; int kk = e >> 4; int nn = (e & 15) * 4;
        float4 v = *(const float4*)&W[(long)(k0 + kk) * ldW + n0 + nn];
        tile[kk][nn] = v.x; tile[kk][nn + 1] = v.y;
        tile[kk][nn + 2] = v.z; tile[kk][nn + 3] = v.w;
    }
    __syncthreads();
    const int n = t >> 2, ks = (t & 3) * 16;
    short h8[16];
#pragma unroll
    for (int j = 0; j < 16; ++j) h8[j] = f2bf(tile[ks + j][n]);
    long base = (long)(n0 + n) * K + k0 + ks;
    *(bf16x8*)&Th[base]     = *(bf16x8*)&h8[0];
    *(bf16x8*)&Th[base + 8] = *(bf16x8*)&h8[8];
}

// ---------------- merged per-layer weight transpose (10 matrices, hi only) --
__global__ __launch_bounds__(256) void wtrans_layer_kernel(
    const float* __restrict__ Wqkvo, const float* __restrict__ W1,
    const float* __restrict__ W2, int l,
    short* __restrict__ Th)
{
    const int j = blockIdx.x;
    const float* W; int ldW, K; long dstOff; int n0, k0;
    if (j < 512) {
        int mat = j >> 6, tile_ = j & 63;
        W = Wqkvo + (long)l * 2097152L + (long)mat * 262144L;
        ldW = 512; K = 512; dstOff = (long)mat * 262144L;
        n0 = (tile_ & 7) * 64; k0 = (tile_ >> 3) * 64;
    } else if (j < 768) {
        int t2 = j - 512;
        W = W1 + (long)l * 1048576L; ldW = 2048; K = 512; dstOff = 2097152L;
        n0 = (t2 & 31) * 64; k0 = (t2 >> 5) * 64;
    } else {
        int t3 = j - 768;
        W = W2 + (long)l * 1048576L; ldW = 512; K = 2048; dstOff = 3145728L;
        n0 = (t3 & 7) * 64; k0 = (t3 >> 3) * 64;
    }
    __shared__ float tile[64][65];
    const int t = threadIdx.x;
#pragma unroll
    for (int i = 0; i < 4; ++i) {
        int e = t + i * 256; int kk = e >> 4; int nn = (e & 15) * 4;
        float4 v = *(const float4*)&W[(long)(k0 + kk) * ldW + n0 + nn];
        tile[kk][nn] = v.x; tile[kk][nn + 1] = v.y;
        tile[kk][nn + 2] = v.z; tile[kk][nn + 3] = v.w;
    }
    __syncthreads();
    const int n = t >> 2, ks = (t & 3) * 16;
    short h8[16];
#pragma unroll
    for (int j2 = 0; j2 < 16; ++j2) h8[j2] = f2bf(tile[ks + j2][n]);
    long base = dstOff + (long)(n0 + n) * K + k0 + ks;
    *(bf16x8*)&Th[base]     = *(bf16x8*)&h8[0];
    *(bf16x8*)&Th[base + 8] = *(bf16x8*)&h8[8];
}

// ---------------- 1-product MFMA GEMM, 2-phase dbuf (BK=32) -----------------
// A = (MODE==3 && z>=aSwitchZ) ? A2h : Ah.  K-window at z*kOff.
// MODE 0: fp32+bias. MODE 2: bf16 hi+bias(+relu). MODE 3: head-major attn
// operand w/ dk swizzle; z!=vtZ -> Q/K hi/lo (z==scaledZ -> *0.125);
// z==vtZ -> transposed V hi. MODE 5: fp32 partial, no bias.
template<int BM, int BN, int ACT, int MODE>
__global__ __launch_bounds__(256) void gemm_mfma_kernel(
    const short* __restrict__ Ah, const short* __restrict__ A2h,
    const short* __restrict__ Bh,
    const float* __restrict__ bias, float* __restrict__ C,
    short* __restrict__ Ch, short* __restrict__ Cl,
    short* __restrict__ VTh,
    int Keff, int ldA, int ldB, int ldc,
    long zB, long zBias, long zC, int kOff, int scaledZ, int vtZ, int aSwitchZ)
{
    constexpr int MT_M = BM / 32;
    constexpr int MT_N = BN / 32;
    const long z = blockIdx.z;
    Bh += z * zB;
    if (MODE != 5) bias += z * zBias;

    const short* Au = (MODE == 3 && (int)z >= aSwitchZ) ? A2h : Ah;

    const int n0 = blockIdx.x * BN, m0 = blockIdx.y * BM;
    const int t = threadIdx.x;
    const int w = t >> 6, lane = t & 63;
    const int wm = w >> 1, wn = w & 1;
    const int lr = lane & 15, ks = lane >> 4;

    __shared__ short sAh[2][BM * 32];
    __shared__ short sBh[2][BN * 32];

    f32x4 acc[MT_M][MT_N];
#pragma unroll
    for (int i = 0; i < MT_M; ++i)
#pragma unroll
        for (int j = 0; j < MT_N; ++j) acc[i][j] = (f32x4){0.f, 0.f, 0.f, 0.f};

    const long rowA = ((long)m0 * ldA + (long)z * kOff) * 2;   // bytes
    const long rowB = ((long)n0 * ldB + (long)z * kOff) * 2;

    auto STAGE = [&](int buf, int k0) {
#pragma unroll
        for (int i = 0; i < BM / 64; ++i) {
            const int  L = i * 4096 + t * 16;
            const int  r = L >> 6, s = L & 63;
            const long gb = ((long)r * ldA + k0) * 2 + s;
            gld16((const char*)Au + rowA + gb, (char*)&sAh[buf][0] + L);
        }
#pragma unroll
        for (int i = 0; i < BN / 64; ++i) {
            const int  L = i * 4096 + t * 16;
            const int  r = L >> 6, s = L & 63;
            const long gb = ((long)r * ldB + k0) * 2 + s;
            gld16((const char*)Bh + rowB + gb, (char*)&sBh[buf][0] + L);
        }
    };
    auto COMPUTE = [&](int buf) {
        bf16x8 ah[MT_M], bh[MT_N];
#pragma unroll
        for (int mt = 0; mt < MT_M; ++mt) {
            int row = wm * (BM / 2) + mt * 16 + lr;
            ah[mt] = *(const bf16x8*)&sAh[buf][row * 32 + ks * 8];
        }
#pragma unroll
        for (int nt = 0; nt < MT_N; ++nt) {
            int col = wn * (BN / 2) + nt * 16 + lr;
            bh[nt] = *(const bf16x8*)&sBh[buf][col * 32 + ks * 8];
        }
#pragma unroll
        for (int mt = 0; mt < MT_M; ++mt)
#pragma unroll
            for (int nt = 0; nt < MT_N; ++nt)
                acc[mt][nt] = __builtin_amdgcn_mfma_f32_16x16x32_bf16(
                    ah[mt], bh[nt], acc[mt][nt], 0, 0, 0);
    };

    STAGE(0, 0);
    __syncthreads();
    int cur = 0;
    for (int k0 = 0; k0 < Keff; k0 += 32) {
        if (k0 + 32 < Keff) STAGE(cur ^ 1, k0 + 32);
        COMPUTE(cur);
        __syncthreads();
        cur ^= 1;
    }

    const int rq = lane >> 4, cq = lane & 15;
#pragma unroll
    for (int mt = 0; mt < MT_M; ++mt)
#pragma unroll
        for (int nt = 0; nt < MT_N; ++nt) {
            int gr0 = m0 + wm * (BM / 2) + mt * 16 + rq * 4;
            int gc  = n0 + wn * (BN / 2) + nt * 16 + cq;
            float vv[4];
            float bv = (MODE == 5) ? 0.f : bias[gc];
#pragma unroll
            for (int i = 0; i < 4; ++i) {
                float v = acc[mt][nt][i] + bv;
                if (ACT == 1) v = fmaxf(v, 0.f);
                vv[i] = v;
            }
            if (MODE == 0 || MODE == 5) {
#pragma unroll
                for (int i = 0; i < 4; ++i)
                    C[(long)(gr0 + i) * ldc + gc + z * zC] = vv[i];
            } else if (MODE == 2) {
#pragma unroll
                for (int i = 0; i < 4; ++i)
                    Ch[(long)(gr0 + i) * ldc + gc] = f2bf(vv[i]);
            } else {               // MODE 3
                if ((int)z == vtZ) {
                    int b = gr0 >> 10, s0 = gr0 & (SEQ - 1);
                    int hh2 = gc >> 6, dk = gc & 63;
                    int swz = (((dk >> 1) & 3) << 3) | (((dk >> 3) & 1) << 5);
                    long base = (((long)(b * NHEAD + hh2)) * 64 + dk) * 1024
                              + (long)(((s0 & ~7) ^ swz) | (s0 & 7));
                    short4v hv;
#pragma unroll
                    for (int i = 0; i < 4; ++i) hv[i] = f2bf(vv[i]);
                    *(short4v*)&VTh[base] = hv;
                } else {
                    float sc = ((int)z == scaledZ) ? 0.125f : 1.f;
#pragma unroll
                    for (int i = 0; i < 4; ++i) {
                        float v2 = vv[i] * sc;
                        int gr = gr0 + i;
                        int b = gr >> 10, s = gr & (SEQ - 1);
                        int hh2 = gc >> 6, dk = gc & 63;
                        int dks = dk ^ (((s >> 1) & 7) << 3);
                        long oidx = z * zC +
                            (((long)(b * NHEAD + hh2)) * SEQ + s) * 64 + dks;
                        short h = f2bf(v2);
                        Ch[oidx] = h;
                        Cl[oidx] = f2bf(v2 - bf2f(h));
                    }
                }
            }
        }
}

// ---------------- fused attention: 32 q-rows, 2 waves ------------------------
// QK: 3-product hi/lo (probs fidelity). PV: 1-product (P_hi * V_hi).
// Causal masked region: single vectorized float4 zero-fill after the PV loop.
template<bool CAUSAL>
__global__ __launch_bounds__(128) void attn_fused_kernel(
    const short* __restrict__ Qh, const short* __restrict__ Ql,
    const short* __restrict__ Kh, const short* __restrict__ Kl,
    const short* __restrict__ VTh,
    float* __restrict__ attn, short* __restrict__ Oh)
{
    const int strip = blockIdx.x, bh = blockIdx.y;
    const int q0 = strip * 32;
    const int t = threadIdx.x, w = t >> 6, lane = t & 63;
    const int lr = lane & 15, ks = lane >> 4;
    const int rq = lane >> 4, cq = lane & 15;
    const int sxq = (lr >> 1) & 7;

    __shared__ short sKh[2][64*64], sKl[2][64*64];   // 32 KB
    __shared__ short sVh[2][64*64];                  // 16 KB
    __shared__ short sPh[2][16*80];                  //  5 KB

    const int diag  = strip >> 1;
    const int ktmax = CAUSAL ? diag + 1 : 16;

    {
        const long qb = ((long)bh * SEQ + q0) * 128;
#pragma unroll
        for (int i2 = 0; i2 < 2; ++i2) {
            int L = i2 * 2048 + t * 16; int r = L >> 7, off = L & 127;
            gld16((const char*)Qh + qb + (long)r*128 + off, (char*)&sKh[0][0] + L);
            gld16((const char*)Ql + qb + (long)r*128 + off, (char*)&sKl[0][0] + L);
        }
    }
    __syncthreads();
    bf16x8 qa[2][2];
#pragma unroll
    for (int k0 = 0; k0 < 2; ++k0) {
        int o = (w*16 + lr) * 64 + ((k0*32 + ks*8) ^ (sxq << 3));
        qa[k0][0] = *(const bf16x8*)&sKh[0][o];
        qa[k0][1] = *(const bf16x8*)&sKl[0][o];
    }
    __syncthreads();

    auto stageK = [&](int buf, int kt) {
        const long kb = ((long)bh * SEQ + kt*64) * 128;
#pragma unroll
        for (int i2 = 0; i2 < 4; ++i2) {
            int L = i2*2048 + t*16; int r = L >> 7, off = L & 127;
            gld16((const char*)Kh + kb + (long)r*128 + off, (char*)&sKh[buf][0] + L);
            gld16((const char*)Kl + kb + (long)r*128 + off, (char*)&sKl[buf][0] + L);
        }
    };
    auto stageV = [&](int buf, int kt) {
        const long vb = ((long)bh * 64) * 2048 + (long)kt * 128;
#pragma unroll
        for (int i2 = 0; i2 < 4; ++i2) {
            int L = i2*2048 + t*16; int r = L >> 7, off = L & 127;
            gld16((const char*)VTh + vb + (long)r*2048 + off, (char*)&sVh[buf][0] + L);
        }
    };
    auto scoresOf = [&](int buf, int kt, f32x4* sc) {
#pragma unroll
        for (int nt = 0; nt < 4; ++nt) sc[nt] = (f32x4){0.f, 0.f, 0.f, 0.f};
#pragma unroll
        for (int k0 = 0; k0 < 2; ++k0) {
            bf16x8 kh[4], kl[4];
#pragma unroll
            for (int nt = 0; nt < 4; ++nt) {
                int o = (nt*16 + lr) * 64 + ((k0*32 + ks*8) ^ (sxq << 3));
                kh[nt] = *(const bf16x8*)&sKh[buf][o];
                kl[nt] = *(const bf16x8*)&sKl[buf][o];
            }
#pragma unroll
            for (int nt = 0; nt < 4; ++nt) {
                sc[nt] = __builtin_amdgcn_mfma_f32_16x16x32_bf16(
                    qa[k0][0], kh[nt], sc[nt], 0, 0, 0);
                sc[nt] = __builtin_amdgcn_mfma_f32_16x16x32_bf16(
                    qa[k0][0], kl[nt], sc[nt], 0, 0, 0);
                sc[nt] = __builtin_amdgcn_mfma_f32_16x16x32_bf16(
                    qa[k0][1], kh[nt], sc[nt], 0, 0, 0);
            }
        }
        if (CAUSAL && kt == diag) {
            int row = q0 + w*16 + rq*4;
#pragma unroll
            for (int nt = 0; nt < 4; ++nt) {
                int col = kt*64 + nt*16 + cq;
#pragma unroll
                for (int i = 0; i < 4; ++i)
                    if (col > row + i) sc[nt][i] = -1e9f;
            }
        }
    };

    // ---- pass 1: online max + sum ----
    float m[4]   = {-3e38f, -3e38f, -3e38f, -3e38f};
    float sum[4] = {0.f, 0.f, 0.f, 0.f};
    int cur = 0;
    stageK(0, 0);
    __syncthreads();
    for (int kt = 0; kt < ktmax; ++kt) {
        if (kt + 1 < ktmax) stageK(cur ^ 1, kt + 1);
        f32x4 sc[4];
        scoresOf(cur, kt, sc);
#pragma unroll
        for (int i = 0; i < 4; ++i) {
            float tm = fmaxf(fmaxf(sc[0][i], sc[1][i]), fmaxf(sc[2][i], sc[3][i]));
#pragma unroll
            for (int d2 = 1; d2 <= 8; d2 <<= 1) tm = fmaxf(tm, __shfl_xor(tm, d2, 64));
            float mn = fmaxf(m[i], tm);
            float ps = __expf(sc[0][i] - mn) + __expf(sc[1][i] - mn)
                     + __expf(sc[2][i] - mn) + __expf(sc[3][i] - mn);
#pragma unroll
            for (int d2 = 1; d2 <= 8; d2 <<= 1) ps += __shfl_xor(ps, d2, 64);
            sum[i] = sum[i] * __expf(m[i] - mn) + ps;
            m[i] = mn;
        }
        __syncthreads();
        cur ^= 1;
    }
    float inv[4];
#pragma unroll
    for (int i = 0; i < 4; ++i) inv[i] = 1.f / sum[i];

    // ---- pass 2: recompute, probs out, PV (1-product) ----
    f32x4 acco[4];
#pragma unroll
    for (int nt = 0; nt < 4; ++nt) acco[nt] = (f32x4){0.f, 0.f, 0.f, 0.f};

    cur = 0;
    stageK(0, 0); stageV(0, 0);
    __syncthreads();
    for (int kt = 0; kt < ktmax; ++kt) {
        if (kt + 1 < ktmax) { stageK(cur ^ 1, kt + 1); stageV(cur ^ 1, kt + 1); }
        f32x4 sc[4];
        scoresOf(cur, kt, sc);
#pragma unroll
        for (int nt = 0; nt < 4; ++nt)
#pragma unroll
            for (int i = 0; i < 4; ++i) {
                float p = __expf(sc[nt][i] - m[i]) * inv[i];
                attn[((long)bh << 20) + ((long)(q0 + w*16 + rq*4 + i) << 10)
                     + kt*64 + nt*16 + cq] = p;
                sPh[w][(rq*4 + i)*80 + nt*16 + cq] = f2bf(p);
            }
#pragma unroll
        for (int k0 = 0; k0 < 2; ++k0) {
            bf16x8 pah = *(const bf16x8*)&sPh[w][lr*80 + k0*32 + ks*8];
#pragma unroll
            for (int nt = 0; nt < 4; ++nt) {
                int dk = nt*16 + lr;
                int swz = (((dk >> 1) & 3) << 3) | (((dk >> 3) & 1) << 5);
                int koff = (k0*32 + ks*8) ^ swz;
                bf16x8 vh8 = *(const bf16x8*)&sVh[cur][dk*64 + koff];
                acco[nt] = __builtin_amdgcn_mfma_f32_16x16x32_bf16(
                    pah, vh8, acco[nt], 0, 0, 0);
            }
        }
        __syncthreads();
        cur ^= 1;
    }

    // ---- causal masked region: vectorized zero fill ----
    if (CAUSAL && ktmax < 16) {
        const int r = t >> 2, g = (t & 3) * 4;
        const long rowbase = ((long)bh << 20) + ((long)(q0 + r) << 10);
        const float4 z4 = {0.f, 0.f, 0.f, 0.f};
        for (int c = ktmax * 64 + g; c < SEQ; c += 16)
            *(float4*)&attn[rowbase + c] = z4;
    }

    const int b = bh >> 3, hh_ = bh & 7;
#pragma unroll
    for (int nt = 0; nt < 4; ++nt)
#pragma unroll
        for (int i = 0; i < 4; ++i) {
            long oidx = ((long)(b * SEQ + q0 + w*16 + rq*4 + i)) * D_MODEL
                      + hh_*64 + nt*16 + cq;
            Oh[oidx] = f2bf(acco[nt][i]);
        }
}

// ---------------- residual + NS partial slabs + bias + LayerNorm + hi -------
template<int NS>
__global__ __launch_bounds__(256) void add_ln_kernel(
    const float* __restrict__ xin, const float* __restrict__ part, long PS,
    const float* __restrict__ bias,
    const float* __restrict__ g, const float* __restrict__ bb,
    float* __restrict__ xout, short* __restrict__ xh)
{
    long row = blockIdx.x;
    const float* xr = xin + row * D_MODEL;
    float*       xo = xout+ row * D_MODEL;
    short*       hh = xh  + row * D_MODEL;
    int t = threadIdx.x;

    float a0 = xr[t]       + bias[t];
    float a1 = xr[t + 256] + bias[t + 256];
#pragma unroll
    for (int s2 = 0; s2 < NS; ++s2) {
        a0 += part[s2 * PS + row * D_MODEL + t];
        a1 += part[s2 * PS + row * D_MODEL + t + 256];
    }

    float s = a0 + a1;
#pragma unroll
    for (int m = 32; m; m >>= 1) s += __shfl_xor(s, m, 64);
    __shared__ float red1[4];
    __shared__ float red2[4];
    int w = t >> 6, lane = t & 63;
    if (lane == 0) red1[w] = s;
    __syncthreads();
    float mean = (red1[0] + red1[1] + red1[2] + red1[3]) * (1.f / 512.f);

    float d0 = a0 - mean, d1 = a1 - mean;
    float q = d0 * d0 + d1 * d1;
#pragma unroll
    for (int m = 32; m; m >>= 1) q += __shfl_xor(q, m, 64);
    if (lane == 0) red2[w] = q;
    __syncthreads();
    float var  = (red2[0] + red2[1] + red2[2] + red2[3]) * (1.f / 512.f);
    float rstd = rsqrtf(var + 1e-5f);

    float r0 = d0 * rstd * g[t]       + bb[t];
    float r1 = d1 * rstd * g[t + 256] + bb[t + 256];
    xo[t] = r0; xo[t + 256] = r1;
    hh[t] = f2bf(r0);
    hh[t + 256] = f2bf(r1);
}

// ---------------------------------------------------------------------------
extern "C" void kernel_launch(void* const* d_in, const int* in_sizes, int n_in,
                              void* d_out, int out_size, void* d_ws, size_t ws_size,
                              hipStream_t stream)
{
    const int*   tokens = (const int*)  d_in[0];
    const float* enc    = (const float*)d_in[1];
    const float* emb    = (const float*)d_in[3];
    const float* Wqkvo  = (const float*)d_in[4];   // [L,2,4,D,D]
    const float* bqkvo  = (const float*)d_in[5];   // [L,2,4,D]
    const float* W1     = (const float*)d_in[6];   // [L,D,DFF]
    const float* b1     = (const float*)d_in[7];
    const float* W2     = (const float*)d_in[8];   // [L,DFF,D]
    const float* b2     = (const float*)d_in[9];
    const float* lng    = (const float*)d_in[10];  // [L,3,D]
    const float* lnb    = (const float*)d_in[11];
    const float* Wout   = (const float*)d_in[12];  // [D,V]
    const float* bout   = (const float*)d_in[13];

    float* out    = (float*)d_out;
    float* selfA  = out + 65536000L;
    float* crossA = selfA + 67108864L;

    // workspace carve
    char* p = (char*)d_ws;
    auto carve = [&](size_t bytes) { char* r = p; p += (bytes + 255) & ~255UL; return r; };
    float* x      = (float*)carve(1048576L * 4);
    short* xh     = (short*)carve(1048576L * 2);
    short* ench   = (short*)carve(1048576L * 2);
    short* qh     = (short*)carve(2097152L * 2);   // head-major Q|K hi
    short* ql     = (short*)carve(2097152L * 2);   // head-major Q|K lo
    short* vth    = (short*)carve(1048576L * 2);   // transposed V hi
    short* oh     = (short*)carve(1048576L * 2);
    short* t1h    = (short*)carve(4194304L * 2);   // FFN1 out hi
    float* part   = (float*)carve(4L * PSLAB * 4); // 4 K-split slabs
    short* WTLh   = (short*)carve(4194304L * 2);   // per-layer weights T hi
    short* WTh    = (short*)carve(8192000L * 2);   // vocab chunk WT hi

    const long PW = 262144L;    // 512*512
    const long HS = 1048576L;   // per attention operand slab

    embed_pe_kernel<<<4096, 256, 0, stream>>>(tokens, emb, x, xh);
    cvt_kernel<<<1024, 256, 0, stream>>>(enc, ench);

    for (int l = 0; l < NLAYER; ++l) {
        const float* bl = bqkvo + (long)l * 4096L;
        const float* bc = bl + 2048;
        const float* g  = lng + (long)l * 3 * 512;
        const float* bb = lnb + (long)l * 3 * 512;

        wtrans_layer_kernel<<<1024, 256, 0, stream>>>(Wqkvo, W1, W2, l, WTLh);

        // ---- self-attention (QKV one dispatch, A always xh) ----
        gemm_mfma_kernel<64,64,0,3><<<dim3(8, 32, 3), 256, 0, stream>>>(
            xh, xh, WTLh, bl, nullptr, qh, ql, vth,
            512, 512, 512, 0, PW, 512, HS, 0, /*scaledZ=*/0, /*vtZ=*/2,
            /*aSwitchZ=*/3);
        attn_fused_kernel<true><<<dim3(32, 16), 128, 0, stream>>>(
            qh, ql, qh + HS, ql + HS, vth,
            selfA + (long)l * 16777216L, oh);
        gemm_mfma_kernel<64,64,0,5><<<dim3(8, 32, 2), 256, 0, stream>>>(
            oh, nullptr, WTLh + 3*PW, nullptr, part, nullptr, nullptr, nullptr,
            256, 512, 512, 512, 0, 0, PSLAB, 256, -1, -1, 99);
        add_ln_kernel<2><<<MROWS, 256, 0, stream>>>(
            x, part, PSLAB, bl + 3*512, g, bb, x, xh);

        // ---- cross-attention (QKV merged: z0 Q from xh, z1 K / z2 V from enc)
        gemm_mfma_kernel<64,64,0,3><<<dim3(8, 32, 3), 256, 0, stream>>>(
            xh, ench, WTLh + 4*PW, bc, nullptr, qh, ql, vth,
            512, 512, 512, 0, PW, 512, HS, 0, /*scaledZ=*/0, /*vtZ=*/2,
            /*aSwitchZ=*/1);
        attn_fused_kernel<false><<<dim3(32, 16), 128, 0, stream>>>(
            qh, ql, qh + HS, ql + HS, vth,
            crossA + (long)l * 16777216L, oh);
        gemm_mfma_kernel<64,64,0,5><<<dim3(8, 32, 2), 256, 0, stream>>>(
            oh, nullptr, WTLh + 7*PW, nullptr, part, nullptr, nullptr, nullptr,
            256, 512, 512, 512, 0, 0, PSLAB, 256, -1, -1, 99);
        add_ln_kernel<2><<<MROWS, 256, 0, stream>>>(
            x, part, PSLAB, bc + 3*512, g + 512, bb + 512, x, xh);

        // ---- FFN ----
        gemm_mfma_kernel<64,64,1,2><<<dim3(32, 32, 1), 256, 0, stream>>>(
            xh, nullptr, WTLh + 2097152L, b1 + (long)l * 2048,
            nullptr, t1h, nullptr, nullptr,
            512, 512, 512, 2048, 0, 0, 0, 0, -1, -1, 99);
        gemm_mfma_kernel<64,64,0,5><<<dim3(8, 32, 4), 256, 0, stream>>>(
            t1h, nullptr, WTLh + 3145728L, nullptr, part,
            nullptr, nullptr, nullptr,
            512, 2048, 2048, 512, 0, 0, PSLAB, 512, -1, -1, 99);
        add_ln_kernel<4><<<MROWS, 256, 0, stream>>>(
            x, part, PSLAB, b2 + (long)l * 512, g + 1024, bb + 1024, x, xh);
    }

    // ---- final vocab projection, two 16000-wide chunks ----
    for (int c = 0; c < 2; ++c) {
        wtrans_kernel<<<dim3(250, 8, 1), 256, 0, stream>>>(
            Wout + c * 16000, WTh, 512, VOCAB);
        gemm_mfma_kernel<128,128,0,0><<<dim3(125, 16, 1), 256, 0, stream>>>(
            xh, nullptr, WTh, bout + c * 16000, out + c * 16000,
            nullptr, nullptr, nullptr,
            512, 512, 512, VOCAB, 0, 0, 0, 0, -1, -1, 99);
    }
}

// Round 18
// 902.635 us; speedup vs baseline: 1.1112x; 1.0995x over previous
//
#include <hip/hip_runtime.h>
#include <hip/hip_bf16.h>

// ---------------------------------------------------------------------------
// Transformer decoder, fp32 I/O. All matmuls pure bf16 1-product (GEMMs,
// QK, PV), fp32 accumulate. BK=32 2-phase dbuf GEMMs; fused attention with
// vectorized causal zero-fill; cross QKV merged via A-select.
// B=2, ST=SS=1024, D=512, H=8, DK=64, L=4, DFF=2048, V=32000.
// ---------------------------------------------------------------------------

#define D_MODEL 512
#define NHEAD   8
#define DKH     64
#define SEQ     1024
#define NLAYER  4
#define DFF_    2048
#define VOCAB   32000
#define BATCH   2
#define MROWS   (BATCH*SEQ)   // 2048
#define PSLAB   1048576L

typedef short bf16x8 __attribute__((ext_vector_type(8)));
typedef short short4v __attribute__((ext_vector_type(4)));
typedef float f32x4  __attribute__((ext_vector_type(4)));

static __device__ __forceinline__ short f2bf(float f) {
    __hip_bfloat16 h = __float2bfloat16(f);
    return *reinterpret_cast<short*>(&h);
}
static __device__ __forceinline__ float bf2f(short s) {
    __hip_bfloat16 h = *reinterpret_cast<__hip_bfloat16*>(&s);
    return __bfloat162float(h);
}
static __device__ __forceinline__ void gld16(const void* g, void* l) {
    __builtin_amdgcn_global_load_lds(
        (__attribute__((address_space(1))) void*)(void*)g,
        (__attribute__((address_space(3))) void*)l, 16, 0, 0);
}

// ---------------- embedding + positional encoding + hi ----------------------
__global__ __launch_bounds__(256) void embed_pe_kernel(
    const int* __restrict__ tokens, const float* __restrict__ emb,
    float* __restrict__ x, short* __restrict__ xh)
{
    long idx = (long)blockIdx.x * 256 + threadIdx.x;   // over 1,048,576
    int  d   = (int)(idx & (D_MODEL - 1));
    long row = idx >> 9;
    int  s   = (int)(row & (SEQ - 1));
    int  tok = tokens[row];
    float twoi = (float)((d >> 1) << 1);
    float div  = expf(twoi * (-9.210340371976184f / 512.0f));
    float arg  = (float)s * div;
    float pe   = (d & 1) ? cosf(arg) : sinf(arg);
    float v = emb[(long)tok * D_MODEL + d] * 22.62741699796952f + pe; // sqrt(512)
    x[idx] = v;
    xh[idx] = f2bf(v);
}

// ---------------- fp32 -> bf16 hi -------------------------------------------
__global__ __launch_bounds__(256) void cvt_kernel(
    const float* __restrict__ in, short* __restrict__ h)
{
    long e = ((long)blockIdx.x * 256 + threadIdx.x) * 4;
    float4 v = *(const float4*)&in[e];
    short4v hv;
    hv[0] = f2bf(v.x); hv[1] = f2bf(v.y); hv[2] = f2bf(v.z); hv[3] = f2bf(v.w);
    *(short4v*)&h[e] = hv;
}

// ---------------- weight transpose-convert: W[K,N] -> WT[N,K] hi ------------
__global__ __launch_bounds__(256) void wtrans_kernel(
    const float* __restrict__ W, short* __restrict__ Th,
    int K, int ldW)
{
    const int n0 = blockIdx.x * 64, k0 = blockIdx.y * 64;
    __shared__ float tile[64][65];
    const int t = threadIdx.x;
#pragma unroll
    for (int i = 0; i < 4; ++i) {
        int e = t + i * 256; int kk = e >> 4; int nn = (e & 15) * 4;
        float4 v = *(const float4*)&W[(long)(k0 + kk) * ldW + n0 + nn];
        tile[kk][nn] = v.x; tile[kk][nn + 1] = v.y;
        tile[kk][nn + 2] = v.z; tile[kk][nn + 3] = v.w;
    }
    __syncthreads();
    const int n = t >> 2, ks = (t & 3) * 16;
    short h8[16];
#pragma unroll
    for (int j = 0; j < 16; ++j) h8[j] = f2bf(tile[ks + j][n]);
    long base = (long)(n0 + n) * K + k0 + ks;
    *(bf16x8*)&Th[base]     = *(bf16x8*)&h8[0];
    *(bf16x8*)&Th[base + 8] = *(bf16x8*)&h8[8];
}

// ---------------- merged per-layer weight transpose (10 matrices, hi only) --
__global__ __launch_bounds__(256) void wtrans_layer_kernel(
    const float* __restrict__ Wqkvo, const float* __restrict__ W1,
    const float* __restrict__ W2, int l,
    short* __restrict__ Th)
{
    const int j = blockIdx.x;
    const float* W; int ldW, K; long dstOff; int n0, k0;
    if (j < 512) {
        int mat = j >> 6, tile_ = j & 63;
        W = Wqkvo + (long)l * 2097152L + (long)mat * 262144L;
        ldW = 512; K = 512; dstOff = (long)mat * 262144L;
        n0 = (tile_ & 7) * 64; k0 = (tile_ >> 3) * 64;
    } else if (j < 768) {
        int t2 = j - 512;
        W = W1 + (long)l * 1048576L; ldW = 2048; K = 512; dstOff = 2097152L;
        n0 = (t2 & 31) * 64; k0 = (t2 >> 5) * 64;
    } else {
        int t3 = j - 768;
        W = W2 + (long)l * 1048576L; ldW = 512; K = 2048; dstOff = 3145728L;
        n0 = (t3 & 7) * 64; k0 = (t3 >> 3) * 64;
    }
    __shared__ float tile[64][65];
    const int t = threadIdx.x;
#pragma unroll
    for (int i = 0; i < 4; ++i) {
        int e = t + i * 256; int kk = e >> 4; int nn = (e & 15) * 4;
        float4 v = *(const float4*)&W[(long)(k0 + kk) * ldW + n0 + nn];
        tile[kk][nn] = v.x; tile[kk][nn + 1] = v.y;
        tile[kk][nn + 2] = v.z; tile[kk][nn + 3] = v.w;
    }
    __syncthreads();
    const int n = t >> 2, ks = (t & 3) * 16;
    short h8[16];
#pragma unroll
    for (int j2 = 0; j2 < 16; ++j2) h8[j2] = f2bf(tile[ks + j2][n]);
    long base = dstOff + (long)(n0 + n) * K + k0 + ks;
    *(bf16x8*)&Th[base]     = *(bf16x8*)&h8[0];
    *(bf16x8*)&Th[base + 8] = *(bf16x8*)&h8[8];
}

// ---------------- 1-product MFMA GEMM, 2-phase dbuf (BK=32) -----------------
// A = (MODE==3 && z>=aSwitchZ) ? A2h : Ah.  K-window at z*kOff.
// MODE 0: fp32+bias. MODE 2: bf16 hi+bias(+relu). MODE 3: head-major attn
// operand hi w/ dk swizzle; z==scaledZ -> *0.125; z==vtZ -> transposed V hi.
// MODE 5: fp32 partial, no bias.
template<int BM, int BN, int ACT, int MODE>
__global__ __launch_bounds__(256) void gemm_mfma_kernel(
    const short* __restrict__ Ah, const short* __restrict__ A2h,
    const short* __restrict__ Bh,
    const float* __restrict__ bias, float* __restrict__ C,
    short* __restrict__ Ch, short* __restrict__ VTh,
    int Keff, int ldA, int ldB, int ldc,
    long zB, long zBias, long zC, int kOff, int scaledZ, int vtZ, int aSwitchZ)
{
    constexpr int MT_M = BM / 32;
    constexpr int MT_N = BN / 32;
    const long z = blockIdx.z;
    Bh += z * zB;
    if (MODE != 5) bias += z * zBias;

    const short* Au = (MODE == 3 && (int)z >= aSwitchZ) ? A2h : Ah;

    const int n0 = blockIdx.x * BN, m0 = blockIdx.y * BM;
    const int t = threadIdx.x;
    const int w = t >> 6, lane = t & 63;
    const int wm = w >> 1, wn = w & 1;
    const int lr = lane & 15, ks = lane >> 4;

    __shared__ short sAh[2][BM * 32];
    __shared__ short sBh[2][BN * 32];

    f32x4 acc[MT_M][MT_N];
#pragma unroll
    for (int i = 0; i < MT_M; ++i)
#pragma unroll
        for (int j = 0; j < MT_N; ++j) acc[i][j] = (f32x4){0.f, 0.f, 0.f, 0.f};

    const long rowA = ((long)m0 * ldA + (long)z * kOff) * 2;   // bytes
    const long rowB = ((long)n0 * ldB + (long)z * kOff) * 2;

    auto STAGE = [&](int buf, int k0) {
#pragma unroll
        for (int i = 0; i < BM / 64; ++i) {
            const int  L = i * 4096 + t * 16;
            const int  r = L >> 6, s = L & 63;
            const long gb = ((long)r * ldA + k0) * 2 + s;
            gld16((const char*)Au + rowA + gb, (char*)&sAh[buf][0] + L);
        }
#pragma unroll
        for (int i = 0; i < BN / 64; ++i) {
            const int  L = i * 4096 + t * 16;
            const int  r = L >> 6, s = L & 63;
            const long gb = ((long)r * ldB + k0) * 2 + s;
            gld16((const char*)Bh + rowB + gb, (char*)&sBh[buf][0] + L);
        }
    };
    auto COMPUTE = [&](int buf) {
        bf16x8 ah[MT_M], bh[MT_N];
#pragma unroll
        for (int mt = 0; mt < MT_M; ++mt) {
            int row = wm * (BM / 2) + mt * 16 + lr;
            ah[mt] = *(const bf16x8*)&sAh[buf][row * 32 + ks * 8];
        }
#pragma unroll
        for (int nt = 0; nt < MT_N; ++nt) {
            int col = wn * (BN / 2) + nt * 16 + lr;
            bh[nt] = *(const bf16x8*)&sBh[buf][col * 32 + ks * 8];
        }
#pragma unroll
        for (int mt = 0; mt < MT_M; ++mt)
#pragma unroll
            for (int nt = 0; nt < MT_N; ++nt)
                acc[mt][nt] = __builtin_amdgcn_mfma_f32_16x16x32_bf16(
                    ah[mt], bh[nt], acc[mt][nt], 0, 0, 0);
    };

    STAGE(0, 0);
    __syncthreads();
    int cur = 0;
    for (int k0 = 0; k0 < Keff; k0 += 32) {
        if (k0 + 32 < Keff) STAGE(cur ^ 1, k0 + 32);
        COMPUTE(cur);
        __syncthreads();
        cur ^= 1;
    }

    const int rq = lane >> 4, cq = lane & 15;
#pragma unroll
    for (int mt = 0; mt < MT_M; ++mt)
#pragma unroll
        for (int nt = 0; nt < MT_N; ++nt) {
            int gr0 = m0 + wm * (BM / 2) + mt * 16 + rq * 4;
            int gc  = n0 + wn * (BN / 2) + nt * 16 + cq;
            float vv[4];
            float bv = (MODE == 5) ? 0.f : bias[gc];
#pragma unroll
            for (int i = 0; i < 4; ++i) {
                float v = acc[mt][nt][i] + bv;
                if (ACT == 1) v = fmaxf(v, 0.f);
                vv[i] = v;
            }
            if (MODE == 0 || MODE == 5) {
#pragma unroll
                for (int i = 0; i < 4; ++i)
                    C[(long)(gr0 + i) * ldc + gc + z * zC] = vv[i];
            } else if (MODE == 2) {
#pragma unroll
                for (int i = 0; i < 4; ++i)
                    Ch[(long)(gr0 + i) * ldc + gc] = f2bf(vv[i]);
            } else {               // MODE 3
                if ((int)z == vtZ) {
                    int b = gr0 >> 10, s0 = gr0 & (SEQ - 1);
                    int hh2 = gc >> 6, dk = gc & 63;
                    int swz = (((dk >> 1) & 3) << 3) | (((dk >> 3) & 1) << 5);
                    long base = (((long)(b * NHEAD + hh2)) * 64 + dk) * 1024
                              + (long)(((s0 & ~7) ^ swz) | (s0 & 7));
                    short4v hv;
#pragma unroll
                    for (int i = 0; i < 4; ++i) hv[i] = f2bf(vv[i]);
                    *(short4v*)&VTh[base] = hv;
                } else {
                    float sc = ((int)z == scaledZ) ? 0.125f : 1.f;
#pragma unroll
                    for (int i = 0; i < 4; ++i) {
                        float v2 = vv[i] * sc;
                        int gr = gr0 + i;
                        int b = gr >> 10, s = gr & (SEQ - 1);
                        int hh2 = gc >> 6, dk = gc & 63;
                        int dks = dk ^ (((s >> 1) & 7) << 3);
                        long oidx = z * zC +
                            (((long)(b * NHEAD + hh2)) * SEQ + s) * 64 + dks;
                        Ch[oidx] = f2bf(v2);
                    }
                }
            }
        }
}

// ---------------- fused attention: 32 q-rows, 2 waves, 4 blocks/CU ----------
// QK and PV both 1-product bf16. LDS = 16+16+5 = 37 KB.
template<bool CAUSAL>
__global__ __launch_bounds__(128) void attn_fused_kernel(
    const short* __restrict__ Qh, const short* __restrict__ Kh,
    const short* __restrict__ VTh,
    float* __restrict__ attn, short* __restrict__ Oh)
{
    const int strip = blockIdx.x, bh = blockIdx.y;
    const int q0 = strip * 32;
    const int t = threadIdx.x, w = t >> 6, lane = t & 63;
    const int lr = lane & 15, ks = lane >> 4;
    const int rq = lane >> 4, cq = lane & 15;
    const int sxq = (lr >> 1) & 7;

    __shared__ short sKh[2][64*64];                  // 16 KB
    __shared__ short sVh[2][64*64];                  // 16 KB
    __shared__ short sPh[2][16*80];                  //  5 KB

    const int diag  = strip >> 1;
    const int ktmax = CAUSAL ? diag + 1 : 16;

    // Q stage (32 rows hi) via sKh[0]
    {
        const long qb = ((long)bh * SEQ + q0) * 128;
#pragma unroll
        for (int i2 = 0; i2 < 2; ++i2) {
            int L = i2 * 2048 + t * 16; int r = L >> 7, off = L & 127;
            gld16((const char*)Qh + qb + (long)r*128 + off, (char*)&sKh[0][0] + L);
        }
    }
    __syncthreads();
    bf16x8 qa[2];
#pragma unroll
    for (int k0 = 0; k0 < 2; ++k0) {
        int o = (w*16 + lr) * 64 + ((k0*32 + ks*8) ^ (sxq << 3));
        qa[k0] = *(const bf16x8*)&sKh[0][o];
    }
    __syncthreads();

    auto stageK = [&](int buf, int kt) {
        const long kb = ((long)bh * SEQ + kt*64) * 128;
#pragma unroll
        for (int i2 = 0; i2 < 4; ++i2) {
            int L = i2*2048 + t*16; int r = L >> 7, off = L & 127;
            gld16((const char*)Kh + kb + (long)r*128 + off, (char*)&sKh[buf][0] + L);
        }
    };
    auto stageV = [&](int buf, int kt) {
        const long vb = ((long)bh * 64) * 2048 + (long)kt * 128;
#pragma unroll
        for (int i2 = 0; i2 < 4; ++i2) {
            int L = i2*2048 + t*16; int r = L >> 7, off = L & 127;
            gld16((const char*)VTh + vb + (long)r*2048 + off, (char*)&sVh[buf][0] + L);
        }
    };
    auto scoresOf = [&](int buf, int kt, f32x4* sc) {
#pragma unroll
        for (int nt = 0; nt < 4; ++nt) sc[nt] = (f32x4){0.f, 0.f, 0.f, 0.f};
#pragma unroll
        for (int k0 = 0; k0 < 2; ++k0) {
            bf16x8 kh[4];
#pragma unroll
            for (int nt = 0; nt < 4; ++nt) {
                int o = (nt*16 + lr) * 64 + ((k0*32 + ks*8) ^ (sxq << 3));
                kh[nt] = *(const bf16x8*)&sKh[buf][o];
            }
#pragma unroll
            for (int nt = 0; nt < 4; ++nt)
                sc[nt] = __builtin_amdgcn_mfma_f32_16x16x32_bf16(
                    qa[k0], kh[nt], sc[nt], 0, 0, 0);
        }
        if (CAUSAL && kt == diag) {
            int row = q0 + w*16 + rq*4;
#pragma unroll
            for (int nt = 0; nt < 4; ++nt) {
                int col = kt*64 + nt*16 + cq;
#pragma unroll
                for (int i = 0; i < 4; ++i)
                    if (col > row + i) sc[nt][i] = -1e9f;
            }
        }
    };

    // ---- pass 1: online max + sum ----
    float m[4]   = {-3e38f, -3e38f, -3e38f, -3e38f};
    float sum[4] = {0.f, 0.f, 0.f, 0.f};
    int cur = 0;
    stageK(0, 0);
    __syncthreads();
    for (int kt = 0; kt < ktmax; ++kt) {
        if (kt + 1 < ktmax) stageK(cur ^ 1, kt + 1);
        f32x4 sc[4];
        scoresOf(cur, kt, sc);
#pragma unroll
        for (int i = 0; i < 4; ++i) {
            float tm = fmaxf(fmaxf(sc[0][i], sc[1][i]), fmaxf(sc[2][i], sc[3][i]));
#pragma unroll
            for (int d2 = 1; d2 <= 8; d2 <<= 1) tm = fmaxf(tm, __shfl_xor(tm, d2, 64));
            float mn = fmaxf(m[i], tm);
            float ps = __expf(sc[0][i] - mn) + __expf(sc[1][i] - mn)
                     + __expf(sc[2][i] - mn) + __expf(sc[3][i] - mn);
#pragma unroll
            for (int d2 = 1; d2 <= 8; d2 <<= 1) ps += __shfl_xor(ps, d2, 64);
            sum[i] = sum[i] * __expf(m[i] - mn) + ps;
            m[i] = mn;
        }
        __syncthreads();
        cur ^= 1;
    }
    float inv[4];
#pragma unroll
    for (int i = 0; i < 4; ++i) inv[i] = 1.f / sum[i];

    // ---- pass 2: recompute, probs out, PV (1-product) ----
    f32x4 acco[4];
#pragma unroll
    for (int nt = 0; nt < 4; ++nt) acco[nt] = (f32x4){0.f, 0.f, 0.f, 0.f};

    cur = 0;
    stageK(0, 0); stageV(0, 0);
    __syncthreads();
    for (int kt = 0; kt < ktmax; ++kt) {
        if (kt + 1 < ktmax) { stageK(cur ^ 1, kt + 1); stageV(cur ^ 1, kt + 1); }
        f32x4 sc[4];
        scoresOf(cur, kt, sc);
#pragma unroll
        for (int nt = 0; nt < 4; ++nt)
#pragma unroll
            for (int i = 0; i < 4; ++i) {
                float p = __expf(sc[nt][i] - m[i]) * inv[i];
                attn[((long)bh << 20) + ((long)(q0 + w*16 + rq*4 + i) << 10)
                     + kt*64 + nt*16 + cq] = p;
                sPh[w][(rq*4 + i)*80 + nt*16 + cq] = f2bf(p);
            }
#pragma unroll
        for (int k0 = 0; k0 < 2; ++k0) {
            bf16x8 pah = *(const bf16x8*)&sPh[w][lr*80 + k0*32 + ks*8];
#pragma unroll
            for (int nt = 0; nt < 4; ++nt) {
                int dk = nt*16 + lr;
                int swz = (((dk >> 1) & 3) << 3) | (((dk >> 3) & 1) << 5);
                int koff = (k0*32 + ks*8) ^ swz;
                bf16x8 vh8 = *(const bf16x8*)&sVh[cur][dk*64 + koff];
                acco[nt] = __builtin_amdgcn_mfma_f32_16x16x32_bf16(
                    pah, vh8, acco[nt], 0, 0, 0);
            }
        }
        __syncthreads();
        cur ^= 1;
    }

    // ---- causal masked region: vectorized zero fill ----
    if (CAUSAL && ktmax < 16) {
        const int r = t >> 2, g = (t & 3) * 4;
        const long rowbase = ((long)bh << 20) + ((long)(q0 + r) << 10);
        const float4 z4 = {0.f, 0.f, 0.f, 0.f};
        for (int c = ktmax * 64 + g; c < SEQ; c += 16)
            *(float4*)&attn[rowbase + c] = z4;
    }

    const int b = bh >> 3, hh_ = bh & 7;
#pragma unroll
    for (int nt = 0; nt < 4; ++nt)
#pragma unroll
        for (int i = 0; i < 4; ++i) {
            long oidx = ((long)(b * SEQ + q0 + w*16 + rq*4 + i)) * D_MODEL
                      + hh_*64 + nt*16 + cq;
            Oh[oidx] = f2bf(acco[nt][i]);
        }
}

// ---------------- residual + NS partial slabs + bias + LayerNorm + hi -------
template<int NS>
__global__ __launch_bounds__(256) void add_ln_kernel(
    const float* __restrict__ xin, const float* __restrict__ part, long PS,
    const float* __restrict__ bias,
    const float* __restrict__ g, const float* __restrict__ bb,
    float* __restrict__ xout, short* __restrict__ xh)
{
    long row = blockIdx.x;
    const float* xr = xin + row * D_MODEL;
    float*       xo = xout+ row * D_MODEL;
    short*       hh = xh  + row * D_MODEL;
    int t = threadIdx.x;

    float a0 = xr[t]       + bias[t];
    float a1 = xr[t + 256] + bias[t + 256];
#pragma unroll
    for (int s2 = 0; s2 < NS; ++s2) {
        a0 += part[s2 * PS + row * D_MODEL + t];
        a1 += part[s2 * PS + row * D_MODEL + t + 256];
    }

    float s = a0 + a1;
#pragma unroll
    for (int m = 32; m; m >>= 1) s += __shfl_xor(s, m, 64);
    __shared__ float red1[4];
    __shared__ float red2[4];
    int w = t >> 6, lane = t & 63;
    if (lane == 0) red1[w] = s;
    __syncthreads();
    float mean = (red1[0] + red1[1] + red1[2] + red1[3]) * (1.f / 512.f);

    float d0 = a0 - mean, d1 = a1 - mean;
    float q = d0 * d0 + d1 * d1;
#pragma unroll
    for (int m = 32; m; m >>= 1) q += __shfl_xor(q, m, 64);
    if (lane == 0) red2[w] = q;
    __syncthreads();
    float var  = (red2[0] + red2[1] + red2[2] + red2[3]) * (1.f / 512.f);
    float rstd = rsqrtf(var + 1e-5f);

    float r0 = d0 * rstd * g[t]       + bb[t];
    float r1 = d1 * rstd * g[t + 256] + bb[t + 256];
    xo[t] = r0; xo[t + 256] = r1;
    hh[t] = f2bf(r0);
    hh[t + 256] = f2bf(r1);
}

// ---------------------------------------------------------------------------
extern "C" void kernel_launch(void* const* d_in, const int* in_sizes, int n_in,
                              void* d_out, int out_size, void* d_ws, size_t ws_size,
                              hipStream_t stream)
{
    const int*   tokens = (const int*)  d_in[0];
    const float* enc    = (const float*)d_in[1];
    const float* emb    = (const float*)d_in[3];
    const float* Wqkvo  = (const float*)d_in[4];   // [L,2,4,D,D]
    const float* bqkvo  = (const float*)d_in[5];   // [L,2,4,D]
    const float* W1     = (const float*)d_in[6];   // [L,D,DFF]
    const float* b1     = (const float*)d_in[7];
    const float* W2     = (const float*)d_in[8];   // [L,DFF,D]
    const float* b2     = (const float*)d_in[9];
    const float* lng    = (const float*)d_in[10];  // [L,3,D]
    const float* lnb    = (const float*)d_in[11];
    const float* Wout   = (const float*)d_in[12];  // [D,V]
    const float* bout   = (const float*)d_in[13];

    float* out    = (float*)d_out;
    float* selfA  = out + 65536000L;
    float* crossA = selfA + 67108864L;

    // workspace carve
    char* p = (char*)d_ws;
    auto carve = [&](size_t bytes) { char* r = p; p += (bytes + 255) & ~255UL; return r; };
    float* x      = (float*)carve(1048576L * 4);
    short* xh     = (short*)carve(1048576L * 2);
    short* ench   = (short*)carve(1048576L * 2);
    short* qh     = (short*)carve(2097152L * 2);   // head-major Q|K hi
    short* vth    = (short*)carve(1048576L * 2);   // transposed V hi
    short* oh     = (short*)carve(1048576L * 2);
    short* t1h    = (short*)carve(4194304L * 2);   // FFN1 out hi
    float* part   = (float*)carve(4L * PSLAB * 4); // 4 K-split slabs
    short* WTLh   = (short*)carve(4194304L * 2);   // per-layer weights T hi
    short* WTh    = (short*)carve(8192000L * 2);   // vocab chunk WT hi

    const long PW = 262144L;    // 512*512
    const long HS = 1048576L;   // per attention operand slab

    embed_pe_kernel<<<4096, 256, 0, stream>>>(tokens, emb, x, xh);
    cvt_kernel<<<1024, 256, 0, stream>>>(enc, ench);

    for (int l = 0; l < NLAYER; ++l) {
        const float* bl = bqkvo + (long)l * 4096L;
        const float* bc = bl + 2048;
        const float* g  = lng + (long)l * 3 * 512;
        const float* bb = lnb + (long)l * 3 * 512;

        wtrans_layer_kernel<<<1024, 256, 0, stream>>>(Wqkvo, W1, W2, l, WTLh);

        // ---- self-attention (QKV one dispatch, A always xh) ----
        gemm_mfma_kernel<64,64,0,3><<<dim3(8, 32, 3), 256, 0, stream>>>(
            xh, xh, WTLh, bl, nullptr, qh, vth,
            512, 512, 512, 0, PW, 512, HS, 0, /*scaledZ=*/0, /*vtZ=*/2,
            /*aSwitchZ=*/3);
        attn_fused_kernel<true><<<dim3(32, 16), 128, 0, stream>>>(
            qh, qh + HS, vth, selfA + (long)l * 16777216L, oh);
        gemm_mfma_kernel<64,64,0,5><<<dim3(8, 32, 2), 256, 0, stream>>>(
            oh, nullptr, WTLh + 3*PW, nullptr, part, nullptr, nullptr,
            256, 512, 512, 512, 0, 0, PSLAB, 256, -1, -1, 99);
        add_ln_kernel<2><<<MROWS, 256, 0, stream>>>(
            x, part, PSLAB, bl + 3*512, g, bb, x, xh);

        // ---- cross-attention (QKV merged: z0 Q from xh, z1 K / z2 V from enc)
        gemm_mfma_kernel<64,64,0,3><<<dim3(8, 32, 3), 256, 0, stream>>>(
            xh, ench, WTLh + 4*PW, bc, nullptr, qh, vth,
            512, 512, 512, 0, PW, 512, HS, 0, /*scaledZ=*/0, /*vtZ=*/2,
            /*aSwitchZ=*/1);
        attn_fused_kernel<false><<<dim3(32, 16), 128, 0, stream>>>(
            qh, qh + HS, vth, crossA + (long)l * 16777216L, oh);
        gemm_mfma_kernel<64,64,0,5><<<dim3(8, 32, 2), 256, 0, stream>>>(
            oh, nullptr, WTLh + 7*PW, nullptr, part, nullptr, nullptr,
            256, 512, 512, 512, 0, 0, PSLAB, 256, -1, -1, 99);
        add_ln_kernel<2><<<MROWS, 256, 0, stream>>>(
            x, part, PSLAB, bc + 3*512, g + 512, bb + 512, x, xh);

        // ---- FFN ----
        gemm_mfma_kernel<64,64,1,2><<<dim3(32, 32, 1), 256, 0, stream>>>(
            xh, nullptr, WTLh + 2097152L, b1 + (long)l * 2048,
            nullptr, t1h, nullptr,
            512, 512, 512, 2048, 0, 0, 0, 0, -1, -1, 99);
        gemm_mfma_kernel<64,64,0,5><<<dim3(8, 32, 4), 256, 0, stream>>>(
            t1h, nullptr, WTLh + 3145728L, nullptr, part,
            nullptr, nullptr,
            512, 2048, 2048, 512, 0, 0, PSLAB, 512, -1, -1, 99);
        add_ln_kernel<4><<<MROWS, 256, 0, stream>>>(
            x, part, PSLAB, b2 + (long)l * 512, g + 1024, bb + 1024, x, xh);
    }

    // ---- final vocab projection, two 16000-wide chunks ----
    for (int c = 0; c < 2; ++c) {
        wtrans_kernel<<<dim3(250, 8, 1), 256, 0, stream>>>(
            Wout + c * 16000, WTh, 512, VOCAB);
        gemm_mfma_kernel<128,128,0,0><<<dim3(125, 16, 1), 256, 0, stream>>>(
            xh, nullptr, WTh, bout + c * 16000, out + c * 16000,
            nullptr, nullptr,
            512, 512, 512, VOCAB, 0, 0, 0, 0, -1, -1, 99);
    }
}

// Round 19
// 889.761 us; speedup vs baseline: 1.1273x; 1.0145x over previous
//
#include <hip/hip_runtime.h>
#include <hip/hip_bf16.h>

// ---------------------------------------------------------------------------
// Transformer decoder, fp32 I/O. All matmuls pure bf16 1-product, fp32 acc.
// BK=32 2-phase dbuf GEMMs; fused 2-pass attention (probs are outputs);
// cross QKV merged via A-select; single full-width vocab wtrans+GEMM.
// B=2, ST=SS=1024, D=512, H=8, DK=64, L=4, DFF=2048, V=32000.
// ---------------------------------------------------------------------------

#define D_MODEL 512
#define NHEAD   8
#define DKH     64
#define SEQ     1024
#define NLAYER  4
#define DFF_    2048
#define VOCAB   32000
#define BATCH   2
#define MROWS   (BATCH*SEQ)   // 2048
#define PSLAB   1048576L

typedef short bf16x8 __attribute__((ext_vector_type(8)));
typedef short short4v __attribute__((ext_vector_type(4)));
typedef float f32x4  __attribute__((ext_vector_type(4)));

static __device__ __forceinline__ short f2bf(float f) {
    __hip_bfloat16 h = __float2bfloat16(f);
    return *reinterpret_cast<short*>(&h);
}
static __device__ __forceinline__ float bf2f(short s) {
    __hip_bfloat16 h = *reinterpret_cast<__hip_bfloat16*>(&s);
    return __bfloat162float(h);
}
static __device__ __forceinline__ void gld16(const void* g, void* l) {
    __builtin_amdgcn_global_load_lds(
        (__attribute__((address_space(1))) void*)(void*)g,
        (__attribute__((address_space(3))) void*)l, 16, 0, 0);
}

// ---------------- embedding+PE (blocks 0..4095) | enc cvt (4096..5119) ------
__global__ __launch_bounds__(256) void embed_cvt_kernel(
    const int* __restrict__ tokens, const float* __restrict__ emb,
    float* __restrict__ x, short* __restrict__ xh,
    const float* __restrict__ enc, short* __restrict__ ench)
{
    if (blockIdx.x < 4096) {
        long idx = (long)blockIdx.x * 256 + threadIdx.x;   // over 1,048,576
        int  d   = (int)(idx & (D_MODEL - 1));
        long row = idx >> 9;
        int  s   = (int)(row & (SEQ - 1));
        int  tok = tokens[row];
        float twoi = (float)((d >> 1) << 1);
        float div  = expf(twoi * (-9.210340371976184f / 512.0f));
        float arg  = (float)s * div;
        float pe   = (d & 1) ? cosf(arg) : sinf(arg);
        float v = emb[(long)tok * D_MODEL + d] * 22.62741699796952f + pe;
        x[idx] = v;
        xh[idx] = f2bf(v);
    } else {
        long e = ((long)(blockIdx.x - 4096) * 256 + threadIdx.x) * 4;
        float4 v = *(const float4*)&enc[e];
        short4v hv;
        hv[0] = f2bf(v.x); hv[1] = f2bf(v.y);
        hv[2] = f2bf(v.z); hv[3] = f2bf(v.w);
        *(short4v*)&ench[e] = hv;
    }
}

// ---------------- weight transpose-convert: W[K,N] -> WT[N,K] hi ------------
__global__ __launch_bounds__(256) void wtrans_kernel(
    const float* __restrict__ W, short* __restrict__ Th,
    int K, int ldW)
{
    const int n0 = blockIdx.x * 64, k0 = blockIdx.y * 64;
    __shared__ float tile[64][65];
    const int t = threadIdx.x;
#pragma unroll
    for (int i = 0; i < 4; ++i) {
        int e = t + i * 256; int kk = e >> 4; int nn = (e & 15) * 4;
        float4 v = *(const float4*)&W[(long)(k0 + kk) * ldW + n0 + nn];
        tile[kk][nn] = v.x; tile[kk][nn + 1] = v.y;
        tile[kk][nn + 2] = v.z; tile[kk][nn + 3] = v.w;
    }
    __syncthreads();
    const int n = t >> 2, ks = (t & 3) * 16;
    short h8[16];
#pragma unroll
    for (int j = 0; j < 16; ++j) h8[j] = f2bf(tile[ks + j][n]);
    long base = (long)(n0 + n) * K + k0 + ks;
    *(bf16x8*)&Th[base]     = *(bf16x8*)&h8[0];
    *(bf16x8*)&Th[base + 8] = *(bf16x8*)&h8[8];
}

// ---------------- merged per-layer weight transpose (10 matrices, hi only) --
__global__ __launch_bounds__(256) void wtrans_layer_kernel(
    const float* __restrict__ Wqkvo, const float* __restrict__ W1,
    const float* __restrict__ W2, int l,
    short* __restrict__ Th)
{
    const int j = blockIdx.x;
    const float* W; int ldW, K; long dstOff; int n0, k0;
    if (j < 512) {
        int mat = j >> 6, tile_ = j & 63;
        W = Wqkvo + (long)l * 2097152L + (long)mat * 262144L;
        ldW = 512; K = 512; dstOff = (long)mat * 262144L;
        n0 = (tile_ & 7) * 64; k0 = (tile_ >> 3) * 64;
    } else if (j < 768) {
        int t2 = j - 512;
        W = W1 + (long)l * 1048576L; ldW = 2048; K = 512; dstOff = 2097152L;
        n0 = (t2 & 31) * 64; k0 = (t2 >> 5) * 64;
    } else {
        int t3 = j - 768;
        W = W2 + (long)l * 1048576L; ldW = 512; K = 2048; dstOff = 3145728L;
        n0 = (t3 & 7) * 64; k0 = (t3 >> 3) * 64;
    }
    __shared__ float tile[64][65];
    const int t = threadIdx.x;
#pragma unroll
    for (int i = 0; i < 4; ++i) {
        int e = t + i * 256; int kk = e >> 4; int nn = (e & 15) * 4;
        float4 v = *(const float4*)&W[(long)(k0 + kk) * ldW + n0 + nn];
        tile[kk][nn] = v.x; tile[kk][nn + 1] = v.y;
        tile[kk][nn + 2] = v.z; tile[kk][nn + 3] = v.w;
    }
    __syncthreads();
    const int n = t >> 2, ks = (t & 3) * 16;
    short h8[16];
#pragma unroll
    for (int j2 = 0; j2 < 16; ++j2) h8[j2] = f2bf(tile[ks + j2][n]);
    long base = dstOff + (long)(n0 + n) * K + k0 + ks;
    *(bf16x8*)&Th[base]     = *(bf16x8*)&h8[0];
    *(bf16x8*)&Th[base + 8] = *(bf16x8*)&h8[8];
}

// ---------------- 1-product MFMA GEMM, 2-phase dbuf (BK=32) -----------------
// A = (MODE==3 && z>=aSwitchZ) ? A2h : Ah.  K-window at z*kOff.
// MODE 0: fp32+bias. MODE 2: bf16 hi+bias(+relu). MODE 3: head-major attn
// operand hi w/ dk swizzle; z==scaledZ -> *0.125; z==vtZ -> transposed V hi.
// MODE 5: fp32 partial, no bias.
template<int BM, int BN, int ACT, int MODE>
__global__ __launch_bounds__(256) void gemm_mfma_kernel(
    const short* __restrict__ Ah, const short* __restrict__ A2h,
    const short* __restrict__ Bh,
    const float* __restrict__ bias, float* __restrict__ C,
    short* __restrict__ Ch, short* __restrict__ VTh,
    int Keff, int ldA, int ldB, int ldc,
    long zB, long zBias, long zC, int kOff, int scaledZ, int vtZ, int aSwitchZ)
{
    constexpr int MT_M = BM / 32;
    constexpr int MT_N = BN / 32;
    const long z = blockIdx.z;
    Bh += z * zB;
    if (MODE != 5) bias += z * zBias;

    const short* Au = (MODE == 3 && (int)z >= aSwitchZ) ? A2h : Ah;

    const int n0 = blockIdx.x * BN, m0 = blockIdx.y * BM;
    const int t = threadIdx.x;
    const int w = t >> 6, lane = t & 63;
    const int wm = w >> 1, wn = w & 1;
    const int lr = lane & 15, ks = lane >> 4;

    __shared__ short sAh[2][BM * 32];
    __shared__ short sBh[2][BN * 32];

    f32x4 acc[MT_M][MT_N];
#pragma unroll
    for (int i = 0; i < MT_M; ++i)
#pragma unroll
        for (int j = 0; j < MT_N; ++j) acc[i][j] = (f32x4){0.f, 0.f, 0.f, 0.f};

    const long rowA = ((long)m0 * ldA + (long)z * kOff) * 2;   // bytes
    const long rowB = ((long)n0 * ldB + (long)z * kOff) * 2;

    auto STAGE = [&](int buf, int k0) {
#pragma unroll
        for (int i = 0; i < BM / 64; ++i) {
            const int  L = i * 4096 + t * 16;
            const int  r = L >> 6, s = L & 63;
            const long gb = ((long)r * ldA + k0) * 2 + s;
            gld16((const char*)Au + rowA + gb, (char*)&sAh[buf][0] + L);
        }
#pragma unroll
        for (int i = 0; i < BN / 64; ++i) {
            const int  L = i * 4096 + t * 16;
            const int  r = L >> 6, s = L & 63;
            const long gb = ((long)r * ldB + k0) * 2 + s;
            gld16((const char*)Bh + rowB + gb, (char*)&sBh[buf][0] + L);
        }
    };
    auto COMPUTE = [&](int buf) {
        bf16x8 ah[MT_M], bh[MT_N];
#pragma unroll
        for (int mt = 0; mt < MT_M; ++mt) {
            int row = wm * (BM / 2) + mt * 16 + lr;
            ah[mt] = *(const bf16x8*)&sAh[buf][row * 32 + ks * 8];
        }
#pragma unroll
        for (int nt = 0; nt < MT_N; ++nt) {
            int col = wn * (BN / 2) + nt * 16 + lr;
            bh[nt] = *(const bf16x8*)&sBh[buf][col * 32 + ks * 8];
        }
#pragma unroll
        for (int mt = 0; mt < MT_M; ++mt)
#pragma unroll
            for (int nt = 0; nt < MT_N; ++nt)
                acc[mt][nt] = __builtin_amdgcn_mfma_f32_16x16x32_bf16(
                    ah[mt], bh[nt], acc[mt][nt], 0, 0, 0);
    };

    STAGE(0, 0);
    __syncthreads();
    int cur = 0;
    for (int k0 = 0; k0 < Keff; k0 += 32) {
        if (k0 + 32 < Keff) STAGE(cur ^ 1, k0 + 32);
        COMPUTE(cur);
        __syncthreads();
        cur ^= 1;
    }

    const int rq = lane >> 4, cq = lane & 15;
#pragma unroll
    for (int mt = 0; mt < MT_M; ++mt)
#pragma unroll
        for (int nt = 0; nt < MT_N; ++nt) {
            int gr0 = m0 + wm * (BM / 2) + mt * 16 + rq * 4;
            int gc  = n0 + wn * (BN / 2) + nt * 16 + cq;
            float vv[4];
            float bv = (MODE == 5) ? 0.f : bias[gc];
#pragma unroll
            for (int i = 0; i < 4; ++i) {
                float v = acc[mt][nt][i] + bv;
                if (ACT == 1) v = fmaxf(v, 0.f);
                vv[i] = v;
            }
            if (MODE == 0 || MODE == 5) {
#pragma unroll
                for (int i = 0; i < 4; ++i)
                    C[(long)(gr0 + i) * ldc + gc + z * zC] = vv[i];
            } else if (MODE == 2) {
#pragma unroll
                for (int i = 0; i < 4; ++i)
                    Ch[(long)(gr0 + i) * ldc + gc] = f2bf(vv[i]);
            } else {               // MODE 3
                if ((int)z == vtZ) {
                    int b = gr0 >> 10, s0 = gr0 & (SEQ - 1);
                    int hh2 = gc >> 6, dk = gc & 63;
                    int swz = (((dk >> 1) & 3) << 3) | (((dk >> 3) & 1) << 5);
                    long base = (((long)(b * NHEAD + hh2)) * 64 + dk) * 1024
                              + (long)(((s0 & ~7) ^ swz) | (s0 & 7));
                    short4v hv;
#pragma unroll
                    for (int i = 0; i < 4; ++i) hv[i] = f2bf(vv[i]);
                    *(short4v*)&VTh[base] = hv;
                } else {
                    float sc = ((int)z == scaledZ) ? 0.125f : 1.f;
#pragma unroll
                    for (int i = 0; i < 4; ++i) {
                        float v2 = vv[i] * sc;
                        int gr = gr0 + i;
                        int b = gr >> 10, s = gr & (SEQ - 1);
                        int hh2 = gc >> 6, dk = gc & 63;
                        int dks = dk ^ (((s >> 1) & 7) << 3);
                        long oidx = z * zC +
                            (((long)(b * NHEAD + hh2)) * SEQ + s) * 64 + dks;
                        Ch[oidx] = f2bf(v2);
                    }
                }
            }
        }
}

// ---------------- fused attention: 32 q-rows, 2 waves, 4 blocks/CU ----------
// QK and PV both 1-product bf16. LDS = 16+16+5 = 37 KB.
template<bool CAUSAL>
__global__ __launch_bounds__(128) void attn_fused_kernel(
    const short* __restrict__ Qh, const short* __restrict__ Kh,
    const short* __restrict__ VTh,
    float* __restrict__ attn, short* __restrict__ Oh)
{
    const int strip = blockIdx.x, bh = blockIdx.y;
    const int q0 = strip * 32;
    const int t = threadIdx.x, w = t >> 6, lane = t & 63;
    const int lr = lane & 15, ks = lane >> 4;
    const int rq = lane >> 4, cq = lane & 15;
    const int sxq = (lr >> 1) & 7;

    __shared__ short sKh[2][64*64];                  // 16 KB
    __shared__ short sVh[2][64*64];                  // 16 KB
    __shared__ short sPh[2][16*80];                  //  5 KB

    const int diag  = strip >> 1;
    const int ktmax = CAUSAL ? diag + 1 : 16;

    // Q stage (32 rows hi) via sKh[0]
    {
        const long qb = ((long)bh * SEQ + q0) * 128;
#pragma unroll
        for (int i2 = 0; i2 < 2; ++i2) {
            int L = i2 * 2048 + t * 16; int r = L >> 7, off = L & 127;
            gld16((const char*)Qh + qb + (long)r*128 + off, (char*)&sKh[0][0] + L);
        }
    }
    __syncthreads();
    bf16x8 qa[2];
#pragma unroll
    for (int k0 = 0; k0 < 2; ++k0) {
        int o = (w*16 + lr) * 64 + ((k0*32 + ks*8) ^ (sxq << 3));
        qa[k0] = *(const bf16x8*)&sKh[0][o];
    }
    __syncthreads();

    auto stageK = [&](int buf, int kt) {
        const long kb = ((long)bh * SEQ + kt*64) * 128;
#pragma unroll
        for (int i2 = 0; i2 < 4; ++i2) {
            int L = i2*2048 + t*16; int r = L >> 7, off = L & 127;
            gld16((const char*)Kh + kb + (long)r*128 + off, (char*)&sKh[buf][0] + L);
        }
    };
    auto stageV = [&](int buf, int kt) {
        const long vb = ((long)bh * 64) * 2048 + (long)kt * 128;
#pragma unroll
        for (int i2 = 0; i2 < 4; ++i2) {
            int L = i2*2048 + t*16; int r = L >> 7, off = L & 127;
            gld16((const char*)VTh + vb + (long)r*2048 + off, (char*)&sVh[buf][0] + L);
        }
    };
    auto scoresOf = [&](int buf, int kt, f32x4* sc) {
#pragma unroll
        for (int nt = 0; nt < 4; ++nt) sc[nt] = (f32x4){0.f, 0.f, 0.f, 0.f};
#pragma unroll
        for (int k0 = 0; k0 < 2; ++k0) {
            bf16x8 kh[4];
#pragma unroll
            for (int nt = 0; nt < 4; ++nt) {
                int o = (nt*16 + lr) * 64 + ((k0*32 + ks*8) ^ (sxq << 3));
                kh[nt] = *(const bf16x8*)&sKh[buf][o];
            }
#pragma unroll
            for (int nt = 0; nt < 4; ++nt)
                sc[nt] = __builtin_amdgcn_mfma_f32_16x16x32_bf16(
                    qa[k0], kh[nt], sc[nt], 0, 0, 0);
        }
        if (CAUSAL && kt == diag) {
            int row = q0 + w*16 + rq*4;
#pragma unroll
            for (int nt = 0; nt < 4; ++nt) {
                int col = kt*64 + nt*16 + cq;
#pragma unroll
                for (int i = 0; i < 4; ++i)
                    if (col > row + i) sc[nt][i] = -1e9f;
            }
        }
    };

    // ---- pass 1: online max + sum ----
    float m[4]   = {-3e38f, -3e38f, -3e38f, -3e38f};
    float sum[4] = {0.f, 0.f, 0.f, 0.f};
    int cur = 0;
    stageK(0, 0);
    __syncthreads();
    for (int kt = 0; kt < ktmax; ++kt) {
        if (kt + 1 < ktmax) stageK(cur ^ 1, kt + 1);
        f32x4 sc[4];
        scoresOf(cur, kt, sc);
#pragma unroll
        for (int i = 0; i < 4; ++i) {
            float tm = fmaxf(fmaxf(sc[0][i], sc[1][i]), fmaxf(sc[2][i], sc[3][i]));
#pragma unroll
            for (int d2 = 1; d2 <= 8; d2 <<= 1) tm = fmaxf(tm, __shfl_xor(tm, d2, 64));
            float mn = fmaxf(m[i], tm);
            float ps = __expf(sc[0][i] - mn) + __expf(sc[1][i] - mn)
                     + __expf(sc[2][i] - mn) + __expf(sc[3][i] - mn);
#pragma unroll
            for (int d2 = 1; d2 <= 8; d2 <<= 1) ps += __shfl_xor(ps, d2, 64);
            sum[i] = sum[i] * __expf(m[i] - mn) + ps;
            m[i] = mn;
        }
        __syncthreads();
        cur ^= 1;
    }
    float inv[4];
#pragma unroll
    for (int i = 0; i < 4; ++i) inv[i] = 1.f / sum[i];

    // ---- pass 2: recompute, probs out, PV (1-product) ----
    f32x4 acco[4];
#pragma unroll
    for (int nt = 0; nt < 4; ++nt) acco[nt] = (f32x4){0.f, 0.f, 0.f, 0.f};

    cur = 0;
    stageK(0, 0); stageV(0, 0);
    __syncthreads();
    for (int kt = 0; kt < ktmax; ++kt) {
        if (kt + 1 < ktmax) { stageK(cur ^ 1, kt + 1); stageV(cur ^ 1, kt + 1); }
        f32x4 sc[4];
        scoresOf(cur, kt, sc);
#pragma unroll
        for (int nt = 0; nt < 4; ++nt)
#pragma unroll
            for (int i = 0; i < 4; ++i) {
                float p = __expf(sc[nt][i] - m[i]) * inv[i];
                attn[((long)bh << 20) + ((long)(q0 + w*16 + rq*4 + i) << 10)
                     + kt*64 + nt*16 + cq] = p;
                sPh[w][(rq*4 + i)*80 + nt*16 + cq] = f2bf(p);
            }
#pragma unroll
        for (int k0 = 0; k0 < 2; ++k0) {
            bf16x8 pah = *(const bf16x8*)&sPh[w][lr*80 + k0*32 + ks*8];
#pragma unroll
            for (int nt = 0; nt < 4; ++nt) {
                int dk = nt*16 + lr;
                int swz = (((dk >> 1) & 3) << 3) | (((dk >> 3) & 1) << 5);
                int koff = (k0*32 + ks*8) ^ swz;
                bf16x8 vh8 = *(const bf16x8*)&sVh[cur][dk*64 + koff];
                acco[nt] = __builtin_amdgcn_mfma_f32_16x16x32_bf16(
                    pah, vh8, acco[nt], 0, 0, 0);
            }
        }
        __syncthreads();
        cur ^= 1;
    }

    // ---- causal masked region: vectorized zero fill ----
    if (CAUSAL && ktmax < 16) {
        const int r = t >> 2, g = (t & 3) * 4;
        const long rowbase = ((long)bh << 20) + ((long)(q0 + r) << 10);
        const float4 z4 = {0.f, 0.f, 0.f, 0.f};
        for (int c = ktmax * 64 + g; c < SEQ; c += 16)
            *(float4*)&attn[rowbase + c] = z4;
    }

    const int b = bh >> 3, hh_ = bh & 7;
#pragma unroll
    for (int nt = 0; nt < 4; ++nt)
#pragma unroll
        for (int i = 0; i < 4; ++i) {
            long oidx = ((long)(b * SEQ + q0 + w*16 + rq*4 + i)) * D_MODEL
                      + hh_*64 + nt*16 + cq;
            Oh[oidx] = f2bf(acco[nt][i]);
        }
}

// ---------------- residual + NS partial slabs + bias + LayerNorm + hi -------
template<int NS>
__global__ __launch_bounds__(256) void add_ln_kernel(
    const float* __restrict__ xin, const float* __restrict__ part, long PS,
    const float* __restrict__ bias,
    const float* __restrict__ g, const float* __restrict__ bb,
    float* __restrict__ xout, short* __restrict__ xh)
{
    long row = blockIdx.x;
    const float* xr = xin + row * D_MODEL;
    float*       xo = xout+ row * D_MODEL;
    short*       hh = xh  + row * D_MODEL;
    int t = threadIdx.x;

    float a0 = xr[t]       + bias[t];
    float a1 = xr[t + 256] + bias[t + 256];
#pragma unroll
    for (int s2 = 0; s2 < NS; ++s2) {
        a0 += part[s2 * PS + row * D_MODEL + t];
        a1 += part[s2 * PS + row * D_MODEL + t + 256];
    }

    float s = a0 + a1;
#pragma unroll
    for (int m = 32; m; m >>= 1) s += __shfl_xor(s, m, 64);
    __shared__ float red1[4];
    __shared__ float red2[4];
    int w = t >> 6, lane = t & 63;
    if (lane == 0) red1[w] = s;
    __syncthreads();
    float mean = (red1[0] + red1[1] + red1[2] + red1[3]) * (1.f / 512.f);

    float d0 = a0 - mean, d1 = a1 - mean;
    float q = d0 * d0 + d1 * d1;
#pragma unroll
    for (int m = 32; m; m >>= 1) q += __shfl_xor(q, m, 64);
    if (lane == 0) red2[w] = q;
    __syncthreads();
    float var  = (red2[0] + red2[1] + red2[2] + red2[3]) * (1.f / 512.f);
    float rstd = rsqrtf(var + 1e-5f);

    float r0 = d0 * rstd * g[t]       + bb[t];
    float r1 = d1 * rstd * g[t + 256] + bb[t + 256];
    xo[t] = r0; xo[t + 256] = r1;
    hh[t] = f2bf(r0);
    hh[t + 256] = f2bf(r1);
}

// ---------------------------------------------------------------------------
extern "C" void kernel_launch(void* const* d_in, const int* in_sizes, int n_in,
                              void* d_out, int out_size, void* d_ws, size_t ws_size,
                              hipStream_t stream)
{
    const int*   tokens = (const int*)  d_in[0];
    const float* enc    = (const float*)d_in[1];
    const float* emb    = (const float*)d_in[3];
    const float* Wqkvo  = (const float*)d_in[4];   // [L,2,4,D,D]
    const float* bqkvo  = (const float*)d_in[5];   // [L,2,4,D]
    const float* W1     = (const float*)d_in[6];   // [L,D,DFF]
    const float* b1     = (const float*)d_in[7];
    const float* W2     = (const float*)d_in[8];   // [L,DFF,D]
    const float* b2     = (const float*)d_in[9];
    const float* lng    = (const float*)d_in[10];  // [L,3,D]
    const float* lnb    = (const float*)d_in[11];
    const float* Wout   = (const float*)d_in[12];  // [D,V]
    const float* bout   = (const float*)d_in[13];

    float* out    = (float*)d_out;
    float* selfA  = out + 65536000L;
    float* crossA = selfA + 67108864L;

    // workspace carve (~90 MB)
    char* p = (char*)d_ws;
    auto carve = [&](size_t bytes) { char* r = p; p += (bytes + 255) & ~255UL; return r; };
    float* x      = (float*)carve(1048576L * 4);
    short* xh     = (short*)carve(1048576L * 2);
    short* ench   = (short*)carve(1048576L * 2);
    short* qh     = (short*)carve(2097152L * 2);   // head-major Q|K hi
    short* vth    = (short*)carve(1048576L * 2);   // transposed V hi
    short* oh     = (short*)carve(1048576L * 2);
    short* t1h    = (short*)carve(4194304L * 2);   // FFN1 out hi
    float* part   = (float*)carve(4L * PSLAB * 4); // 4 K-split slabs
    short* WTLh   = (short*)carve(4194304L * 2);   // per-layer weights T hi
    short* WTh    = (short*)carve(16384000L * 2);  // full vocab WT hi (32.8 MB)

    const long PW = 262144L;    // 512*512
    const long HS = 1048576L;   // per attention operand slab

    embed_cvt_kernel<<<5120, 256, 0, stream>>>(tokens, emb, x, xh, enc, ench);

    for (int l = 0; l < NLAYER; ++l) {
        const float* bl = bqkvo + (long)l * 4096L;
        const float* bc = bl + 2048;
        const float* g  = lng + (long)l * 3 * 512;
        const float* bb = lnb + (long)l * 3 * 512;

        wtrans_layer_kernel<<<1024, 256, 0, stream>>>(Wqkvo, W1, W2, l, WTLh);

        // ---- self-attention (QKV one dispatch, A always xh) ----
        gemm_mfma_kernel<64,64,0,3><<<dim3(8, 32, 3), 256, 0, stream>>>(
            xh, xh, WTLh, bl, nullptr, qh, vth,
            512, 512, 512, 0, PW, 512, HS, 0, /*scaledZ=*/0, /*vtZ=*/2,
            /*aSwitchZ=*/3);
        attn_fused_kernel<true><<<dim3(32, 16), 128, 0, stream>>>(
            qh, qh + HS, vth, selfA + (long)l * 16777216L, oh);
        gemm_mfma_kernel<64,64,0,5><<<dim3(8, 32, 2), 256, 0, stream>>>(
            oh, nullptr, WTLh + 3*PW, nullptr, part, nullptr, nullptr,
            256, 512, 512, 512, 0, 0, PSLAB, 256, -1, -1, 99);
        add_ln_kernel<2><<<MROWS, 256, 0, stream>>>(
            x, part, PSLAB, bl + 3*512, g, bb, x, xh);

        // ---- cross-attention (QKV merged: z0 Q from xh, z1 K / z2 V from enc)
        gemm_mfma_kernel<64,64,0,3><<<dim3(8, 32, 3), 256, 0, stream>>>(
            xh, ench, WTLh + 4*PW, bc, nullptr, qh, vth,
            512, 512, 512, 0, PW, 512, HS, 0, /*scaledZ=*/0, /*vtZ=*/2,
            /*aSwitchZ=*/1);
        attn_fused_kernel<false><<<dim3(32, 16), 128, 0, stream>>>(
            qh, qh + HS, vth, crossA + (long)l * 16777216L, oh);
        gemm_mfma_kernel<64,64,0,5><<<dim3(8, 32, 2), 256, 0, stream>>>(
            oh, nullptr, WTLh + 7*PW, nullptr, part, nullptr, nullptr,
            256, 512, 512, 512, 0, 0, PSLAB, 256, -1, -1, 99);
        add_ln_kernel<2><<<MROWS, 256, 0, stream>>>(
            x, part, PSLAB, bc + 3*512, g + 512, bb + 512, x, xh);

        // ---- FFN ----
        gemm_mfma_kernel<64,64,1,2><<<dim3(32, 32, 1), 256, 0, stream>>>(
            xh, nullptr, WTLh + 2097152L, b1 + (long)l * 2048,
            nullptr, t1h, nullptr,
            512, 512, 512, 2048, 0, 0, 0, 0, -1, -1, 99);
        gemm_mfma_kernel<64,64,0,5><<<dim3(8, 32, 4), 256, 0, stream>>>(
            t1h, nullptr, WTLh + 3145728L, nullptr, part,
            nullptr, nullptr,
            512, 2048, 2048, 512, 0, 0, PSLAB, 512, -1, -1, 99);
        add_ln_kernel<4><<<MROWS, 256, 0, stream>>>(
            x, part, PSLAB, b2 + (long)l * 512, g + 1024, bb + 1024, x, xh);
    }

    // ---- final vocab projection: one full-width wtrans + one 128^2 GEMM ----
    wtrans_kernel<<<dim3(500, 8, 1), 256, 0, stream>>>(Wout, WTh, 512, VOCAB);
    gemm_mfma_kernel<128,128,0,0><<<dim3(250, 16, 1), 256, 0, stream>>>(
        xh, nullptr, WTh, bout, out,
        nullptr, nullptr,
        512, 512, 512, VOCAB, 0, 0, 0, 0, -1, -1, 99);
}

// Round 20
// 875.807 us; speedup vs baseline: 1.1452x; 1.0159x over previous
//
#include <hip/hip_runtime.h>
#include <hip/hip_bf16.h>

// ---------------------------------------------------------------------------
// Transformer decoder, fp32 I/O. All matmuls pure bf16 1-product, fp32 acc.
// BK=32 2-phase dbuf GEMMs (+T1 XCD swizzle on vocab/FFN1); fused 2-pass
// attention; cross QKV merged via A-select; single full-width vocab GEMM.
// B=2, ST=SS=1024, D=512, H=8, DK=64, L=4, DFF=2048, V=32000.
// ---------------------------------------------------------------------------

#define D_MODEL 512
#define NHEAD   8
#define DKH     64
#define SEQ     1024
#define NLAYER  4
#define DFF_    2048
#define VOCAB   32000
#define BATCH   2
#define MROWS   (BATCH*SEQ)   // 2048
#define PSLAB   1048576L

typedef short bf16x8 __attribute__((ext_vector_type(8)));
typedef short short4v __attribute__((ext_vector_type(4)));
typedef float f32x4  __attribute__((ext_vector_type(4)));

static __device__ __forceinline__ short f2bf(float f) {
    __hip_bfloat16 h = __float2bfloat16(f);
    return *reinterpret_cast<short*>(&h);
}
static __device__ __forceinline__ float bf2f(short s) {
    __hip_bfloat16 h = *reinterpret_cast<__hip_bfloat16*>(&s);
    return __bfloat162float(h);
}
static __device__ __forceinline__ void gld16(const void* g, void* l) {
    __builtin_amdgcn_global_load_lds(
        (__attribute__((address_space(1))) void*)(void*)g,
        (__attribute__((address_space(3))) void*)l, 16, 0, 0);
}

// ---------------- embedding+PE (blocks 0..4095) | enc cvt (4096..5119) ------
__global__ __launch_bounds__(256) void embed_cvt_kernel(
    const int* __restrict__ tokens, const float* __restrict__ emb,
    float* __restrict__ x, short* __restrict__ xh,
    const float* __restrict__ enc, short* __restrict__ ench)
{
    if (blockIdx.x < 4096) {
        long idx = (long)blockIdx.x * 256 + threadIdx.x;   // over 1,048,576
        int  d   = (int)(idx & (D_MODEL - 1));
        long row = idx >> 9;
        int  s   = (int)(row & (SEQ - 1));
        int  tok = tokens[row];
        float twoi = (float)((d >> 1) << 1);
        float div  = expf(twoi * (-9.210340371976184f / 512.0f));
        float arg  = (float)s * div;
        float pe   = (d & 1) ? cosf(arg) : sinf(arg);
        float v = emb[(long)tok * D_MODEL + d] * 22.62741699796952f + pe;
        x[idx] = v;
        xh[idx] = f2bf(v);
    } else {
        long e = ((long)(blockIdx.x - 4096) * 256 + threadIdx.x) * 4;
        float4 v = *(const float4*)&enc[e];
        short4v hv;
        hv[0] = f2bf(v.x); hv[1] = f2bf(v.y);
        hv[2] = f2bf(v.z); hv[3] = f2bf(v.w);
        *(short4v*)&ench[e] = hv;
    }
}

// ---------------- weight transpose-convert: W[K,N] -> WT[N,K] hi ------------
__global__ __launch_bounds__(256) void wtrans_kernel(
    const float* __restrict__ W, short* __restrict__ Th,
    int K, int ldW)
{
    const int n0 = blockIdx.x * 64, k0 = blockIdx.y * 64;
    __shared__ float tile[64][65];
    const int t = threadIdx.x;
#pragma unroll
    for (int i = 0; i < 4; ++i) {
        int e = t + i * 256; int kk = e >> 4; int nn = (e & 15) * 4;
        float4 v = *(const float4*)&W[(long)(k0 + kk) * ldW + n0 + nn];
        tile[kk][nn] = v.x; tile[kk][nn + 1] = v.y;
        tile[kk][nn + 2] = v.z; tile[kk][nn + 3] = v.w;
    }
    __syncthreads();
    const int n = t >> 2, ks = (t & 3) * 16;
    short h8[16];
#pragma unroll
    for (int j = 0; j < 16; ++j) h8[j] = f2bf(tile[ks + j][n]);
    long base = (long)(n0 + n) * K + k0 + ks;
    *(bf16x8*)&Th[base]     = *(bf16x8*)&h8[0];
    *(bf16x8*)&Th[base + 8] = *(bf16x8*)&h8[8];
}

// ---------------- merged per-layer weight transpose (10 matrices, hi only) --
__global__ __launch_bounds__(256) void wtrans_layer_kernel(
    const float* __restrict__ Wqkvo, const float* __restrict__ W1,
    const float* __restrict__ W2, int l,
    short* __restrict__ Th)
{
    const int j = blockIdx.x;
    const float* W; int ldW, K; long dstOff; int n0, k0;
    if (j < 512) {
        int mat = j >> 6, tile_ = j & 63;
        W = Wqkvo + (long)l * 2097152L + (long)mat * 262144L;
        ldW = 512; K = 512; dstOff = (long)mat * 262144L;
        n0 = (tile_ & 7) * 64; k0 = (tile_ >> 3) * 64;
    } else if (j < 768) {
        int t2 = j - 512;
        W = W1 + (long)l * 1048576L; ldW = 2048; K = 512; dstOff = 2097152L;
        n0 = (t2 & 31) * 64; k0 = (t2 >> 5) * 64;
    } else {
        int t3 = j - 768;
        W = W2 + (long)l * 1048576L; ldW = 512; K = 2048; dstOff = 3145728L;
        n0 = (t3 & 7) * 64; k0 = (t3 >> 3) * 64;
    }
    __shared__ float tile[64][65];
    const int t = threadIdx.x;
#pragma unroll
    for (int i = 0; i < 4; ++i) {
        int e = t + i * 256; int kk = e >> 4; int nn = (e & 15) * 4;
        float4 v = *(const float4*)&W[(long)(k0 + kk) * ldW + n0 + nn];
        tile[kk][nn] = v.x; tile[kk][nn + 1] = v.y;
        tile[kk][nn + 2] = v.z; tile[kk][nn + 3] = v.w;
    }
    __syncthreads();
    const int n = t >> 2, ks = (t & 3) * 16;
    short h8[16];
#pragma unroll
    for (int j2 = 0; j2 < 16; ++j2) h8[j2] = f2bf(tile[ks + j2][n]);
    long base = dstOff + (long)(n0 + n) * K + k0 + ks;
    *(bf16x8*)&Th[base]     = *(bf16x8*)&h8[0];
    *(bf16x8*)&Th[base + 8] = *(bf16x8*)&h8[8];
}

// ---------------- 1-product MFMA GEMM, 2-phase dbuf (BK=32) -----------------
// A = (MODE==3 && z>=aSwitchZ) ? A2h : Ah.  K-window at z*kOff.
// MODE 0: fp32+bias. MODE 2: bf16 hi+bias(+relu). MODE 3: head-major attn
// operand hi w/ dk swizzle; z==scaledZ -> *0.125; z==vtZ -> transposed V hi.
// MODE 5: fp32 partial, no bias.  SWZ: XCD-chunked blockIdx remap (nwg%8==0).
template<int BM, int BN, int ACT, int MODE, bool SWZ>
__global__ __launch_bounds__(256) void gemm_mfma_kernel(
    const short* __restrict__ Ah, const short* __restrict__ A2h,
    const short* __restrict__ Bh,
    const float* __restrict__ bias, float* __restrict__ C,
    short* __restrict__ Ch, short* __restrict__ VTh,
    int Keff, int ldA, int ldB, int ldc,
    long zB, long zBias, long zC, int kOff, int scaledZ, int vtZ, int aSwitchZ)
{
    constexpr int MT_M = BM / 32;
    constexpr int MT_N = BN / 32;
    const long z = blockIdx.z;
    Bh += z * zB;
    if (MODE != 5) bias += z * zBias;

    const short* Au = (MODE == 3 && (int)z >= aSwitchZ) ? A2h : Ah;

    int bx = blockIdx.x, by = blockIdx.y;
    if (SWZ) {
        int gx = gridDim.x;
        int nwg = gx * gridDim.y;
        int flat = by * gx + bx;
        int swz = (flat & 7) * (nwg >> 3) + (flat >> 3);   // XCD-chunked
        bx = swz % gx;
        by = swz / gx;
    }
    const int n0 = bx * BN, m0 = by * BM;
    const int t = threadIdx.x;
    const int w = t >> 6, lane = t & 63;
    const int wm = w >> 1, wn = w & 1;
    const int lr = lane & 15, ks = lane >> 4;

    __shared__ short sAh[2][BM * 32];
    __shared__ short sBh[2][BN * 32];

    f32x4 acc[MT_M][MT_N];
#pragma unroll
    for (int i = 0; i < MT_M; ++i)
#pragma unroll
        for (int j = 0; j < MT_N; ++j) acc[i][j] = (f32x4){0.f, 0.f, 0.f, 0.f};

    const long rowA = ((long)m0 * ldA + (long)z * kOff) * 2;   // bytes
    const long rowB = ((long)n0 * ldB + (long)z * kOff) * 2;

    auto STAGE = [&](int buf, int k0) {
#pragma unroll
        for (int i = 0; i < BM / 64; ++i) {
            const int  L = i * 4096 + t * 16;
            const int  r = L >> 6, s = L & 63;
            const long gb = ((long)r * ldA + k0) * 2 + s;
            gld16((const char*)Au + rowA + gb, (char*)&sAh[buf][0] + L);
        }
#pragma unroll
        for (int i = 0; i < BN / 64; ++i) {
            const int  L = i * 4096 + t * 16;
            const int  r = L >> 6, s = L & 63;
            const long gb = ((long)r * ldB + k0) * 2 + s;
            gld16((const char*)Bh + rowB + gb, (char*)&sBh[buf][0] + L);
        }
    };
    auto COMPUTE = [&](int buf) {
        bf16x8 ah[MT_M], bh[MT_N];
#pragma unroll
        for (int mt = 0; mt < MT_M; ++mt) {
            int row = wm * (BM / 2) + mt * 16 + lr;
            ah[mt] = *(const bf16x8*)&sAh[buf][row * 32 + ks * 8];
        }
#pragma unroll
        for (int nt = 0; nt < MT_N; ++nt) {
            int col = wn * (BN / 2) + nt * 16 + lr;
            bh[nt] = *(const bf16x8*)&sBh[buf][col * 32 + ks * 8];
        }
#pragma unroll
        for (int mt = 0; mt < MT_M; ++mt)
#pragma unroll
            for (int nt = 0; nt < MT_N; ++nt)
                acc[mt][nt] = __builtin_amdgcn_mfma_f32_16x16x32_bf16(
                    ah[mt], bh[nt], acc[mt][nt], 0, 0, 0);
    };

    STAGE(0, 0);
    __syncthreads();
    int cur = 0;
    for (int k0 = 0; k0 < Keff; k0 += 32) {
        if (k0 + 32 < Keff) STAGE(cur ^ 1, k0 + 32);
        COMPUTE(cur);
        __syncthreads();
        cur ^= 1;
    }

    const int rq = lane >> 4, cq = lane & 15;
#pragma unroll
    for (int mt = 0; mt < MT_M; ++mt)
#pragma unroll
        for (int nt = 0; nt < MT_N; ++nt) {
            int gr0 = m0 + wm * (BM / 2) + mt * 16 + rq * 4;
            int gc  = n0 + wn * (BN / 2) + nt * 16 + cq;
            float vv[4];
            float bv = (MODE == 5) ? 0.f : bias[gc];
#pragma unroll
            for (int i = 0; i < 4; ++i) {
                float v = acc[mt][nt][i] + bv;
                if (ACT == 1) v = fmaxf(v, 0.f);
                vv[i] = v;
            }
            if (MODE == 0 || MODE == 5) {
#pragma unroll
                for (int i = 0; i < 4; ++i)
                    C[(long)(gr0 + i) * ldc + gc + z * zC] = vv[i];
            } else if (MODE == 2) {
#pragma unroll
                for (int i = 0; i < 4; ++i)
                    Ch[(long)(gr0 + i) * ldc + gc] = f2bf(vv[i]);
            } else {               // MODE 3
                if ((int)z == vtZ) {
                    int b = gr0 >> 10, s0 = gr0 & (SEQ - 1);
                    int hh2 = gc >> 6, dk = gc & 63;
                    int swz = (((dk >> 1) & 3) << 3) | (((dk >> 3) & 1) << 5);
                    long base = (((long)(b * NHEAD + hh2)) * 64 + dk) * 1024
                              + (long)(((s0 & ~7) ^ swz) | (s0 & 7));
                    short4v hv;
#pragma unroll
                    for (int i = 0; i < 4; ++i) hv[i] = f2bf(vv[i]);
                    *(short4v*)&VTh[base] = hv;
                } else {
                    float sc = ((int)z == scaledZ) ? 0.125f : 1.f;
#pragma unroll
                    for (int i = 0; i < 4; ++i) {
                        float v2 = vv[i] * sc;
                        int gr = gr0 + i;
                        int b = gr >> 10, s = gr & (SEQ - 1);
                        int hh2 = gc >> 6, dk = gc & 63;
                        int dks = dk ^ (((s >> 1) & 7) << 3);
                        long oidx = z * zC +
                            (((long)(b * NHEAD + hh2)) * SEQ + s) * 64 + dks;
                        Ch[oidx] = f2bf(v2);
                    }
                }
            }
        }
}

// ---------------- fused attention: 32 q-rows, 2 waves, 4 blocks/CU ----------
// QK and PV both 1-product bf16. LDS = 16+16+5 = 37 KB.
template<bool CAUSAL>
__global__ __launch_bounds__(128) void attn_fused_kernel(
    const short* __restrict__ Qh, const short* __restrict__ Kh,
    const short* __restrict__ VTh,
    float* __restrict__ attn, short* __restrict__ Oh)
{
    const int strip = blockIdx.x, bh = blockIdx.y;
    const int q0 = strip * 32;
    const int t = threadIdx.x, w = t >> 6, lane = t & 63;
    const int lr = lane & 15, ks = lane >> 4;
    const int rq = lane >> 4, cq = lane & 15;
    const int sxq = (lr >> 1) & 7;

    __shared__ short sKh[2][64*64];                  // 16 KB
    __shared__ short sVh[2][64*64];                  // 16 KB
    __shared__ short sPh[2][16*80];                  //  5 KB

    const int diag  = strip >> 1;
    const int ktmax = CAUSAL ? diag + 1 : 16;

    // Q stage (32 rows hi) via sKh[0]
    {
        const long qb = ((long)bh * SEQ + q0) * 128;
#pragma unroll
        for (int i2 = 0; i2 < 2; ++i2) {
            int L = i2 * 2048 + t * 16; int r = L >> 7, off = L & 127;
            gld16((const char*)Qh + qb + (long)r*128 + off, (char*)&sKh[0][0] + L);
        }
    }
    __syncthreads();
    bf16x8 qa[2];
#pragma unroll
    for (int k0 = 0; k0 < 2; ++k0) {
        int o = (w*16 + lr) * 64 + ((k0*32 + ks*8) ^ (sxq << 3));
        qa[k0] = *(const bf16x8*)&sKh[0][o];
    }
    __syncthreads();

    auto stageK = [&](int buf, int kt) {
        const long kb = ((long)bh * SEQ + kt*64) * 128;
#pragma unroll
        for (int i2 = 0; i2 < 4; ++i2) {
            int L = i2*2048 + t*16; int r = L >> 7, off = L & 127;
            gld16((const char*)Kh + kb + (long)r*128 + off, (char*)&sKh[buf][0] + L);
        }
    };
    auto stageV = [&](int buf, int kt) {
        const long vb = ((long)bh * 64) * 2048 + (long)kt * 128;
#pragma unroll
        for (int i2 = 0; i2 < 4; ++i2) {
            int L = i2*2048 + t*16; int r = L >> 7, off = L & 127;
            gld16((const char*)VTh + vb + (long)r*2048 + off, (char*)&sVh[buf][0] + L);
        }
    };
    auto scoresOf = [&](int buf, int kt, f32x4* sc) {
#pragma unroll
        for (int nt = 0; nt < 4; ++nt) sc[nt] = (f32x4){0.f, 0.f, 0.f, 0.f};
#pragma unroll
        for (int k0 = 0; k0 < 2; ++k0) {
            bf16x8 kh[4];
#pragma unroll
            for (int nt = 0; nt < 4; ++nt) {
                int o = (nt*16 + lr) * 64 + ((k0*32 + ks*8) ^ (sxq << 3));
                kh[nt] = *(const bf16x8*)&sKh[buf][o];
            }
#pragma unroll
            for (int nt = 0; nt < 4; ++nt)
                sc[nt] = __builtin_amdgcn_mfma_f32_16x16x32_bf16(
                    qa[k0], kh[nt], sc[nt], 0, 0, 0);
        }
        if (CAUSAL && kt == diag) {
            int row = q0 + w*16 + rq*4;
#pragma unroll
            for (int nt = 0; nt < 4; ++nt) {
                int col = kt*64 + nt*16 + cq;
#pragma unroll
                for (int i = 0; i < 4; ++i)
                    if (col > row + i) sc[nt][i] = -1e9f;
            }
        }
    };

    // ---- pass 1: online max + sum ----
    float m[4]   = {-3e38f, -3e38f, -3e38f, -3e38f};
    float sum[4] = {0.f, 0.f, 0.f, 0.f};
    int cur = 0;
    stageK(0, 0);
    __syncthreads();
    for (int kt = 0; kt < ktmax; ++kt) {
        if (kt + 1 < ktmax) stageK(cur ^ 1, kt + 1);
        f32x4 sc[4];
        scoresOf(cur, kt, sc);
#pragma unroll
        for (int i = 0; i < 4; ++i) {
            float tm = fmaxf(fmaxf(sc[0][i], sc[1][i]), fmaxf(sc[2][i], sc[3][i]));
#pragma unroll
            for (int d2 = 1; d2 <= 8; d2 <<= 1) tm = fmaxf(tm, __shfl_xor(tm, d2, 64));
            float mn = fmaxf(m[i], tm);
            float ps = __expf(sc[0][i] - mn) + __expf(sc[1][i] - mn)
                     + __expf(sc[2][i] - mn) + __expf(sc[3][i] - mn);
#pragma unroll
            for (int d2 = 1; d2 <= 8; d2 <<= 1) ps += __shfl_xor(ps, d2, 64);
            sum[i] = sum[i] * __expf(m[i] - mn) + ps;
            m[i] = mn;
        }
        __syncthreads();
        cur ^= 1;
    }
    float inv[4];
#pragma unroll
    for (int i = 0; i < 4; ++i) inv[i] = 1.f / sum[i];

    // ---- pass 2: recompute, probs out, PV (1-product) ----
    f32x4 acco[4];
#pragma unroll
    for (int nt = 0; nt < 4; ++nt) acco[nt] = (f32x4){0.f, 0.f, 0.f, 0.f};

    cur = 0;
    stageK(0, 0); stageV(0, 0);
    __syncthreads();
    for (int kt = 0; kt < ktmax; ++kt) {
        if (kt + 1 < ktmax) { stageK(cur ^ 1, kt + 1); stageV(cur ^ 1, kt + 1); }
        f32x4 sc[4];
        scoresOf(cur, kt, sc);
#pragma unroll
        for (int nt = 0; nt < 4; ++nt)
#pragma unroll
            for (int i = 0; i < 4; ++i) {
                float p = __expf(sc[nt][i] - m[i]) * inv[i];
                attn[((long)bh << 20) + ((long)(q0 + w*16 + rq*4 + i) << 10)
                     + kt*64 + nt*16 + cq] = p;
                sPh[w][(rq*4 + i)*80 + nt*16 + cq] = f2bf(p);
            }
#pragma unroll
        for (int k0 = 0; k0 < 2; ++k0) {
            bf16x8 pah = *(const bf16x8*)&sPh[w][lr*80 + k0*32 + ks*8];
#pragma unroll
            for (int nt = 0; nt < 4; ++nt) {
                int dk = nt*16 + lr;
                int swz = (((dk >> 1) & 3) << 3) | (((dk >> 3) & 1) << 5);
                int koff = (k0*32 + ks*8) ^ swz;
                bf16x8 vh8 = *(const bf16x8*)&sVh[cur][dk*64 + koff];
                acco[nt] = __builtin_amdgcn_mfma_f32_16x16x32_bf16(
                    pah, vh8, acco[nt], 0, 0, 0);
            }
        }
        __syncthreads();
        cur ^= 1;
    }

    // ---- causal masked region: vectorized zero fill ----
    if (CAUSAL && ktmax < 16) {
        const int r = t >> 2, g = (t & 3) * 4;
        const long rowbase = ((long)bh << 20) + ((long)(q0 + r) << 10);
        const float4 z4 = {0.f, 0.f, 0.f, 0.f};
        for (int c = ktmax * 64 + g; c < SEQ; c += 16)
            *(float4*)&attn[rowbase + c] = z4;
    }

    const int b = bh >> 3, hh_ = bh & 7;
#pragma unroll
    for (int nt = 0; nt < 4; ++nt)
#pragma unroll
        for (int i = 0; i < 4; ++i) {
            long oidx = ((long)(b * SEQ + q0 + w*16 + rq*4 + i)) * D_MODEL
                      + hh_*64 + nt*16 + cq;
            Oh[oidx] = f2bf(acco[nt][i]);
        }
}

// ---------------- residual + NS partial slabs + bias + LayerNorm + hi -------
template<int NS>
__global__ __launch_bounds__(256) void add_ln_kernel(
    const float* __restrict__ xin, const float* __restrict__ part, long PS,
    const float* __restrict__ bias,
    const float* __restrict__ g, const float* __restrict__ bb,
    float* __restrict__ xout, short* __restrict__ xh)
{
    long row = blockIdx.x;
    const float* xr = xin + row * D_MODEL;
    float*       xo = xout+ row * D_MODEL;
    short*       hh = xh  + row * D_MODEL;
    int t = threadIdx.x;

    float a0 = xr[t]       + bias[t];
    float a1 = xr[t + 256] + bias[t + 256];
#pragma unroll
    for (int s2 = 0; s2 < NS; ++s2) {
        a0 += part[s2 * PS + row * D_MODEL + t];
        a1 += part[s2 * PS + row * D_MODEL + t + 256];
    }

    float s = a0 + a1;
#pragma unroll
    for (int m = 32; m; m >>= 1) s += __shfl_xor(s, m, 64);
    __shared__ float red1[4];
    __shared__ float red2[4];
    int w = t >> 6, lane = t & 63;
    if (lane == 0) red1[w] = s;
    __syncthreads();
    float mean = (red1[0] + red1[1] + red1[2] + red1[3]) * (1.f / 512.f);

    float d0 = a0 - mean, d1 = a1 - mean;
    float q = d0 * d0 + d1 * d1;
#pragma unroll
    for (int m = 32; m; m >>= 1) q += __shfl_xor(q, m, 64);
    if (lane == 0) red2[w] = q;
    __syncthreads();
    float var  = (red2[0] + red2[1] + red2[2] + red2[3]) * (1.f / 512.f);
    float rstd = rsqrtf(var + 1e-5f);

    float r0 = d0 * rstd * g[t]       + bb[t];
    float r1 = d1 * rstd * g[t + 256] + bb[t + 256];
    xo[t] = r0; xo[t + 256] = r1;
    hh[t] = f2bf(r0);
    hh[t + 256] = f2bf(r1);
}

// ---------------------------------------------------------------------------
extern "C" void kernel_launch(void* const* d_in, const int* in_sizes, int n_in,
                              void* d_out, int out_size, void* d_ws, size_t ws_size,
                              hipStream_t stream)
{
    const int*   tokens = (const int*)  d_in[0];
    const float* enc    = (const float*)d_in[1];
    const float* emb    = (const float*)d_in[3];
    const float* Wqkvo  = (const float*)d_in[4];   // [L,2,4,D,D]
    const float* bqkvo  = (const float*)d_in[5];   // [L,2,4,D]
    const float* W1     = (const float*)d_in[6];   // [L,D,DFF]
    const float* b1     = (const float*)d_in[7];
    const float* W2     = (const float*)d_in[8];   // [L,DFF,D]
    const float* b2     = (const float*)d_in[9];
    const float* lng    = (const float*)d_in[10];  // [L,3,D]
    const float* lnb    = (const float*)d_in[11];
    const float* Wout   = (const float*)d_in[12];  // [D,V]
    const float* bout   = (const float*)d_in[13];

    float* out    = (float*)d_out;
    float* selfA  = out + 65536000L;
    float* crossA = selfA + 67108864L;

    // workspace carve (~90 MB)
    char* p = (char*)d_ws;
    auto carve = [&](size_t bytes) { char* r = p; p += (bytes + 255) & ~255UL; return r; };
    float* x      = (float*)carve(1048576L * 4);
    short* xh     = (short*)carve(1048576L * 2);
    short* ench   = (short*)carve(1048576L * 2);
    short* qh     = (short*)carve(2097152L * 2);   // head-major Q|K hi
    short* vth    = (short*)carve(1048576L * 2);   // transposed V hi
    short* oh     = (short*)carve(1048576L * 2);
    short* t1h    = (short*)carve(4194304L * 2);   // FFN1 out hi
    float* part   = (float*)carve(4L * PSLAB * 4); // 4 K-split slabs
    short* WTLh   = (short*)carve(4194304L * 2);   // per-layer weights T hi
    short* WTh    = (short*)carve(16384000L * 2);  // full vocab WT hi (32.8 MB)

    const long PW = 262144L;    // 512*512
    const long HS = 1048576L;   // per attention operand slab

    embed_cvt_kernel<<<5120, 256, 0, stream>>>(tokens, emb, x, xh, enc, ench);

    for (int l = 0; l < NLAYER; ++l) {
        const float* bl = bqkvo + (long)l * 4096L;
        const float* bc = bl + 2048;
        const float* g  = lng + (long)l * 3 * 512;
        const float* bb = lnb + (long)l * 3 * 512;

        wtrans_layer_kernel<<<1024, 256, 0, stream>>>(Wqkvo, W1, W2, l, WTLh);

        // ---- self-attention (QKV one dispatch, A always xh) ----
        gemm_mfma_kernel<64,64,0,3,false><<<dim3(8, 32, 3), 256, 0, stream>>>(
            xh, xh, WTLh, bl, nullptr, qh, vth,
            512, 512, 512, 0, PW, 512, HS, 0, /*scaledZ=*/0, /*vtZ=*/2,
            /*aSwitchZ=*/3);
        attn_fused_kernel<true><<<dim3(32, 16), 128, 0, stream>>>(
            qh, qh + HS, vth, selfA + (long)l * 16777216L, oh);
        gemm_mfma_kernel<64,64,0,5,false><<<dim3(8, 32, 2), 256, 0, stream>>>(
            oh, nullptr, WTLh + 3*PW, nullptr, part, nullptr, nullptr,
            256, 512, 512, 512, 0, 0, PSLAB, 256, -1, -1, 99);
        add_ln_kernel<2><<<MROWS, 256, 0, stream>>>(
            x, part, PSLAB, bl + 3*512, g, bb, x, xh);

        // ---- cross-attention (QKV merged: z0 Q from xh, z1 K / z2 V from enc)
        gemm_mfma_kernel<64,64,0,3,false><<<dim3(8, 32, 3), 256, 0, stream>>>(
            xh, ench, WTLh + 4*PW, bc, nullptr, qh, vth,
            512, 512, 512, 0, PW, 512, HS, 0, /*scaledZ=*/0, /*vtZ=*/2,
            /*aSwitchZ=*/1);
        attn_fused_kernel<false><<<dim3(32, 16), 128, 0, stream>>>(
            qh, qh + HS, vth, crossA + (long)l * 16777216L, oh);
        gemm_mfma_kernel<64,64,0,5,false><<<dim3(8, 32, 2), 256, 0, stream>>>(
            oh, nullptr, WTLh + 7*PW, nullptr, part, nullptr, nullptr,
            256, 512, 512, 512, 0, 0, PSLAB, 256, -1, -1, 99);
        add_ln_kernel<2><<<MROWS, 256, 0, stream>>>(
            x, part, PSLAB, bc + 3*512, g + 512, bb + 512, x, xh);

        // ---- FFN (FFN1 with T1 XCD swizzle, nwg=1024) ----
        gemm_mfma_kernel<64,64,1,2,true><<<dim3(32, 32, 1), 256, 0, stream>>>(
            xh, nullptr, WTLh + 2097152L, b1 + (long)l * 2048,
            nullptr, t1h, nullptr,
            512, 512, 512, 2048, 0, 0, 0, 0, -1, -1, 99);
        gemm_mfma_kernel<64,64,0,5,false><<<dim3(8, 32, 4), 256, 0, stream>>>(
            t1h, nullptr, WTLh + 3145728L, nullptr, part,
            nullptr, nullptr,
            512, 2048, 2048, 512, 0, 0, PSLAB, 512, -1, -1, 99);
        add_ln_kernel<4><<<MROWS, 256, 0, stream>>>(
            x, part, PSLAB, b2 + (long)l * 512, g + 1024, bb + 1024, x, xh);
    }

    // ---- final vocab projection (T1 XCD swizzle, nwg=4000) ----
    wtrans_kernel<<<dim3(500, 8, 1), 256, 0, stream>>>(Wout, WTh, 512, VOCAB);
    gemm_mfma_kernel<128,128,0,0,true><<<dim3(250, 16, 1), 256, 0, stream>>>(
        xh, nullptr, WTh, bout, out,
        nullptr, nullptr,
        512, 512, 512, VOCAB, 0, 0, 0, 0, -1, -1, 99);
}

// Round 21
// 860.396 us; speedup vs baseline: 1.1657x; 1.0179x over previous
//
#include <hip/hip_runtime.h>
#include <hip/hip_bf16.h>

// ---------------------------------------------------------------------------
// Transformer decoder, fp32 I/O. All matmuls pure bf16 1-product, fp32 acc.
// BK=32 2-phase dbuf GEMMs, T1 XCD-chunked swizzle on ALL GEMMs + attention;
// fused 2-pass attention; cross QKV merged via A-select; single vocab GEMM.
// B=2, ST=SS=1024, D=512, H=8, DK=64, L=4, DFF=2048, V=32000.
// ---------------------------------------------------------------------------

#define D_MODEL 512
#define NHEAD   8
#define DKH     64
#define SEQ     1024
#define NLAYER  4
#define DFF_    2048
#define VOCAB   32000
#define BATCH   2
#define MROWS   (BATCH*SEQ)   // 2048
#define PSLAB   1048576L

typedef short bf16x8 __attribute__((ext_vector_type(8)));
typedef short short4v __attribute__((ext_vector_type(4)));
typedef float f32x4  __attribute__((ext_vector_type(4)));

static __device__ __forceinline__ short f2bf(float f) {
    __hip_bfloat16 h = __float2bfloat16(f);
    return *reinterpret_cast<short*>(&h);
}
static __device__ __forceinline__ float bf2f(short s) {
    __hip_bfloat16 h = *reinterpret_cast<__hip_bfloat16*>(&s);
    return __bfloat162float(h);
}
static __device__ __forceinline__ void gld16(const void* g, void* l) {
    __builtin_amdgcn_global_load_lds(
        (__attribute__((address_space(1))) void*)(void*)g,
        (__attribute__((address_space(3))) void*)l, 16, 0, 0);
}

// ---------------- embedding+PE (blocks 0..4095) | enc cvt (4096..5119) ------
__global__ __launch_bounds__(256) void embed_cvt_kernel(
    const int* __restrict__ tokens, const float* __restrict__ emb,
    float* __restrict__ x, short* __restrict__ xh,
    const float* __restrict__ enc, short* __restrict__ ench)
{
    if (blockIdx.x < 4096) {
        long idx = (long)blockIdx.x * 256 + threadIdx.x;   // over 1,048,576
        int  d   = (int)(idx & (D_MODEL - 1));
        long row = idx >> 9;
        int  s   = (int)(row & (SEQ - 1));
        int  tok = tokens[row];
        float twoi = (float)((d >> 1) << 1);
        float div  = expf(twoi * (-9.210340371976184f / 512.0f));
        float arg  = (float)s * div;
        float pe   = (d & 1) ? cosf(arg) : sinf(arg);
        float v = emb[(long)tok * D_MODEL + d] * 22.62741699796952f + pe;
        x[idx] = v;
        xh[idx] = f2bf(v);
    } else {
        long e = ((long)(blockIdx.x - 4096) * 256 + threadIdx.x) * 4;
        float4 v = *(const float4*)&enc[e];
        short4v hv;
        hv[0] = f2bf(v.x); hv[1] = f2bf(v.y);
        hv[2] = f2bf(v.z); hv[3] = f2bf(v.w);
        *(short4v*)&ench[e] = hv;
    }
}

// ---------------- weight transpose-convert: W[K,N] -> WT[N,K] hi ------------
__global__ __launch_bounds__(256) void wtrans_kernel(
    const float* __restrict__ W, short* __restrict__ Th,
    int K, int ldW)
{
    const int n0 = blockIdx.x * 64, k0 = blockIdx.y * 64;
    __shared__ float tile[64][65];
    const int t = threadIdx.x;
#pragma unroll
    for (int i = 0; i < 4; ++i) {
        int e = t + i * 256; int kk = e >> 4; int nn = (e & 15) * 4;
        float4 v = *(const float4*)&W[(long)(k0 + kk) * ldW + n0 + nn];
        tile[kk][nn] = v.x; tile[kk][nn + 1] = v.y;
        tile[kk][nn + 2] = v.z; tile[kk][nn + 3] = v.w;
    }
    __syncthreads();
    const int n = t >> 2, ks = (t & 3) * 16;
    short h8[16];
#pragma unroll
    for (int j = 0; j < 16; ++j) h8[j] = f2bf(tile[ks + j][n]);
    long base = (long)(n0 + n) * K + k0 + ks;
    *(bf16x8*)&Th[base]     = *(bf16x8*)&h8[0];
    *(bf16x8*)&Th[base + 8] = *(bf16x8*)&h8[8];
}

// ---------------- merged per-layer weight transpose (10 matrices, hi only) --
__global__ __launch_bounds__(256) void wtrans_layer_kernel(
    const float* __restrict__ Wqkvo, const float* __restrict__ W1,
    const float* __restrict__ W2, int l,
    short* __restrict__ Th)
{
    const int j = blockIdx.x;
    const float* W; int ldW, K; long dstOff; int n0, k0;
    if (j < 512) {
        int mat = j >> 6, tile_ = j & 63;
        W = Wqkvo + (long)l * 2097152L + (long)mat * 262144L;
        ldW = 512; K = 512; dstOff = (long)mat * 262144L;
        n0 = (tile_ & 7) * 64; k0 = (tile_ >> 3) * 64;
    } else if (j < 768) {
        int t2 = j - 512;
        W = W1 + (long)l * 1048576L; ldW = 2048; K = 512; dstOff = 2097152L;
        n0 = (t2 & 31) * 64; k0 = (t2 >> 5) * 64;
    } else {
        int t3 = j - 768;
        W = W2 + (long)l * 1048576L; ldW = 512; K = 2048; dstOff = 3145728L;
        n0 = (t3 & 7) * 64; k0 = (t3 >> 3) * 64;
    }
    __shared__ float tile[64][65];
    const int t = threadIdx.x;
#pragma unroll
    for (int i = 0; i < 4; ++i) {
        int e = t + i * 256; int kk = e >> 4; int nn = (e & 15) * 4;
        float4 v = *(const float4*)&W[(long)(k0 + kk) * ldW + n0 + nn];
        tile[kk][nn] = v.x; tile[kk][nn + 1] = v.y;
        tile[kk][nn + 2] = v.z; tile[kk][nn + 3] = v.w;
    }
    __syncthreads();
    const int n = t >> 2, ks = (t & 3) * 16;
    short h8[16];
#pragma unroll
    for (int j2 = 0; j2 < 16; ++j2) h8[j2] = f2bf(tile[ks + j2][n]);
    long base = dstOff + (long)(n0 + n) * K + k0 + ks;
    *(bf16x8*)&Th[base]     = *(bf16x8*)&h8[0];
    *(bf16x8*)&Th[base + 8] = *(bf16x8*)&h8[8];
}

// ---------------- 1-product MFMA GEMM, 2-phase dbuf (BK=32) -----------------
// A = (MODE==3 && z>=aSwitchZ) ? A2h : Ah.  K-window at z*kOff.
// MODE 0: fp32+bias. MODE 2: bf16 hi+bias(+relu). MODE 3: head-major attn
// operand hi w/ dk swizzle; z==scaledZ -> *0.125; z==vtZ -> transposed V hi.
// MODE 5: fp32 partial, no bias.  T1 XCD-chunked x/y remap (nwg_xy%8==0).
template<int BM, int BN, int ACT, int MODE>
__global__ __launch_bounds__(256) void gemm_mfma_kernel(
    const short* __restrict__ Ah, const short* __restrict__ A2h,
    const short* __restrict__ Bh,
    const float* __restrict__ bias, float* __restrict__ C,
    short* __restrict__ Ch, short* __restrict__ VTh,
    int Keff, int ldA, int ldB, int ldc,
    long zB, long zBias, long zC, int kOff, int scaledZ, int vtZ, int aSwitchZ)
{
    constexpr int MT_M = BM / 32;
    constexpr int MT_N = BN / 32;
    const long z = blockIdx.z;
    Bh += z * zB;
    if (MODE != 5) bias += z * zBias;

    const short* Au = (MODE == 3 && (int)z >= aSwitchZ) ? A2h : Ah;

    int bx, by;
    {
        int gx = gridDim.x;
        int nwg = gx * gridDim.y;
        int flat = blockIdx.y * gx + blockIdx.x;
        int swz = (flat & 7) * (nwg >> 3) + (flat >> 3);   // XCD-chunked
        bx = swz % gx;
        by = swz / gx;
    }
    const int n0 = bx * BN, m0 = by * BM;
    const int t = threadIdx.x;
    const int w = t >> 6, lane = t & 63;
    const int wm = w >> 1, wn = w & 1;
    const int lr = lane & 15, ks = lane >> 4;

    __shared__ short sAh[2][BM * 32];
    __shared__ short sBh[2][BN * 32];

    f32x4 acc[MT_M][MT_N];
#pragma unroll
    for (int i = 0; i < MT_M; ++i)
#pragma unroll
        for (int j = 0; j < MT_N; ++j) acc[i][j] = (f32x4){0.f, 0.f, 0.f, 0.f};

    const long rowA = ((long)m0 * ldA + (long)z * kOff) * 2;   // bytes
    const long rowB = ((long)n0 * ldB + (long)z * kOff) * 2;

    auto STAGE = [&](int buf, int k0) {
#pragma unroll
        for (int i = 0; i < BM / 64; ++i) {
            const int  L = i * 4096 + t * 16;
            const int  r = L >> 6, s = L & 63;
            const long gb = ((long)r * ldA + k0) * 2 + s;
            gld16((const char*)Au + rowA + gb, (char*)&sAh[buf][0] + L);
        }
#pragma unroll
        for (int i = 0; i < BN / 64; ++i) {
            const int  L = i * 4096 + t * 16;
            const int  r = L >> 6, s = L & 63;
            const long gb = ((long)r * ldB + k0) * 2 + s;
            gld16((const char*)Bh + rowB + gb, (char*)&sBh[buf][0] + L);
        }
    };
    auto COMPUTE = [&](int buf) {
        bf16x8 ah[MT_M], bh[MT_N];
#pragma unroll
        for (int mt = 0; mt < MT_M; ++mt) {
            int row = wm * (BM / 2) + mt * 16 + lr;
            ah[mt] = *(const bf16x8*)&sAh[buf][row * 32 + ks * 8];
        }
#pragma unroll
        for (int nt = 0; nt < MT_N; ++nt) {
            int col = wn * (BN / 2) + nt * 16 + lr;
            bh[nt] = *(const bf16x8*)&sBh[buf][col * 32 + ks * 8];
        }
#pragma unroll
        for (int mt = 0; mt < MT_M; ++mt)
#pragma unroll
            for (int nt = 0; nt < MT_N; ++nt)
                acc[mt][nt] = __builtin_amdgcn_mfma_f32_16x16x32_bf16(
                    ah[mt], bh[nt], acc[mt][nt], 0, 0, 0);
    };

    STAGE(0, 0);
    __syncthreads();
    int cur = 0;
    for (int k0 = 0; k0 < Keff; k0 += 32) {
        if (k0 + 32 < Keff) STAGE(cur ^ 1, k0 + 32);
        COMPUTE(cur);
        __syncthreads();
        cur ^= 1;
    }

    const int rq = lane >> 4, cq = lane & 15;
#pragma unroll
    for (int mt = 0; mt < MT_M; ++mt)
#pragma unroll
        for (int nt = 0; nt < MT_N; ++nt) {
            int gr0 = m0 + wm * (BM / 2) + mt * 16 + rq * 4;
            int gc  = n0 + wn * (BN / 2) + nt * 16 + cq;
            float vv[4];
            float bv = (MODE == 5) ? 0.f : bias[gc];
#pragma unroll
            for (int i = 0; i < 4; ++i) {
                float v = acc[mt][nt][i] + bv;
                if (ACT == 1) v = fmaxf(v, 0.f);
                vv[i] = v;
            }
            if (MODE == 0 || MODE == 5) {
#pragma unroll
                for (int i = 0; i < 4; ++i)
                    C[(long)(gr0 + i) * ldc + gc + z * zC] = vv[i];
            } else if (MODE == 2) {
#pragma unroll
                for (int i = 0; i < 4; ++i)
                    Ch[(long)(gr0 + i) * ldc + gc] = f2bf(vv[i]);
            } else {               // MODE 3
                if ((int)z == vtZ) {
                    int b = gr0 >> 10, s0 = gr0 & (SEQ - 1);
                    int hh2 = gc >> 6, dk = gc & 63;
                    int swz = (((dk >> 1) & 3) << 3) | (((dk >> 3) & 1) << 5);
                    long base = (((long)(b * NHEAD + hh2)) * 64 + dk) * 1024
                              + (long)(((s0 & ~7) ^ swz) | (s0 & 7));
                    short4v hv;
#pragma unroll
                    for (int i = 0; i < 4; ++i) hv[i] = f2bf(vv[i]);
                    *(short4v*)&VTh[base] = hv;
                } else {
                    float sc = ((int)z == scaledZ) ? 0.125f : 1.f;
#pragma unroll
                    for (int i = 0; i < 4; ++i) {
                        float v2 = vv[i] * sc;
                        int gr = gr0 + i;
                        int b = gr >> 10, s = gr & (SEQ - 1);
                        int hh2 = gc >> 6, dk = gc & 63;
                        int dks = dk ^ (((s >> 1) & 7) << 3);
                        long oidx = z * zC +
                            (((long)(b * NHEAD + hh2)) * SEQ + s) * 64 + dks;
                        Ch[oidx] = f2bf(v2);
                    }
                }
            }
        }
}

// ---------------- fused attention: 32 q-rows, 2 waves, 4 blocks/CU ----------
// QK and PV both 1-product bf16. LDS = 16+16+5 = 37 KB.
// T1 XCD-chunked (strip,bh) remap: each XCD handles 2 whole heads (K/V L2
// locality); per-XCD causal work balanced (all strips of its heads).
template<bool CAUSAL>
__global__ __launch_bounds__(128) void attn_fused_kernel(
    const short* __restrict__ Qh, const short* __restrict__ Kh,
    const short* __restrict__ VTh,
    float* __restrict__ attn, short* __restrict__ Oh)
{
    int strip, bh;
    {
        int flat = blockIdx.y * 32 + blockIdx.x;           // nwg = 512
        int swz = (flat & 7) * 64 + (flat >> 3);
        bh = swz >> 5;
        strip = swz & 31;
    }
    const int q0 = strip * 32;
    const int t = threadIdx.x, w = t >> 6, lane = t & 63;
    const int lr = lane & 15, ks = lane >> 4;
    const int rq = lane >> 4, cq = lane & 15;
    const int sxq = (lr >> 1) & 7;

    __shared__ short sKh[2][64*64];                  // 16 KB
    __shared__ short sVh[2][64*64];                  // 16 KB
    __shared__ short sPh[2][16*80];                  //  5 KB

    const int diag  = strip >> 1;
    const int ktmax = CAUSAL ? diag + 1 : 16;

    // Q stage (32 rows hi) via sKh[0]
    {
        const long qb = ((long)bh * SEQ + q0) * 128;
#pragma unroll
        for (int i2 = 0; i2 < 2; ++i2) {
            int L = i2 * 2048 + t * 16; int r = L >> 7, off = L & 127;
            gld16((const char*)Qh + qb + (long)r*128 + off, (char*)&sKh[0][0] + L);
        }
    }
    __syncthreads();
    bf16x8 qa[2];
#pragma unroll
    for (int k0 = 0; k0 < 2; ++k0) {
        int o = (w*16 + lr) * 64 + ((k0*32 + ks*8) ^ (sxq << 3));
        qa[k0] = *(const bf16x8*)&sKh[0][o];
    }
    __syncthreads();

    auto stageK = [&](int buf, int kt) {
        const long kb = ((long)bh * SEQ + kt*64) * 128;
#pragma unroll
        for (int i2 = 0; i2 < 4; ++i2) {
            int L = i2*2048 + t*16; int r = L >> 7, off = L & 127;
            gld16((const char*)Kh + kb + (long)r*128 + off, (char*)&sKh[buf][0] + L);
        }
    };
    auto stageV = [&](int buf, int kt) {
        const long vb = ((long)bh * 64) * 2048 + (long)kt * 128;
#pragma unroll
        for (int i2 = 0; i2 < 4; ++i2) {
            int L = i2*2048 + t*16; int r = L >> 7, off = L & 127;
            gld16((const char*)VTh + vb + (long)r*2048 + off, (char*)&sVh[buf][0] + L);
        }
    };
    auto scoresOf = [&](int buf, int kt, f32x4* sc) {
#pragma unroll
        for (int nt = 0; nt < 4; ++nt) sc[nt] = (f32x4){0.f, 0.f, 0.f, 0.f};
#pragma unroll
        for (int k0 = 0; k0 < 2; ++k0) {
            bf16x8 kh[4];
#pragma unroll
            for (int nt = 0; nt < 4; ++nt) {
                int o = (nt*16 + lr) * 64 + ((k0*32 + ks*8) ^ (sxq << 3));
                kh[nt] = *(const bf16x8*)&sKh[buf][o];
            }
#pragma unroll
            for (int nt = 0; nt < 4; ++nt)
                sc[nt] = __builtin_amdgcn_mfma_f32_16x16x32_bf16(
                    qa[k0], kh[nt], sc[nt], 0, 0, 0);
        }
        if (CAUSAL && kt == diag) {
            int row = q0 + w*16 + rq*4;
#pragma unroll
            for (int nt = 0; nt < 4; ++nt) {
                int col = kt*64 + nt*16 + cq;
#pragma unroll
                for (int i = 0; i < 4; ++i)
                    if (col > row + i) sc[nt][i] = -1e9f;
            }
        }
    };

    // ---- pass 1: online max + sum ----
    float m[4]   = {-3e38f, -3e38f, -3e38f, -3e38f};
    float sum[4] = {0.f, 0.f, 0.f, 0.f};
    int cur = 0;
    stageK(0, 0);
    __syncthreads();
    for (int kt = 0; kt < ktmax; ++kt) {
        if (kt + 1 < ktmax) stageK(cur ^ 1, kt + 1);
        f32x4 sc[4];
        scoresOf(cur, kt, sc);
#pragma unroll
        for (int i = 0; i < 4; ++i) {
            float tm = fmaxf(fmaxf(sc[0][i], sc[1][i]), fmaxf(sc[2][i], sc[3][i]));
#pragma unroll
            for (int d2 = 1; d2 <= 8; d2 <<= 1) tm = fmaxf(tm, __shfl_xor(tm, d2, 64));
            float mn = fmaxf(m[i], tm);
            float ps = __expf(sc[0][i] - mn) + __expf(sc[1][i] - mn)
                     + __expf(sc[2][i] - mn) + __expf(sc[3][i] - mn);
#pragma unroll
            for (int d2 = 1; d2 <= 8; d2 <<= 1) ps += __shfl_xor(ps, d2, 64);
            sum[i] = sum[i] * __expf(m[i] - mn) + ps;
            m[i] = mn;
        }
        __syncthreads();
        cur ^= 1;
    }
    float inv[4];
#pragma unroll
    for (int i = 0; i < 4; ++i) inv[i] = 1.f / sum[i];

    // ---- pass 2: recompute, probs out, PV (1-product) ----
    f32x4 acco[4];
#pragma unroll
    for (int nt = 0; nt < 4; ++nt) acco[nt] = (f32x4){0.f, 0.f, 0.f, 0.f};

    cur = 0;
    stageK(0, 0); stageV(0, 0);
    __syncthreads();
    for (int kt = 0; kt < ktmax; ++kt) {
        if (kt + 1 < ktmax) { stageK(cur ^ 1, kt + 1); stageV(cur ^ 1, kt + 1); }
        f32x4 sc[4];
        scoresOf(cur, kt, sc);
#pragma unroll
        for (int nt = 0; nt < 4; ++nt)
#pragma unroll
            for (int i = 0; i < 4; ++i) {
                float p = __expf(sc[nt][i] - m[i]) * inv[i];
                attn[((long)bh << 20) + ((long)(q0 + w*16 + rq*4 + i) << 10)
                     + kt*64 + nt*16 + cq] = p;
                sPh[w][(rq*4 + i)*80 + nt*16 + cq] = f2bf(p);
            }
#pragma unroll
        for (int k0 = 0; k0 < 2; ++k0) {
            bf16x8 pah = *(const bf16x8*)&sPh[w][lr*80 + k0*32 + ks*8];
#pragma unroll
            for (int nt = 0; nt < 4; ++nt) {
                int dk = nt*16 + lr;
                int swz = (((dk >> 1) & 3) << 3) | (((dk >> 3) & 1) << 5);
                int koff = (k0*32 + ks*8) ^ swz;
                bf16x8 vh8 = *(const bf16x8*)&sVh[cur][dk*64 + koff];
                acco[nt] = __builtin_amdgcn_mfma_f32_16x16x32_bf16(
                    pah, vh8, acco[nt], 0, 0, 0);
            }
        }
        __syncthreads();
        cur ^= 1;
    }

    // ---- causal masked region: vectorized zero fill ----
    if (CAUSAL && ktmax < 16) {
        const int r = t >> 2, g = (t & 3) * 4;
        const long rowbase = ((long)bh << 20) + ((long)(q0 + r) << 10);
        const float4 z4 = {0.f, 0.f, 0.f, 0.f};
        for (int c = ktmax * 64 + g; c < SEQ; c += 16)
            *(float4*)&attn[rowbase + c] = z4;
    }

    const int b = bh >> 3, hh_ = bh & 7;
#pragma unroll
    for (int nt = 0; nt < 4; ++nt)
#pragma unroll
        for (int i = 0; i < 4; ++i) {
            long oidx = ((long)(b * SEQ + q0 + w*16 + rq*4 + i)) * D_MODEL
                      + hh_*64 + nt*16 + cq;
            Oh[oidx] = f2bf(acco[nt][i]);
        }
}

// ---------------- residual + NS partial slabs + bias + LayerNorm + hi -------
template<int NS>
__global__ __launch_bounds__(256) void add_ln_kernel(
    const float* __restrict__ xin, const float* __restrict__ part, long PS,
    const float* __restrict__ bias,
    const float* __restrict__ g, const float* __restrict__ bb,
    float* __restrict__ xout, short* __restrict__ xh)
{
    long row = blockIdx.x;
    const float* xr = xin + row * D_MODEL;
    float*       xo = xout+ row * D_MODEL;
    short*       hh = xh  + row * D_MODEL;
    int t = threadIdx.x;

    float a0 = xr[t]       + bias[t];
    float a1 = xr[t + 256] + bias[t + 256];
#pragma unroll
    for (int s2 = 0; s2 < NS; ++s2) {
        a0 += part[s2 * PS + row * D_MODEL + t];
        a1 += part[s2 * PS + row * D_MODEL + t + 256];
    }

    float s = a0 + a1;
#pragma unroll
    for (int m = 32; m; m >>= 1) s += __shfl_xor(s, m, 64);
    __shared__ float red1[4];
    __shared__ float red2[4];
    int w = t >> 6, lane = t & 63;
    if (lane == 0) red1[w] = s;
    __syncthreads();
    float mean = (red1[0] + red1[1] + red1[2] + red1[3]) * (1.f / 512.f);

    float d0 = a0 - mean, d1 = a1 - mean;
    float q = d0 * d0 + d1 * d1;
#pragma unroll
    for (int m = 32; m; m >>= 1) q += __shfl_xor(q, m, 64);
    if (lane == 0) red2[w] = q;
    __syncthreads();
    float var  = (red2[0] + red2[1] + red2[2] + red2[3]) * (1.f / 512.f);
    float rstd = rsqrtf(var + 1e-5f);

    float r0 = d0 * rstd * g[t]       + bb[t];
    float r1 = d1 * rstd * g[t + 256] + bb[t + 256];
    xo[t] = r0; xo[t + 256] = r1;
    hh[t] = f2bf(r0);
    hh[t + 256] = f2bf(r1);
}

// ---------------------------------------------------------------------------
extern "C" void kernel_launch(void* const* d_in, const int* in_sizes, int n_in,
                              void* d_out, int out_size, void* d_ws, size_t ws_size,
                              hipStream_t stream)
{
    const int*   tokens = (const int*)  d_in[0];
    const float* enc    = (const float*)d_in[1];
    const float* emb    = (const float*)d_in[3];
    const float* Wqkvo  = (const float*)d_in[4];   // [L,2,4,D,D]
    const float* bqkvo  = (const float*)d_in[5];   // [L,2,4,D]
    const float* W1     = (const float*)d_in[6];   // [L,D,DFF]
    const float* b1     = (const float*)d_in[7];
    const float* W2     = (const float*)d_in[8];   // [L,DFF,D]
    const float* b2     = (const float*)d_in[9];
    const float* lng    = (const float*)d_in[10];  // [L,3,D]
    const float* lnb    = (const float*)d_in[11];
    const float* Wout   = (const float*)d_in[12];  // [D,V]
    const float* bout   = (const float*)d_in[13];

    float* out    = (float*)d_out;
    float* selfA  = out + 65536000L;
    float* crossA = selfA + 67108864L;

    // workspace carve (~90 MB)
    char* p = (char*)d_ws;
    auto carve = [&](size_t bytes) { char* r = p; p += (bytes + 255) & ~255UL; return r; };
    float* x      = (float*)carve(1048576L * 4);
    short* xh     = (short*)carve(1048576L * 2);
    short* ench   = (short*)carve(1048576L * 2);
    short* qh     = (short*)carve(2097152L * 2);   // head-major Q|K hi
    short* vth    = (short*)carve(1048576L * 2);   // transposed V hi
    short* oh     = (short*)carve(1048576L * 2);
    short* t1h    = (short*)carve(4194304L * 2);   // FFN1 out hi
    float* part   = (float*)carve(4L * PSLAB * 4); // 4 K-split slabs
    short* WTLh   = (short*)carve(4194304L * 2);   // per-layer weights T hi
    short* WTh    = (short*)carve(16384000L * 2);  // full vocab WT hi (32.8 MB)

    const long PW = 262144L;    // 512*512
    const long HS = 1048576L;   // per attention operand slab

    embed_cvt_kernel<<<5120, 256, 0, stream>>>(tokens, emb, x, xh, enc, ench);

    for (int l = 0; l < NLAYER; ++l) {
        const float* bl = bqkvo + (long)l * 4096L;
        const float* bc = bl + 2048;
        const float* g  = lng + (long)l * 3 * 512;
        const float* bb = lnb + (long)l * 3 * 512;

        wtrans_layer_kernel<<<1024, 256, 0, stream>>>(Wqkvo, W1, W2, l, WTLh);

        // ---- self-attention (QKV one dispatch, A always xh) ----
        gemm_mfma_kernel<64,64,0,3><<<dim3(8, 32, 3), 256, 0, stream>>>(
            xh, xh, WTLh, bl, nullptr, qh, vth,
            512, 512, 512, 0, PW, 512, HS, 0, /*scaledZ=*/0, /*vtZ=*/2,
            /*aSwitchZ=*/3);
        attn_fused_kernel<true><<<dim3(32, 16), 128, 0, stream>>>(
            qh, qh + HS, vth, selfA + (long)l * 16777216L, oh);
        gemm_mfma_kernel<64,64,0,5><<<dim3(8, 32, 2), 256, 0, stream>>>(
            oh, nullptr, WTLh + 3*PW, nullptr, part, nullptr, nullptr,
            256, 512, 512, 512, 0, 0, PSLAB, 256, -1, -1, 99);
        add_ln_kernel<2><<<MROWS, 256, 0, stream>>>(
            x, part, PSLAB, bl + 3*512, g, bb, x, xh);

        // ---- cross-attention (QKV merged: z0 Q from xh, z1 K / z2 V from enc)
        gemm_mfma_kernel<64,64,0,3><<<dim3(8, 32, 3), 256, 0, stream>>>(
            xh, ench, WTLh + 4*PW, bc, nullptr, qh, vth,
            512, 512, 512, 0, PW, 512, HS, 0, /*scaledZ=*/0, /*vtZ=*/2,
            /*aSwitchZ=*/1);
        attn_fused_kernel<false><<<dim3(32, 16), 128, 0, stream>>>(
            qh, qh + HS, vth, crossA + (long)l * 16777216L, oh);
        gemm_mfma_kernel<64,64,0,5><<<dim3(8, 32, 2), 256, 0, stream>>>(
            oh, nullptr, WTLh + 7*PW, nullptr, part, nullptr, nullptr,
            256, 512, 512, 512, 0, 0, PSLAB, 256, -1, -1, 99);
        add_ln_kernel<2><<<MROWS, 256, 0, stream>>>(
            x, part, PSLAB, bc + 3*512, g + 512, bb + 512, x, xh);

        // ---- FFN ----
        gemm_mfma_kernel<64,64,1,2><<<dim3(32, 32, 1), 256, 0, stream>>>(
            xh, nullptr, WTLh + 2097152L, b1 + (long)l * 2048,
            nullptr, t1h, nullptr,
            512, 512, 512, 2048, 0, 0, 0, 0, -1, -1, 99);
        gemm_mfma_kernel<64,64,0,5><<<dim3(8, 32, 4), 256, 0, stream>>>(
            t1h, nullptr, WTLh + 3145728L, nullptr, part,
            nullptr, nullptr,
            512, 2048, 2048, 512, 0, 0, PSLAB, 512, -1, -1, 99);
        add_ln_kernel<4><<<MROWS, 256, 0, stream>>>(
            x, part, PSLAB, b2 + (long)l * 512, g + 1024, bb + 1024, x, xh);
    }

    // ---- final vocab projection (T1 XCD swizzle, nwg=4000) ----
    wtrans_kernel<<<dim3(500, 8, 1), 256, 0, stream>>>(Wout, WTh, 512, VOCAB);
    gemm_mfma_kernel<128,128,0,0><<<dim3(250, 16, 1), 256, 0, stream>>>(
        xh, nullptr, WTh, bout, out,
        nullptr, nullptr,
        512, 512, 512, VOCAB, 0, 0, 0, 0, -1, -1, 99);
}

// Round 22
// 852.703 us; speedup vs baseline: 1.1763x; 1.0090x over previous
//
#include <hip/hip_runtime.h>
#include <hip/hip_bf16.h>

// ---------------------------------------------------------------------------
// Transformer decoder, fp32 I/O. All matmuls pure bf16 1-product, fp32 acc.
// BK=32 2-phase dbuf GEMMs, T1 XCD-chunked swizzle everywhere; fused 2-pass
// attention (+T5 setprio around MFMA); cross QKV merged via A-select.
// B=2, ST=SS=1024, D=512, H=8, DK=64, L=4, DFF=2048, V=32000.
// ---------------------------------------------------------------------------

#define D_MODEL 512
#define NHEAD   8
#define DKH     64
#define SEQ     1024
#define NLAYER  4
#define DFF_    2048
#define VOCAB   32000
#define BATCH   2
#define MROWS   (BATCH*SEQ)   // 2048
#define PSLAB   1048576L

typedef short bf16x8 __attribute__((ext_vector_type(8)));
typedef short short4v __attribute__((ext_vector_type(4)));
typedef float f32x4  __attribute__((ext_vector_type(4)));

static __device__ __forceinline__ short f2bf(float f) {
    __hip_bfloat16 h = __float2bfloat16(f);
    return *reinterpret_cast<short*>(&h);
}
static __device__ __forceinline__ float bf2f(short s) {
    __hip_bfloat16 h = *reinterpret_cast<__hip_bfloat16*>(&s);
    return __bfloat162float(h);
}
static __device__ __forceinline__ void gld16(const void* g, void* l) {
    __builtin_amdgcn_global_load_lds(
        (__attribute__((address_space(1))) void*)(void*)g,
        (__attribute__((address_space(3))) void*)l, 16, 0, 0);
}

// ---------------- embedding+PE (blocks 0..4095) | enc cvt (4096..5119) ------
__global__ __launch_bounds__(256) void embed_cvt_kernel(
    const int* __restrict__ tokens, const float* __restrict__ emb,
    float* __restrict__ x, short* __restrict__ xh,
    const float* __restrict__ enc, short* __restrict__ ench)
{
    if (blockIdx.x < 4096) {
        long idx = (long)blockIdx.x * 256 + threadIdx.x;   // over 1,048,576
        int  d   = (int)(idx & (D_MODEL - 1));
        long row = idx >> 9;
        int  s   = (int)(row & (SEQ - 1));
        int  tok = tokens[row];
        float twoi = (float)((d >> 1) << 1);
        float div  = expf(twoi * (-9.210340371976184f / 512.0f));
        float arg  = (float)s * div;
        float pe   = (d & 1) ? cosf(arg) : sinf(arg);
        float v = emb[(long)tok * D_MODEL + d] * 22.62741699796952f + pe;
        x[idx] = v;
        xh[idx] = f2bf(v);
    } else {
        long e = ((long)(blockIdx.x - 4096) * 256 + threadIdx.x) * 4;
        float4 v = *(const float4*)&enc[e];
        short4v hv;
        hv[0] = f2bf(v.x); hv[1] = f2bf(v.y);
        hv[2] = f2bf(v.z); hv[3] = f2bf(v.w);
        *(short4v*)&ench[e] = hv;
    }
}

// ---------------- weight transpose-convert: W[K,N] -> WT[N,K] hi ------------
__global__ __launch_bounds__(256) void wtrans_kernel(
    const float* __restrict__ W, short* __restrict__ Th,
    int K, int ldW)
{
    const int n0 = blockIdx.x * 64, k0 = blockIdx.y * 64;
    __shared__ float tile[64][65];
    const int t = threadIdx.x;
#pragma unroll
    for (int i = 0; i < 4; ++i) {
        int e = t + i * 256; int kk = e >> 4; int nn = (e & 15) * 4;
        float4 v = *(const float4*)&W[(long)(k0 + kk) * ldW + n0 + nn];
        tile[kk][nn] = v.x; tile[kk][nn + 1] = v.y;
        tile[kk][nn + 2] = v.z; tile[kk][nn + 3] = v.w;
    }
    __syncthreads();
    const int n = t >> 2, ks = (t & 3) * 16;
    short h8[16];
#pragma unroll
    for (int j = 0; j < 16; ++j) h8[j] = f2bf(tile[ks + j][n]);
    long base = (long)(n0 + n) * K + k0 + ks;
    *(bf16x8*)&Th[base]     = *(bf16x8*)&h8[0];
    *(bf16x8*)&Th[base + 8] = *(bf16x8*)&h8[8];
}

// ---------------- merged per-layer weight transpose (10 matrices, hi only) --
__global__ __launch_bounds__(256) void wtrans_layer_kernel(
    const float* __restrict__ Wqkvo, const float* __restrict__ W1,
    const float* __restrict__ W2, int l,
    short* __restrict__ Th)
{
    const int j = blockIdx.x;
    const float* W; int ldW, K; long dstOff; int n0, k0;
    if (j < 512) {
        int mat = j >> 6, tile_ = j & 63;
        W = Wqkvo + (long)l * 2097152L + (long)mat * 262144L;
        ldW = 512; K = 512; dstOff = (long)mat * 262144L;
        n0 = (tile_ & 7) * 64; k0 = (tile_ >> 3) * 64;
    } else if (j < 768) {
        int t2 = j - 512;
        W = W1 + (long)l * 1048576L; ldW = 2048; K = 512; dstOff = 2097152L;
        n0 = (t2 & 31) * 64; k0 = (t2 >> 5) * 64;
    } else {
        int t3 = j - 768;
        W = W2 + (long)l * 1048576L; ldW = 512; K = 2048; dstOff = 3145728L;
        n0 = (t3 & 7) * 64; k0 = (t3 >> 3) * 64;
    }
    __shared__ float tile[64][65];
    const int t = threadIdx.x;
#pragma unroll
    for (int i = 0; i < 4; ++i) {
        int e = t + i * 256; int kk = e >> 4; int nn = (e & 15) * 4;
        float4 v = *(const float4*)&W[(long)(k0 + kk) * ldW + n0 + nn];
        tile[kk][nn] = v.x; tile[kk][nn + 1] = v.y;
        tile[kk][nn + 2] = v.z; tile[kk][nn + 3] = v.w;
    }
    __syncthreads();
    const int n = t >> 2, ks = (t & 3) * 16;
    short h8[16];
#pragma unroll
    for (int j2 = 0; j2 < 16; ++j2) h8[j2] = f2bf(tile[ks + j2][n]);
    long base = dstOff + (long)(n0 + n) * K + k0 + ks;
    *(bf16x8*)&Th[base]     = *(bf16x8*)&h8[0];
    *(bf16x8*)&Th[base + 8] = *(bf16x8*)&h8[8];
}

// ---------------- 1-product MFMA GEMM, 2-phase dbuf (BK=32) -----------------
// A = (MODE==3 && z>=aSwitchZ) ? A2h : Ah.  K-window at z*kOff.
// MODE 0: fp32+bias. MODE 2: bf16 hi+bias(+relu). MODE 3: head-major attn
// operand hi w/ dk swizzle; z==scaledZ -> *0.125; z==vtZ -> transposed V hi.
// MODE 5: fp32 partial, no bias.  T1 XCD-chunked x/y remap (nwg_xy%8==0).
template<int BM, int BN, int ACT, int MODE>
__global__ __launch_bounds__(256) void gemm_mfma_kernel(
    const short* __restrict__ Ah, const short* __restrict__ A2h,
    const short* __restrict__ Bh,
    const float* __restrict__ bias, float* __restrict__ C,
    short* __restrict__ Ch, short* __restrict__ VTh,
    int Keff, int ldA, int ldB, int ldc,
    long zB, long zBias, long zC, int kOff, int scaledZ, int vtZ, int aSwitchZ)
{
    constexpr int MT_M = BM / 32;
    constexpr int MT_N = BN / 32;
    const long z = blockIdx.z;
    Bh += z * zB;
    if (MODE != 5) bias += z * zBias;

    const short* Au = (MODE == 3 && (int)z >= aSwitchZ) ? A2h : Ah;

    int bx, by;
    {
        int gx = gridDim.x;
        int nwg = gx * gridDim.y;
        int flat = blockIdx.y * gx + blockIdx.x;
        int swz = (flat & 7) * (nwg >> 3) + (flat >> 3);   // XCD-chunked
        bx = swz % gx;
        by = swz / gx;
    }
    const int n0 = bx * BN, m0 = by * BM;
    const int t = threadIdx.x;
    const int w = t >> 6, lane = t & 63;
    const int wm = w >> 1, wn = w & 1;
    const int lr = lane & 15, ks = lane >> 4;

    __shared__ short sAh[2][BM * 32];
    __shared__ short sBh[2][BN * 32];

    f32x4 acc[MT_M][MT_N];
#pragma unroll
    for (int i = 0; i < MT_M; ++i)
#pragma unroll
        for (int j = 0; j < MT_N; ++j) acc[i][j] = (f32x4){0.f, 0.f, 0.f, 0.f};

    const long rowA = ((long)m0 * ldA + (long)z * kOff) * 2;   // bytes
    const long rowB = ((long)n0 * ldB + (long)z * kOff) * 2;

    auto STAGE = [&](int buf, int k0) {
#pragma unroll
        for (int i = 0; i < BM / 64; ++i) {
            const int  L = i * 4096 + t * 16;
            const int  r = L >> 6, s = L & 63;
            const long gb = ((long)r * ldA + k0) * 2 + s;
            gld16((const char*)Au + rowA + gb, (char*)&sAh[buf][0] + L);
        }
#pragma unroll
        for (int i = 0; i < BN / 64; ++i) {
            const int  L = i * 4096 + t * 16;
            const int  r = L >> 6, s = L & 63;
            const long gb = ((long)r * ldB + k0) * 2 + s;
            gld16((const char*)Bh + rowB + gb, (char*)&sBh[buf][0] + L);
        }
    };
    auto COMPUTE = [&](int buf) {
        bf16x8 ah[MT_M], bh[MT_N];
#pragma unroll
        for (int mt = 0; mt < MT_M; ++mt) {
            int row = wm * (BM / 2) + mt * 16 + lr;
            ah[mt] = *(const bf16x8*)&sAh[buf][row * 32 + ks * 8];
        }
#pragma unroll
        for (int nt = 0; nt < MT_N; ++nt) {
            int col = wn * (BN / 2) + nt * 16 + lr;
            bh[nt] = *(const bf16x8*)&sBh[buf][col * 32 + ks * 8];
        }
#pragma unroll
        for (int mt = 0; mt < MT_M; ++mt)
#pragma unroll
            for (int nt = 0; nt < MT_N; ++nt)
                acc[mt][nt] = __builtin_amdgcn_mfma_f32_16x16x32_bf16(
                    ah[mt], bh[nt], acc[mt][nt], 0, 0, 0);
    };

    STAGE(0, 0);
    __syncthreads();
    int cur = 0;
    for (int k0 = 0; k0 < Keff; k0 += 32) {
        if (k0 + 32 < Keff) STAGE(cur ^ 1, k0 + 32);
        COMPUTE(cur);
        __syncthreads();
        cur ^= 1;
    }

    const int rq = lane >> 4, cq = lane & 15;
#pragma unroll
    for (int mt = 0; mt < MT_M; ++mt)
#pragma unroll
        for (int nt = 0; nt < MT_N; ++nt) {
            int gr0 = m0 + wm * (BM / 2) + mt * 16 + rq * 4;
            int gc  = n0 + wn * (BN / 2) + nt * 16 + cq;
            float vv[4];
            float bv = (MODE == 5) ? 0.f : bias[gc];
#pragma unroll
            for (int i = 0; i < 4; ++i) {
                float v = acc[mt][nt][i] + bv;
                if (ACT == 1) v = fmaxf(v, 0.f);
                vv[i] = v;
            }
            if (MODE == 0 || MODE == 5) {
#pragma unroll
                for (int i = 0; i < 4; ++i)
                    C[(long)(gr0 + i) * ldc + gc + z * zC] = vv[i];
            } else if (MODE == 2) {
#pragma unroll
                for (int i = 0; i < 4; ++i)
                    Ch[(long)(gr0 + i) * ldc + gc] = f2bf(vv[i]);
            } else {               // MODE 3
                if ((int)z == vtZ) {
                    int b = gr0 >> 10, s0 = gr0 & (SEQ - 1);
                    int hh2 = gc >> 6, dk = gc & 63;
                    int swz = (((dk >> 1) & 3) << 3) | (((dk >> 3) & 1) << 5);
                    long base = (((long)(b * NHEAD + hh2)) * 64 + dk) * 1024
                              + (long)(((s0 & ~7) ^ swz) | (s0 & 7));
                    short4v hv;
#pragma unroll
                    for (int i = 0; i < 4; ++i) hv[i] = f2bf(vv[i]);
                    *(short4v*)&VTh[base] = hv;
                } else {
                    float sc = ((int)z == scaledZ) ? 0.125f : 1.f;
#pragma unroll
                    for (int i = 0; i < 4; ++i) {
                        float v2 = vv[i] * sc;
                        int gr = gr0 + i;
                        int b = gr >> 10, s = gr & (SEQ - 1);
                        int hh2 = gc >> 6, dk = gc & 63;
                        int dks = dk ^ (((s >> 1) & 7) << 3);
                        long oidx = z * zC +
                            (((long)(b * NHEAD + hh2)) * SEQ + s) * 64 + dks;
                        Ch[oidx] = f2bf(v2);
                    }
                }
            }
        }
}

// ---------------- fused attention: 32 q-rows, 2 waves, 4 blocks/CU ----------
// QK and PV both 1-product bf16. LDS = 16+16+5 = 37 KB. T1 XCD remap +
// T5 setprio around MFMA clusters.
template<bool CAUSAL>
__global__ __launch_bounds__(128) void attn_fused_kernel(
    const short* __restrict__ Qh, const short* __restrict__ Kh,
    const short* __restrict__ VTh,
    float* __restrict__ attn, short* __restrict__ Oh)
{
    int strip, bh;
    {
        int flat = blockIdx.y * 32 + blockIdx.x;           // nwg = 512
        int swz = (flat & 7) * 64 + (flat >> 3);
        bh = swz >> 5;
        strip = swz & 31;
    }
    const int q0 = strip * 32;
    const int t = threadIdx.x, w = t >> 6, lane = t & 63;
    const int lr = lane & 15, ks = lane >> 4;
    const int rq = lane >> 4, cq = lane & 15;
    const int sxq = (lr >> 1) & 7;

    __shared__ short sKh[2][64*64];                  // 16 KB
    __shared__ short sVh[2][64*64];                  // 16 KB
    __shared__ short sPh[2][16*80];                  //  5 KB

    const int diag  = strip >> 1;
    const int ktmax = CAUSAL ? diag + 1 : 16;

    // Q stage (32 rows hi) via sKh[0]
    {
        const long qb = ((long)bh * SEQ + q0) * 128;
#pragma unroll
        for (int i2 = 0; i2 < 2; ++i2) {
            int L = i2 * 2048 + t * 16; int r = L >> 7, off = L & 127;
            gld16((const char*)Qh + qb + (long)r*128 + off, (char*)&sKh[0][0] + L);
        }
    }
    __syncthreads();
    bf16x8 qa[2];
#pragma unroll
    for (int k0 = 0; k0 < 2; ++k0) {
        int o = (w*16 + lr) * 64 + ((k0*32 + ks*8) ^ (sxq << 3));
        qa[k0] = *(const bf16x8*)&sKh[0][o];
    }
    __syncthreads();

    auto stageK = [&](int buf, int kt) {
        const long kb = ((long)bh * SEQ + kt*64) * 128;
#pragma unroll
        for (int i2 = 0; i2 < 4; ++i2) {
            int L = i2*2048 + t*16; int r = L >> 7, off = L & 127;
            gld16((const char*)Kh + kb + (long)r*128 + off, (char*)&sKh[buf][0] + L);
        }
    };
    auto stageV = [&](int buf, int kt) {
        const long vb = ((long)bh * 64) * 2048 + (long)kt * 128;
#pragma unroll
        for (int i2 = 0; i2 < 4; ++i2) {
            int L = i2*2048 + t*16; int r = L >> 7, off = L & 127;
            gld16((const char*)VTh + vb + (long)r*2048 + off, (char*)&sVh[buf][0] + L);
        }
    };
    auto scoresOf = [&](int buf, int kt, f32x4* sc) {
#pragma unroll
        for (int nt = 0; nt < 4; ++nt) sc[nt] = (f32x4){0.f, 0.f, 0.f, 0.f};
        __builtin_amdgcn_s_setprio(1);                     // T5
#pragma unroll
        for (int k0 = 0; k0 < 2; ++k0) {
            bf16x8 kh[4];
#pragma unroll
            for (int nt = 0; nt < 4; ++nt) {
                int o = (nt*16 + lr) * 64 + ((k0*32 + ks*8) ^ (sxq << 3));
                kh[nt] = *(const bf16x8*)&sKh[buf][o];
            }
#pragma unroll
            for (int nt = 0; nt < 4; ++nt)
                sc[nt] = __builtin_amdgcn_mfma_f32_16x16x32_bf16(
                    qa[k0], kh[nt], sc[nt], 0, 0, 0);
        }
        __builtin_amdgcn_s_setprio(0);                     // T5
        if (CAUSAL && kt == diag) {
            int row = q0 + w*16 + rq*4;
#pragma unroll
            for (int nt = 0; nt < 4; ++nt) {
                int col = kt*64 + nt*16 + cq;
#pragma unroll
                for (int i = 0; i < 4; ++i)
                    if (col > row + i) sc[nt][i] = -1e9f;
            }
        }
    };

    // ---- pass 1: online max + sum ----
    float m[4]   = {-3e38f, -3e38f, -3e38f, -3e38f};
    float sum[4] = {0.f, 0.f, 0.f, 0.f};
    int cur = 0;
    stageK(0, 0);
    __syncthreads();
    for (int kt = 0; kt < ktmax; ++kt) {
        if (kt + 1 < ktmax) stageK(cur ^ 1, kt + 1);
        f32x4 sc[4];
        scoresOf(cur, kt, sc);
#pragma unroll
        for (int i = 0; i < 4; ++i) {
            float tm = fmaxf(fmaxf(sc[0][i], sc[1][i]), fmaxf(sc[2][i], sc[3][i]));
#pragma unroll
            for (int d2 = 1; d2 <= 8; d2 <<= 1) tm = fmaxf(tm, __shfl_xor(tm, d2, 64));
            float mn = fmaxf(m[i], tm);
            float ps = __expf(sc[0][i] - mn) + __expf(sc[1][i] - mn)
                     + __expf(sc[2][i] - mn) + __expf(sc[3][i] - mn);
#pragma unroll
            for (int d2 = 1; d2 <= 8; d2 <<= 1) ps += __shfl_xor(ps, d2, 64);
            sum[i] = sum[i] * __expf(m[i] - mn) + ps;
            m[i] = mn;
        }
        __syncthreads();
        cur ^= 1;
    }
    float inv[4];
#pragma unroll
    for (int i = 0; i < 4; ++i) inv[i] = 1.f / sum[i];

    // ---- pass 2: recompute, probs out, PV (1-product) ----
    f32x4 acco[4];
#pragma unroll
    for (int nt = 0; nt < 4; ++nt) acco[nt] = (f32x4){0.f, 0.f, 0.f, 0.f};

    cur = 0;
    stageK(0, 0); stageV(0, 0);
    __syncthreads();
    for (int kt = 0; kt < ktmax; ++kt) {
        if (kt + 1 < ktmax) { stageK(cur ^ 1, kt + 1); stageV(cur ^ 1, kt + 1); }
        f32x4 sc[4];
        scoresOf(cur, kt, sc);
#pragma unroll
        for (int nt = 0; nt < 4; ++nt)
#pragma unroll
            for (int i = 0; i < 4; ++i) {
                float p = __expf(sc[nt][i] - m[i]) * inv[i];
                attn[((long)bh << 20) + ((long)(q0 + w*16 + rq*4 + i) << 10)
                     + kt*64 + nt*16 + cq] = p;
                sPh[w][(rq*4 + i)*80 + nt*16 + cq] = f2bf(p);
            }
        __builtin_amdgcn_s_setprio(1);                     // T5
#pragma unroll
        for (int k0 = 0; k0 < 2; ++k0) {
            bf16x8 pah = *(const bf16x8*)&sPh[w][lr*80 + k0*32 + ks*8];
#pragma unroll
            for (int nt = 0; nt < 4; ++nt) {
                int dk = nt*16 + lr;
                int swz = (((dk >> 1) & 3) << 3) | (((dk >> 3) & 1) << 5);
                int koff = (k0*32 + ks*8) ^ swz;
                bf16x8 vh8 = *(const bf16x8*)&sVh[cur][dk*64 + koff];
                acco[nt] = __builtin_amdgcn_mfma_f32_16x16x32_bf16(
                    pah, vh8, acco[nt], 0, 0, 0);
            }
        }
        __builtin_amdgcn_s_setprio(0);                     // T5
        __syncthreads();
        cur ^= 1;
    }

    // ---- causal masked region: vectorized zero fill ----
    if (CAUSAL && ktmax < 16) {
        const int r = t >> 2, g = (t & 3) * 4;
        const long rowbase = ((long)bh << 20) + ((long)(q0 + r) << 10);
        const float4 z4 = {0.f, 0.f, 0.f, 0.f};
        for (int c = ktmax * 64 + g; c < SEQ; c += 16)
            *(float4*)&attn[rowbase + c] = z4;
    }

    const int b = bh >> 3, hh_ = bh & 7;
#pragma unroll
    for (int nt = 0; nt < 4; ++nt)
#pragma unroll
        for (int i = 0; i < 4; ++i) {
            long oidx = ((long)(b * SEQ + q0 + w*16 + rq*4 + i)) * D_MODEL
                      + hh_*64 + nt*16 + cq;
            Oh[oidx] = f2bf(acco[nt][i]);
        }
}

// ---------------- residual + NS partial slabs + bias + LayerNorm + hi -------
template<int NS>
__global__ __launch_bounds__(256) void add_ln_kernel(
    const float* __restrict__ xin, const float* __restrict__ part, long PS,
    const float* __restrict__ bias,
    const float* __restrict__ g, const float* __restrict__ bb,
    float* __restrict__ xout, short* __restrict__ xh)
{
    long row = blockIdx.x;
    const float* xr = xin + row * D_MODEL;
    float*       xo = xout+ row * D_MODEL;
    short*       hh = xh  + row * D_MODEL;
    int t = threadIdx.x;

    float a0 = xr[t]       + bias[t];
    float a1 = xr[t + 256] + bias[t + 256];
#pragma unroll
    for (int s2 = 0; s2 < NS; ++s2) {
        a0 += part[s2 * PS + row * D_MODEL + t];
        a1 += part[s2 * PS + row * D_MODEL + t + 256];
    }

    float s = a0 + a1;
#pragma unroll
    for (int m = 32; m; m >>= 1) s += __shfl_xor(s, m, 64);
    __shared__ float red1[4];
    __shared__ float red2[4];
    int w = t >> 6, lane = t & 63;
    if (lane == 0) red1[w] = s;
    __syncthreads();
    float mean = (red1[0] + red1[1] + red1[2] + red1[3]) * (1.f / 512.f);

    float d0 = a0 - mean, d1 = a1 - mean;
    float q = d0 * d0 + d1 * d1;
#pragma unroll
    for (int m = 32; m; m >>= 1) q += __shfl_xor(q, m, 64);
    if (lane == 0) red2[w] = q;
    __syncthreads();
    float var  = (red2[0] + red2[1] + red2[2] + red2[3]) * (1.f / 512.f);
    float rstd = rsqrtf(var + 1e-5f);

    float r0 = d0 * rstd * g[t]       + bb[t];
    float r1 = d1 * rstd * g[t + 256] + bb[t + 256];
    xo[t] = r0; xo[t + 256] = r1;
    hh[t] = f2bf(r0);
    hh[t + 256] = f2bf(r1);
}

// ---------------------------------------------------------------------------
extern "C" void kernel_launch(void* const* d_in, const int* in_sizes, int n_in,
                              void* d_out, int out_size, void* d_ws, size_t ws_size,
                              hipStream_t stream)
{
    const int*   tokens = (const int*)  d_in[0];
    const float* enc    = (const float*)d_in[1];
    const float* emb    = (const float*)d_in[3];
    const float* Wqkvo  = (const float*)d_in[4];   // [L,2,4,D,D]
    const float* bqkvo  = (const float*)d_in[5];   // [L,2,4,D]
    const float* W1     = (const float*)d_in[6];   // [L,D,DFF]
    const float* b1     = (const float*)d_in[7];
    const float* W2     = (const float*)d_in[8];   // [L,DFF,D]
    const float* b2     = (const float*)d_in[9];
    const float* lng    = (const float*)d_in[10];  // [L,3,D]
    const float* lnb    = (const float*)d_in[11];
    const float* Wout   = (const float*)d_in[12];  // [D,V]
    const float* bout   = (const float*)d_in[13];

    float* out    = (float*)d_out;
    float* selfA  = out + 65536000L;
    float* crossA = selfA + 67108864L;

    // workspace carve (~90 MB)
    char* p = (char*)d_ws;
    auto carve = [&](size_t bytes) { char* r = p; p += (bytes + 255) & ~255UL; return r; };
    float* x      = (float*)carve(1048576L * 4);
    short* xh     = (short*)carve(1048576L * 2);
    short* ench   = (short*)carve(1048576L * 2);
    short* qh     = (short*)carve(2097152L * 2);   // head-major Q|K hi
    short* vth    = (short*)carve(1048576L * 2);   // transposed V hi
    short* oh     = (short*)carve(1048576L * 2);
    short* t1h    = (short*)carve(4194304L * 2);   // FFN1 out hi
    float* part   = (float*)carve(4L * PSLAB * 4); // 4 K-split slabs
    short* WTLh   = (short*)carve(4194304L * 2);   // per-layer weights T hi
    short* WTh    = (short*)carve(16384000L * 2);  // full vocab WT hi (32.8 MB)

    const long PW = 262144L;    // 512*512
    const long HS = 1048576L;   // per attention operand slab

    embed_cvt_kernel<<<5120, 256, 0, stream>>>(tokens, emb, x, xh, enc, ench);

    for (int l = 0; l < NLAYER; ++l) {
        const float* bl = bqkvo + (long)l * 4096L;
        const float* bc = bl + 2048;
        const float* g  = lng + (long)l * 3 * 512;
        const float* bb = lnb + (long)l * 3 * 512;

        wtrans_layer_kernel<<<1024, 256, 0, stream>>>(Wqkvo, W1, W2, l, WTLh);

        // ---- self-attention (QKV one dispatch, A always xh) ----
        gemm_mfma_kernel<64,64,0,3><<<dim3(8, 32, 3), 256, 0, stream>>>(
            xh, xh, WTLh, bl, nullptr, qh, vth,
            512, 512, 512, 0, PW, 512, HS, 0, /*scaledZ=*/0, /*vtZ=*/2,
            /*aSwitchZ=*/3);
        attn_fused_kernel<true><<<dim3(32, 16), 128, 0, stream>>>(
            qh, qh + HS, vth, selfA + (long)l * 16777216L, oh);
        gemm_mfma_kernel<64,64,0,5><<<dim3(8, 32, 2), 256, 0, stream>>>(
            oh, nullptr, WTLh + 3*PW, nullptr, part, nullptr, nullptr,
            256, 512, 512, 512, 0, 0, PSLAB, 256, -1, -1, 99);
        add_ln_kernel<2><<<MROWS, 256, 0, stream>>>(
            x, part, PSLAB, bl + 3*512, g, bb, x, xh);

        // ---- cross-attention (QKV merged: z0 Q from xh, z1 K / z2 V from enc)
        gemm_mfma_kernel<64,64,0,3><<<dim3(8, 32, 3), 256, 0, stream>>>(
            xh, ench, WTLh + 4*PW, bc, nullptr, qh, vth,
            512, 512, 512, 0, PW, 512, HS, 0, /*scaledZ=*/0, /*vtZ=*/2,
            /*aSwitchZ=*/1);
        attn_fused_kernel<false><<<dim3(32, 16), 128, 0, stream>>>(
            qh, qh + HS, vth, crossA + (long)l * 16777216L, oh);
        gemm_mfma_kernel<64,64,0,5><<<dim3(8, 32, 2), 256, 0, stream>>>(
            oh, nullptr, WTLh + 7*PW, nullptr, part, nullptr, nullptr,
            256, 512, 512, 512, 0, 0, PSLAB, 256, -1, -1, 99);
        add_ln_kernel<2><<<MROWS, 256, 0, stream>>>(
            x, part, PSLAB, bc + 3*512, g + 512, bb + 512, x, xh);

        // ---- FFN ----
        gemm_mfma_kernel<64,64,1,2><<<dim3(32, 32, 1), 256, 0, stream>>>(
            xh, nullptr, WTLh + 2097152L, b1 + (long)l * 2048,
            nullptr, t1h, nullptr,
            512, 512, 512, 2048, 0, 0, 0, 0, -1, -1, 99);
        gemm_mfma_kernel<64,64,0,5><<<dim3(8, 32, 4), 256, 0, stream>>>(
            t1h, nullptr, WTLh + 3145728L, nullptr, part,
            nullptr, nullptr,
            512, 2048, 2048, 512, 0, 0, PSLAB, 512, -1, -1, 99);
        add_ln_kernel<4><<<MROWS, 256, 0, stream>>>(
            x, part, PSLAB, b2 + (long)l * 512, g + 1024, bb + 1024, x, xh);
    }

    // ---- final vocab projection (T1 XCD swizzle) ----
    wtrans_kernel<<<dim3(500, 8, 1), 256, 0, stream>>>(Wout, WTh, 512, VOCAB);
    gemm_mfma_kernel<128,128,0,0><<<dim3(250, 16, 1), 256, 0, stream>>>(
        xh, nullptr, WTh, bout, out,
        nullptr, nullptr,
        512, 512, 512, VOCAB, 0, 0, 0, 0, -1, -1, 99);
}